// Round 1
// baseline (1204.568 us; speedup 1.0000x reference)
//
#include <hip/hip_runtime.h>
#include <hip/hip_bf16.h>

#define H 128
#define IN_DIM 30

// ---------------- CSR build ----------------
__global__ void k_count(const int* __restrict__ col, int* __restrict__ counts, int E){
  for (int e = blockIdx.x*blockDim.x + threadIdx.x; e < E; e += gridDim.x*blockDim.x)
    atomicAdd(&counts[col[e]], 1);
}

__global__ void k_scanA(const int* __restrict__ counts, int* __restrict__ offsets,
                        int* __restrict__ bsum, int n){
  __shared__ int buf[256];
  int i = blockIdx.x*256 + threadIdx.x;
  int v = (i < n) ? counts[i] : 0;
  buf[threadIdx.x] = v; __syncthreads();
  for (int off = 1; off < 256; off <<= 1){
    int t = (threadIdx.x >= off) ? buf[threadIdx.x - off] : 0;
    __syncthreads();
    buf[threadIdx.x] += t;
    __syncthreads();
  }
  if (i < n) offsets[i] = buf[threadIdx.x] - v;           // block-local exclusive
  if (threadIdx.x == 255) bsum[blockIdx.x] = buf[255];
}

__global__ void k_scanB(int* __restrict__ bsum, int nb){
  __shared__ int buf[256];
  int v = (threadIdx.x < nb) ? bsum[threadIdx.x] : 0;
  buf[threadIdx.x] = v; __syncthreads();
  for (int off = 1; off < 256; off <<= 1){
    int t = (threadIdx.x >= off) ? buf[threadIdx.x - off] : 0;
    __syncthreads();
    buf[threadIdx.x] += t;
    __syncthreads();
  }
  if (threadIdx.x < nb) bsum[threadIdx.x] = buf[threadIdx.x] - v;  // exclusive
}

__global__ void k_scanC(int* __restrict__ offsets, int* __restrict__ cursor,
                        const int* __restrict__ bsum, int n){
  int i = blockIdx.x*256 + threadIdx.x;
  if (i < n){ int o = offsets[i] + bsum[blockIdx.x]; offsets[i] = o; cursor[i] = o; }
}

__global__ void k_scatter(const int* __restrict__ ei, int* __restrict__ cursor,
                          int* __restrict__ csr, int E){
  for (int e = blockIdx.x*blockDim.x + threadIdx.x; e < E; e += gridDim.x*blockDim.x){
    int c = ei[E + e];
    int p = atomicAdd(&cursor[c], 1);
    csr[p] = ei[e];
  }
}

// ---------------- SAGE1: agg(30) + linear(30->128) + relu ----------------
__global__ __launch_bounds__(256) void k_sage1(
    const float* __restrict__ x, const int* __restrict__ csr,
    const int* __restrict__ offsets, const int* __restrict__ counts,
    const float* __restrict__ W1l, const float* __restrict__ b1l,
    const float* __restrict__ W1r, float* __restrict__ x1, int N)
{
  __shared__ __align__(16) float wl[128*33];
  __shared__ __align__(16) float wr[128*33];
  __shared__ float agv[2][32];
  __shared__ float xdv[2][32];
  int tid = threadIdx.x;
  for (int i = tid; i < 128*IN_DIM; i += 256){
    int c = i / IN_DIM, k = i % IN_DIM;
    wl[c*33 + k] = W1l[i];
    wr[c*33 + k] = W1r[i];
  }
  __syncthreads();
  int slot = tid >> 7, c = tid & 127;
  float bc = b1l[c];
  for (int d0 = blockIdx.x*2; d0 < N; d0 += gridDim.x*2){
    int d = d0 + slot; bool ok = d < N;
    if (ok && c < IN_DIM){
      int base = offsets[d], cnt = counts[d];
      float s = 0.f;
      for (int i = 0; i < cnt; i++){ int sr = csr[base + i]; s += x[sr*IN_DIM + c]; }
      float inv = 1.f / (float)(cnt > 0 ? cnt : 1);
      agv[slot][c] = s * inv;
      xdv[slot][c] = x[d*IN_DIM + c];
    }
    __syncthreads();
    if (ok){
      float s = bc;
      const float* wlr = &wl[c*33];
      const float* wrr = &wr[c*33];
      #pragma unroll
      for (int k = 0; k < IN_DIM; k++) s += agv[slot][k]*wlr[k] + xdv[slot][k]*wrr[k];
      x1[d*H + c] = fmaxf(s, 0.f);
    }
    __syncthreads();
  }
}

// ---------------- agg2: mean of x1 rows, one wave per node ----------------
__global__ __launch_bounds__(256) void k_agg2(
    const float* __restrict__ x1, const int* __restrict__ csr,
    const int* __restrict__ offsets, const int* __restrict__ counts,
    float* __restrict__ agg2, int N)
{
  int t = blockIdx.x*blockDim.x + threadIdx.x;
  int gw = t >> 6, lane = t & 63;
  int nw = (gridDim.x*blockDim.x) >> 6;
  for (int d = gw; d < N; d += nw){
    int base = offsets[d], cnt = counts[d];
    float a0 = 0.f, a1 = 0.f;
    for (int i = 0; i < cnt; i++){
      int s = csr[base + i];
      a0 += x1[s*H + lane];
      a1 += x1[s*H + 64 + lane];
    }
    float inv = 1.f / (float)(cnt > 0 ? cnt : 1);
    agg2[d*H + lane]      = a0 * inv;
    agg2[d*H + 64 + lane] = a1 * inv;
  }
}

// ---------------- SAGE2 linear: x2 = relu(agg2@W2l.T + b2l + x1@W2r.T) ----------------
__global__ __launch_bounds__(1024) void k_lin2(
    const float* __restrict__ agg2, const float* __restrict__ x1,
    const float* __restrict__ W2l, const float* __restrict__ b2l,
    const float* __restrict__ W2r, float* __restrict__ x2, int N)
{
  __shared__ __align__(16) float wl[128*132];
  __shared__ __align__(16) float wr[128*132];
  __shared__ __align__(16) float sa[8][128];
  __shared__ __align__(16) float sx[8][128];
  int tid = threadIdx.x;
  const float4* W2l4 = (const float4*)W2l;
  const float4* W2r4 = (const float4*)W2r;
  for (int i = tid; i < 128*128/4; i += 1024){
    int c = i >> 5, k = (i & 31) << 2;
    *(float4*)&wl[c*132 + k] = W2l4[i];
    *(float4*)&wr[c*132 + k] = W2r4[i];
  }
  __syncthreads();
  int slot = tid >> 7, c = tid & 127;
  float bc = b2l[c];
  for (int d0 = blockIdx.x*8; d0 < N; d0 += gridDim.x*8){
    int d = d0 + slot; bool ok = d < N;
    if (ok){ sa[slot][c] = agg2[d*H + c]; sx[slot][c] = x1[d*H + c]; }
    __syncthreads();
    if (ok){
      float s = bc;
      const float* wlr = &wl[c*132];
      const float* wrr = &wr[c*132];
      #pragma unroll
      for (int k = 0; k < H; k += 4){
        float4 a4 = *(const float4*)&sa[slot][k];
        float4 x4 = *(const float4*)&sx[slot][k];
        float4 w1 = *(const float4*)&wlr[k];
        float4 w2 = *(const float4*)&wrr[k];
        s += a4.x*w1.x + a4.y*w1.y + a4.z*w1.z + a4.w*w1.w;
        s += x4.x*w2.x + x4.y*w2.y + x4.z*w2.z + x4.w*w2.w;
      }
      x2[d*H + c] = fmaxf(s, 0.f);
    }
    __syncthreads();
  }
}

// ---------------- GRU gate kernels (GATE 0=r, 1=z, 2=n+combine) ----------------
template<int GATE>
__global__ __launch_bounds__(1024) void k_gate(
    const float* __restrict__ x2, const float* __restrict__ h,
    const float* __restrict__ Wih, const float* __restrict__ Whh,
    const float* __restrict__ bih, const float* __restrict__ bhh,
    const float* __restrict__ rr, const float* __restrict__ zz,
    float* __restrict__ out, int N)
{
  __shared__ __align__(16) float wi[128*132];
  __shared__ __align__(16) float wh[128*132];
  __shared__ __align__(16) float sx[8][128];
  __shared__ __align__(16) float sh[8][128];
  int tid = threadIdx.x;
  const float4* Wi4 = (const float4*)(Wih + GATE*128*128);
  const float4* Wh4 = (const float4*)(Whh + GATE*128*128);
  for (int i = tid; i < 128*128/4; i += 1024){
    int c = i >> 5, k = (i & 31) << 2;
    *(float4*)&wi[c*132 + k] = Wi4[i];
    *(float4*)&wh[c*132 + k] = Wh4[i];
  }
  __syncthreads();
  int slot = tid >> 7, c = tid & 127;
  float bi = bih[GATE*128 + c];
  float bh = bhh[GATE*128 + c];
  for (int d0 = blockIdx.x*8; d0 < N; d0 += gridDim.x*8){
    int d = d0 + slot; bool ok = d < N;
    if (ok){ sx[slot][c] = x2[d*H + c]; sh[slot][c] = h[d*H + c]; }
    __syncthreads();
    if (ok){
      float si = bi, sv = bh;
      const float* wir = &wi[c*132];
      const float* whr = &wh[c*132];
      #pragma unroll
      for (int k = 0; k < H; k += 4){
        float4 a4 = *(const float4*)&sx[slot][k];
        float4 h4 = *(const float4*)&sh[slot][k];
        float4 w1 = *(const float4*)&wir[k];
        float4 w2 = *(const float4*)&whr[k];
        si += a4.x*w1.x + a4.y*w1.y + a4.z*w1.z + a4.w*w1.w;
        sv += h4.x*w2.x + h4.y*w2.y + h4.z*w2.z + h4.w*w2.w;
      }
      if (GATE < 2){
        out[d*H + c] = 1.f / (1.f + expf(-(si + sv)));
      } else {
        float rv = rr[d*H + c], zv = zz[d*H + c];
        float nn = tanhf(si + rv*sv);
        out[d*H + c] = (1.f - zv)*nn + zv*sh[slot][c];
      }
    }
    __syncthreads();
  }
}

// ---------------- P/Q precompute: P = h_new @ Wf1[:, :128].T, Q = ... [:,128:256].T ----------------
__global__ __launch_bounds__(1024) void k_pq(
    const float* __restrict__ hnew, const float* __restrict__ Wf1,
    float* __restrict__ P, float* __restrict__ Q, int N)
{
  __shared__ __align__(16) float wa[64*132];
  __shared__ __align__(16) float wb[64*132];
  __shared__ __align__(16) float shh[8][128];
  int tid = threadIdx.x;
  for (int i = tid; i < 64*128; i += 1024){
    int j = i >> 7, k = i & 127;
    wa[j*132 + k] = Wf1[j*260 + k];
    wb[j*132 + k] = Wf1[j*260 + 128 + k];
  }
  __syncthreads();
  int slot = tid >> 7, c = tid & 127;
  int j = c & 63;
  const float* w = (c < 64) ? &wa[j*132] : &wb[j*132];
  float* op = (c < 64) ? P : Q;
  for (int d0 = blockIdx.x*8; d0 < N; d0 += gridDim.x*8){
    int d = d0 + slot; bool ok = d < N;
    if (ok) shh[slot][c] = hnew[d*H + c];
    __syncthreads();
    if (ok){
      float s = 0.f;
      #pragma unroll
      for (int k = 0; k < H; k += 4){
        float4 h4 = *(const float4*)&shh[slot][k];
        float4 w4 = *(const float4*)&w[k];
        s += h4.x*w4.x + h4.y*w4.y + h4.z*w4.z + h4.w*w4.w;
      }
      op[d*64 + j] = s;
    }
    __syncthreads();
  }
}

// ---------------- disp decoder: relu(h@Wd1.T+bd1)@Wd2.T+bd2, half-wave per node ----------------
__global__ __launch_bounds__(256) void k_disp(
    const float* __restrict__ hnew, const float* __restrict__ Wd1,
    const float* __restrict__ bd1, const float* __restrict__ Wd2,
    const float* __restrict__ bd2, float* __restrict__ disp, int N)
{
  __shared__ __align__(16) float wd[32*132];
  int tid = threadIdx.x;
  for (int i = tid; i < 32*128; i += 256){
    int j = i >> 7, k = i & 127;
    wd[j*132 + k] = Wd1[i];
  }
  __syncthreads();
  int wave = tid >> 6, lane = tid & 63, half = lane >> 5, sub = lane & 31;
  int gw = blockIdx.x*4 + wave;
  int stride = gridDim.x*8;
  float b1  = bd1[sub];
  float w20 = Wd2[sub], w21 = Wd2[32 + sub], w22 = Wd2[64 + sub];
  for (int d0 = gw*2; d0 < N; d0 += stride){
    int d = d0 + half;
    if (d < N){
      float s = b1;
      const float* wr = &wd[sub*132];
      const float4* hv4 = (const float4*)&hnew[d*H];
      #pragma unroll
      for (int k = 0; k < 32; k++){
        float4 hv = hv4[k];
        float4 w = *(const float4*)&wr[k*4];
        s += hv.x*w.x + hv.y*w.y + hv.z*w.z + hv.w*w.w;
      }
      float d1 = fmaxf(s, 0.f);
      float v0 = d1*w20, v1 = d1*w21, v2 = d1*w22;
      #pragma unroll
      for (int off = 1; off < 32; off <<= 1){
        v0 += __shfl_xor(v0, off);
        v1 += __shfl_xor(v1, off);
        v2 += __shfl_xor(v2, off);
      }
      if (sub < 3) disp[d*3 + sub] = (sub == 0 ? v0 : (sub == 1 ? v1 : v2)) + bd2[sub];
    }
  }
}

// ---------------- force decoder per edge: wave per edge ----------------
__global__ __launch_bounds__(256) void k_force(
    const int* __restrict__ ei, const float* __restrict__ ea,
    const float* __restrict__ P, const float* __restrict__ Q,
    const float* __restrict__ Wf1, const float* __restrict__ bf1,
    const float* __restrict__ Wf2, const float* __restrict__ bf2,
    float* __restrict__ out, int E)
{
  int t = blockIdx.x*blockDim.x + threadIdx.x;
  int gw = t >> 6, lane = t & 63;
  int nw = (gridDim.x*blockDim.x) >> 6;
  float4 wc = *(const float4*)&Wf1[lane*260 + 256];
  float b1 = bf1[lane];
  float w0 = Wf2[lane], w1 = Wf2[64 + lane], w2 = Wf2[128 + lane];
  float bo = (lane < 3) ? bf2[lane] : 0.f;
  for (int e = gw; e < E; e += nw){
    int r0 = ei[e], c0 = ei[E + e];
    float4 a = *(const float4*)&ea[e*4];
    float hsum = P[r0*64 + lane] + Q[c0*64 + lane] + b1
               + a.x*wc.x + a.y*wc.y + a.z*wc.z + a.w*wc.w;
    float hd = fmaxf(hsum, 0.f);
    float v0 = hd*w0, v1 = hd*w1, v2 = hd*w2;
    #pragma unroll
    for (int off = 1; off < 64; off <<= 1){
      v0 += __shfl_xor(v0, off);
      v1 += __shfl_xor(v1, off);
      v2 += __shfl_xor(v2, off);
    }
    if (lane < 3) out[e*3 + lane] = (lane == 0 ? v0 : (lane == 1 ? v1 : v2)) + bo;
  }
}

extern "C" void kernel_launch(void* const* d_in, const int* in_sizes, int n_in,
                              void* d_out, int out_size, void* d_ws, size_t ws_size,
                              hipStream_t stream)
{
  const float* x   = (const float*)d_in[0];
  const int*   ei  = (const int*)d_in[1];
  const float* ea  = (const float*)d_in[2];
  const float* h   = (const float*)d_in[3];
  const float* W1l = (const float*)d_in[4];
  const float* b1l = (const float*)d_in[5];
  const float* W1r = (const float*)d_in[6];
  const float* W2l = (const float*)d_in[7];
  const float* b2l = (const float*)d_in[8];
  const float* W2r = (const float*)d_in[9];
  const float* Wih = (const float*)d_in[10];
  const float* Whh = (const float*)d_in[11];
  const float* bih = (const float*)d_in[12];
  const float* bhh = (const float*)d_in[13];
  const float* Wd1 = (const float*)d_in[14];
  const float* bd1 = (const float*)d_in[15];
  const float* Wd2 = (const float*)d_in[16];
  const float* bd2 = (const float*)d_in[17];
  const float* Wf1 = (const float*)d_in[18];
  const float* bf1 = (const float*)d_in[19];
  const float* Wf2 = (const float*)d_in[20];
  const float* bf2 = (const float*)d_in[21];

  int N = in_sizes[0] / IN_DIM;
  int E = in_sizes[1] / 2;

  char* ws = (char*)d_ws;
  size_t off = 0;
  auto alloc = [&](size_t bytes) -> char* {
    char* p = ws + off;
    off = (off + bytes + 255) & ~(size_t)255;
    return p;
  };
  int* counts  = (int*)alloc((size_t)N*4);
  int* offsets = (int*)alloc((size_t)N*4);
  int* cursor  = (int*)alloc((size_t)N*4);
  int* bsum    = (int*)alloc(1024);
  int* csr     = (int*)alloc((size_t)E*4);
  float* x1    = (float*)alloc((size_t)N*H*4);
  float* agg2  = (float*)alloc((size_t)N*H*4);
  float* x2    = (float*)alloc((size_t)N*H*4);
  // Buffer reuse (lifetimes disjoint):
  float* rbuf = x1;    // written after x1 dead (post-lin2)
  float* zbuf = agg2;  // written after agg2 dead (post-lin2)
  float* P    = x1;    // written after rbuf dead (post-gate2)
  float* Q    = agg2;  // written after zbuf dead (post-gate2)

  float* disp  = (float*)d_out;
  float* force = disp + (size_t)N*3;
  float* hnew  = force + (size_t)E*3;

  hipMemsetAsync(counts, 0, (size_t)N*4, stream);
  int nb = (N + 255) / 256;
  k_count  <<<2048, 256, 0, stream>>>(ei + E, counts, E);
  k_scanA  <<<nb, 256, 0, stream>>>(counts, offsets, bsum, N);
  k_scanB  <<<1, 256, 0, stream>>>(bsum, nb);
  k_scanC  <<<nb, 256, 0, stream>>>(offsets, cursor, bsum, N);
  k_scatter<<<2048, 256, 0, stream>>>(ei, cursor, csr, E);

  k_sage1  <<<2048, 256, 0, stream>>>(x, csr, offsets, counts, W1l, b1l, W1r, x1, N);
  k_agg2   <<<4096, 256, 0, stream>>>(x1, csr, offsets, counts, agg2, N);
  k_lin2   <<<256, 1024, 0, stream>>>(agg2, x1, W2l, b2l, W2r, x2, N);
  k_gate<0><<<256, 1024, 0, stream>>>(x2, h, Wih, Whh, bih, bhh, nullptr, nullptr, rbuf, N);
  k_gate<1><<<256, 1024, 0, stream>>>(x2, h, Wih, Whh, bih, bhh, nullptr, nullptr, zbuf, N);
  k_gate<2><<<256, 1024, 0, stream>>>(x2, h, Wih, Whh, bih, bhh, rbuf, zbuf, hnew, N);
  k_pq     <<<256, 1024, 0, stream>>>(hnew, Wf1, P, Q, N);
  k_disp   <<<1024, 256, 0, stream>>>(hnew, Wd1, bd1, Wd2, bd2, disp, N);
  k_force  <<<2048, 256, 0, stream>>>(ei, ea, P, Q, Wf1, bf1, Wf2, bf2, force, E);
}

// Round 2
// 979.375 us; speedup vs baseline: 1.2299x; 1.2299x over previous
//
#include <hip/hip_runtime.h>
#include <hip/hip_bf16.h>

#define H 128
#define IN_DIM 30

typedef __attribute__((ext_vector_type(8))) short bf16x8;
typedef __attribute__((ext_vector_type(4))) float f32x4;

__device__ inline unsigned short f2bf(float f){
  unsigned int u = __builtin_bit_cast(unsigned int, f);
  unsigned int r = u + 0x7FFF + ((u >> 16) & 1);
  return (unsigned short)(r >> 16);
}
__device__ inline float bf2f(unsigned short b){
  unsigned int u = ((unsigned int)b) << 16;
  return __builtin_bit_cast(float, u);
}
__device__ inline bf16x8 ldfrag(const unsigned short* p){
  return *(const bf16x8*)p;
}

// ---------------- CSR build ----------------
__global__ void k_count(const int* __restrict__ col, int* __restrict__ counts, int E){
  for (int e = blockIdx.x*blockDim.x + threadIdx.x; e < E; e += gridDim.x*blockDim.x)
    atomicAdd(&counts[col[e]], 1);
}

__global__ void k_scanA(const int* __restrict__ counts, int* __restrict__ offsets,
                        int* __restrict__ bsum, int n){
  __shared__ int buf[256];
  int i = blockIdx.x*256 + threadIdx.x;
  int v = (i < n) ? counts[i] : 0;
  buf[threadIdx.x] = v; __syncthreads();
  for (int off = 1; off < 256; off <<= 1){
    int t = (threadIdx.x >= off) ? buf[threadIdx.x - off] : 0;
    __syncthreads();
    buf[threadIdx.x] += t;
    __syncthreads();
  }
  if (i < n) offsets[i] = buf[threadIdx.x] - v;
  if (threadIdx.x == 255) bsum[blockIdx.x] = buf[255];
}

__global__ void k_scanB(int* __restrict__ bsum, int nb){
  __shared__ int buf[256];
  int v = (threadIdx.x < nb) ? bsum[threadIdx.x] : 0;
  buf[threadIdx.x] = v; __syncthreads();
  for (int off = 1; off < 256; off <<= 1){
    int t = (threadIdx.x >= off) ? buf[threadIdx.x - off] : 0;
    __syncthreads();
    buf[threadIdx.x] += t;
    __syncthreads();
  }
  if (threadIdx.x < nb) bsum[threadIdx.x] = buf[threadIdx.x] - v;
}

__global__ void k_scanC(int* __restrict__ offsets, int* __restrict__ cursor,
                        const int* __restrict__ bsum, int n){
  int i = blockIdx.x*256 + threadIdx.x;
  if (i < n){ int o = offsets[i] + bsum[blockIdx.x]; offsets[i] = o; cursor[i] = o; }
}

__global__ void k_scatter(const int* __restrict__ ei, int* __restrict__ cursor,
                          int* __restrict__ csr, int E){
  for (int e = blockIdx.x*blockDim.x + threadIdx.x; e < E; e += gridDim.x*blockDim.x){
    int c = ei[E + e];
    int p = atomicAdd(&cursor[c], 1);
    csr[p] = ei[e];
  }
}

// ---------------- weight conversion to bf16 ----------------
__global__ void k_wconv(const float* __restrict__ W2l, const float* __restrict__ W2r,
                        const float* __restrict__ Wih, const float* __restrict__ Whh,
                        const float* __restrict__ Wf1,
                        unsigned short* __restrict__ W2l_bf, unsigned short* __restrict__ W2r_bf,
                        unsigned short* __restrict__ Wih_bf, unsigned short* __restrict__ Whh_bf,
                        unsigned short* __restrict__ V_bf){
  int stride = gridDim.x*blockDim.x;
  for (int i = blockIdx.x*blockDim.x + threadIdx.x; i < 49152; i += stride){
    if (i < 16384){
      W2l_bf[i] = f2bf(W2l[i]);
      W2r_bf[i] = f2bf(W2r[i]);
      int j = i >> 7, k = i & 127;
      V_bf[i] = f2bf(j < 64 ? Wf1[j*260 + k] : Wf1[(j-64)*260 + 128 + k]);
    }
    Wih_bf[i] = f2bf(Wih[i]);
    Whh_bf[i] = f2bf(Whh[i]);
  }
}

// ---------------- h f32 -> bf16 ----------------
__global__ void k_hconv(const float* __restrict__ h, unsigned short* __restrict__ hbf, int total4){
  int stride = gridDim.x*blockDim.x;
  for (int i = blockIdx.x*blockDim.x + threadIdx.x; i < total4; i += stride){
    float4 v = ((const float4*)h)[i];
    ushort4 o; o.x = f2bf(v.x); o.y = f2bf(v.y); o.z = f2bf(v.z); o.w = f2bf(v.w);
    ((ushort4*)hbf)[i] = o;
  }
}

// ---------------- aggx: mean of x (30-dim) rows; 2 edges per wave ----------------
__global__ __launch_bounds__(256) void k_aggx(
    const float* __restrict__ x, const int* __restrict__ csr,
    const int* __restrict__ offsets, const int* __restrict__ counts,
    float* __restrict__ aggx, int N)
{
  int t = blockIdx.x*blockDim.x + threadIdx.x;
  int gw = t >> 6, lane = t & 63;
  int nw = (gridDim.x*blockDim.x) >> 6;
  int half = lane >> 5, c = lane & 31;
  bool act = (c < IN_DIM);
  for (int d = gw; d < N; d += nw){
    int base = offsets[d], cnt = counts[d];
    float s = 0.f;
    for (int i = half; i < cnt; i += 2){
      int sr = csr[base + i];
      if (act) s += x[(size_t)sr*IN_DIM + c];
    }
    s += __shfl_xor(s, 32);
    if (lane < 32){
      float inv = 1.f / (float)(cnt > 0 ? cnt : 1);
      aggx[d*32 + c] = act ? s*inv : 0.f;
    }
  }
}

// ---------------- lin1: x1 = relu(aggx@W1l.T + b1l + x@W1r.T) -> bf16 ----------------
__global__ __launch_bounds__(256) void k_lin1(
    const float* __restrict__ aggx, const float* __restrict__ x,
    const float* __restrict__ W1l, const float* __restrict__ b1l,
    const float* __restrict__ W1r, unsigned short* __restrict__ x1bf, int N)
{
  int tid = threadIdx.x;
  int slot = tid >> 7, c = tid & 127;
  float wl[IN_DIM], wr[IN_DIM];
  #pragma unroll
  for (int k = 0; k < IN_DIM; k++){ wl[k] = W1l[c*IN_DIM + k]; wr[k] = W1r[c*IN_DIM + k]; }
  float bc = b1l[c];
  for (int d0 = blockIdx.x*2; d0 < N; d0 += gridDim.x*2){
    int d = d0 + slot;
    if (d >= N) continue;
    float s = bc;
    const float* ag = &aggx[d*32];
    const float* xd = &x[(size_t)d*IN_DIM];
    #pragma unroll
    for (int k = 0; k < IN_DIM; k++) s += ag[k]*wl[k] + xd[k]*wr[k];
    x1bf[(size_t)d*H + c] = f2bf(fmaxf(s, 0.f));
  }
}

// ---------------- agg2: mean of bf16 x1 rows; wave per node, 2 dims/lane ----------------
__global__ __launch_bounds__(256) void k_agg2(
    const unsigned short* __restrict__ x1bf, const int* __restrict__ csr,
    const int* __restrict__ offsets, const int* __restrict__ counts,
    unsigned short* __restrict__ agg2bf, int N)
{
  int t = blockIdx.x*blockDim.x + threadIdx.x;
  int gw = t >> 6, lane = t & 63;
  int nw = (gridDim.x*blockDim.x) >> 6;
  const unsigned int* x1u = (const unsigned int*)x1bf;
  unsigned int* agu = (unsigned int*)agg2bf;
  for (int d = gw; d < N; d += nw){
    int base = offsets[d], cnt = counts[d];
    float a0 = 0.f, a1 = 0.f;
    for (int i = 0; i < cnt; i++){
      int s = csr[base + i];
      unsigned int v = x1u[(size_t)s*64 + lane];
      a0 += bf2f((unsigned short)(v & 0xffff));
      a1 += bf2f((unsigned short)(v >> 16));
    }
    float inv = 1.f / (float)(cnt > 0 ? cnt : 1);
    unsigned int o = (unsigned int)f2bf(a0*inv) | ((unsigned int)f2bf(a1*inv) << 16);
    agu[(size_t)d*64 + lane] = o;
  }
}

// ---------------- dual MFMA: out = relu(A@Wa.T + bias + B@Wb.T) -> bf16 ----------------
__global__ __launch_bounds__(256) void k_mfma_dual(
    const unsigned short* __restrict__ Abf, const unsigned short* __restrict__ Bbf,
    const unsigned short* __restrict__ Wa, const unsigned short* __restrict__ Wb,
    const float* __restrict__ bias, unsigned short* __restrict__ outbf, int N)
{
  int nt = (N + 15) >> 4;
  int l = threadIdx.x & 63;
  int m16 = l & 15, g4 = l >> 4;
  for (int t = blockIdx.x*4 + (threadIdx.x >> 6); t < nt; t += gridDim.x*4){
    int row0 = t << 4;
    int rml = min(row0 + m16, N-1);
    bf16x8 aA[4], aB[4];
    #pragma unroll
    for (int kb = 0; kb < 4; kb++){
      aA[kb] = ldfrag(Abf + (size_t)rml*H + kb*32 + g4*8);
      aB[kb] = ldfrag(Bbf + (size_t)rml*H + kb*32 + g4*8);
    }
    #pragma unroll
    for (int ct = 0; ct < 8; ct++){
      int c0 = ct*16;
      float bv = bias[c0 + m16];
      f32x4 acc = {bv, bv, bv, bv};
      #pragma unroll
      for (int kb = 0; kb < 4; kb++){
        bf16x8 wa = ldfrag(Wa + (size_t)(c0 + m16)*H + kb*32 + g4*8);
        acc = __builtin_amdgcn_mfma_f32_16x16x32_bf16(aA[kb], wa, acc, 0, 0, 0);
        bf16x8 wb = ldfrag(Wb + (size_t)(c0 + m16)*H + kb*32 + g4*8);
        acc = __builtin_amdgcn_mfma_f32_16x16x32_bf16(aB[kb], wb, acc, 0, 0, 0);
      }
      #pragma unroll
      for (int j = 0; j < 4; j++){
        int row = row0 + g4*4 + j;
        if (row < N)
          outbf[(size_t)row*H + c0 + m16] = f2bf(fmaxf(acc[j], 0.f));
      }
    }
  }
}

// ---------------- fused GRU via MFMA ----------------
__global__ __launch_bounds__(256) void k_gru(
    const unsigned short* __restrict__ x2bf, const unsigned short* __restrict__ hbf,
    const float* __restrict__ h,
    const unsigned short* __restrict__ Wih_bf, const unsigned short* __restrict__ Whh_bf,
    const float* __restrict__ bih, const float* __restrict__ bhh,
    float* __restrict__ hnew, unsigned short* __restrict__ hnewbf, int N)
{
  int nt = (N + 15) >> 4;
  int l = threadIdx.x & 63;
  int m16 = l & 15, g4 = l >> 4;
  for (int t = blockIdx.x*4 + (threadIdx.x >> 6); t < nt; t += gridDim.x*4){
    int row0 = t << 4;
    int rml = min(row0 + m16, N-1);
    bf16x8 aX[4], aH[4];
    #pragma unroll
    for (int kb = 0; kb < 4; kb++){
      aX[kb] = ldfrag(x2bf + (size_t)rml*H + kb*32 + g4*8);
      aH[kb] = ldfrag(hbf  + (size_t)rml*H + kb*32 + g4*8);
    }
    #pragma unroll
    for (int ct = 0; ct < 8; ct++){
      int c0 = ct*16, col = c0 + m16;
      float bir = bih[col],      bhr = bhh[col];
      float biz = bih[H + col],  bhz = bhh[H + col];
      float bin = bih[2*H + col], bhn = bhh[2*H + col];
      f32x4 aRi = {bir,bir,bir,bir}, aRh = {bhr,bhr,bhr,bhr};
      f32x4 aZi = {biz,biz,biz,biz}, aZh = {bhz,bhz,bhz,bhz};
      f32x4 aNi = {bin,bin,bin,bin}, aNh = {bhn,bhn,bhn,bhn};
      #pragma unroll
      for (int kb = 0; kb < 4; kb++){
        int ko = kb*32 + g4*8;
        aRi = __builtin_amdgcn_mfma_f32_16x16x32_bf16(aX[kb], ldfrag(Wih_bf + (size_t)(col)*H + ko),       aRi, 0,0,0);
        aRh = __builtin_amdgcn_mfma_f32_16x16x32_bf16(aH[kb], ldfrag(Whh_bf + (size_t)(col)*H + ko),       aRh, 0,0,0);
        aZi = __builtin_amdgcn_mfma_f32_16x16x32_bf16(aX[kb], ldfrag(Wih_bf + (size_t)(H + col)*H + ko),   aZi, 0,0,0);
        aZh = __builtin_amdgcn_mfma_f32_16x16x32_bf16(aH[kb], ldfrag(Whh_bf + (size_t)(H + col)*H + ko),   aZh, 0,0,0);
        aNi = __builtin_amdgcn_mfma_f32_16x16x32_bf16(aX[kb], ldfrag(Wih_bf + (size_t)(2*H + col)*H + ko), aNi, 0,0,0);
        aNh = __builtin_amdgcn_mfma_f32_16x16x32_bf16(aH[kb], ldfrag(Whh_bf + (size_t)(2*H + col)*H + ko), aNh, 0,0,0);
      }
      #pragma unroll
      for (int j = 0; j < 4; j++){
        int row = row0 + g4*4 + j;
        if (row < N){
          float r = 1.f / (1.f + expf(-(aRi[j] + aRh[j])));
          float z = 1.f / (1.f + expf(-(aZi[j] + aZh[j])));
          float nn = tanhf(aNi[j] + r*aNh[j]);
          float hv = h[(size_t)row*H + col];
          float o = (1.f - z)*nn + z*hv;
          hnew[(size_t)row*H + col] = o;
          hnewbf[(size_t)row*H + col] = f2bf(o);
        }
      }
    }
  }
}

// ---------------- PQ = hnew @ V.T (f32 out, no bias) ----------------
__global__ __launch_bounds__(256) void k_pq(
    const unsigned short* __restrict__ hnewbf, const unsigned short* __restrict__ V_bf,
    float* __restrict__ PQ, int N)
{
  int nt = (N + 15) >> 4;
  int l = threadIdx.x & 63;
  int m16 = l & 15, g4 = l >> 4;
  for (int t = blockIdx.x*4 + (threadIdx.x >> 6); t < nt; t += gridDim.x*4){
    int row0 = t << 4;
    int rml = min(row0 + m16, N-1);
    bf16x8 aH[4];
    #pragma unroll
    for (int kb = 0; kb < 4; kb++)
      aH[kb] = ldfrag(hnewbf + (size_t)rml*H + kb*32 + g4*8);
    #pragma unroll
    for (int ct = 0; ct < 8; ct++){
      int c0 = ct*16;
      f32x4 acc = {0.f, 0.f, 0.f, 0.f};
      #pragma unroll
      for (int kb = 0; kb < 4; kb++){
        bf16x8 w = ldfrag(V_bf + (size_t)(c0 + m16)*H + kb*32 + g4*8);
        acc = __builtin_amdgcn_mfma_f32_16x16x32_bf16(aH[kb], w, acc, 0, 0, 0);
      }
      #pragma unroll
      for (int j = 0; j < 4; j++){
        int row = row0 + g4*4 + j;
        if (row < N)
          PQ[(size_t)row*H + c0 + m16] = acc[j];
      }
    }
  }
}

// ---------------- disp decoder ----------------
__global__ __launch_bounds__(256) void k_disp(
    const float* __restrict__ hnew, const float* __restrict__ Wd1,
    const float* __restrict__ bd1, const float* __restrict__ Wd2,
    const float* __restrict__ bd2, float* __restrict__ disp, int N)
{
  __shared__ __align__(16) float wd[32*132];
  int tid = threadIdx.x;
  for (int i = tid; i < 32*128; i += 256){
    int j = i >> 7, k = i & 127;
    wd[j*132 + k] = Wd1[i];
  }
  __syncthreads();
  int wave = tid >> 6, lane = tid & 63, half = lane >> 5, sub = lane & 31;
  int gw = blockIdx.x*4 + wave;
  int stride = gridDim.x*8;
  float b1  = bd1[sub];
  float w20 = Wd2[sub], w21 = Wd2[32 + sub], w22 = Wd2[64 + sub];
  for (int d0 = gw*2; d0 < N; d0 += stride){
    int d = d0 + half;
    if (d < N){
      float s = b1;
      const float* wr = &wd[sub*132];
      const float4* hv4 = (const float4*)&hnew[(size_t)d*H];
      #pragma unroll
      for (int k = 0; k < 32; k++){
        float4 hv = hv4[k];
        float4 w = *(const float4*)&wr[k*4];
        s += hv.x*w.x + hv.y*w.y + hv.z*w.z + hv.w*w.w;
      }
      float d1 = fmaxf(s, 0.f);
      float v0 = d1*w20, v1 = d1*w21, v2 = d1*w22;
      #pragma unroll
      for (int off = 1; off < 32; off <<= 1){
        v0 += __shfl_xor(v0, off);
        v1 += __shfl_xor(v1, off);
        v2 += __shfl_xor(v2, off);
      }
      if (sub < 3) disp[(size_t)d*3 + sub] = (sub == 0 ? v0 : (sub == 1 ? v1 : v2)) + bd2[sub];
    }
  }
}

// ---------------- force decoder per edge ----------------
__global__ __launch_bounds__(256) void k_force(
    const int* __restrict__ ei, const float* __restrict__ ea,
    const float* __restrict__ PQ,
    const float* __restrict__ Wf1, const float* __restrict__ bf1,
    const float* __restrict__ Wf2, const float* __restrict__ bf2,
    float* __restrict__ out, int E)
{
  int t = blockIdx.x*blockDim.x + threadIdx.x;
  int gw = t >> 6, lane = t & 63;
  int nw = (gridDim.x*blockDim.x) >> 6;
  float4 wc = *(const float4*)&Wf1[lane*260 + 256];
  float b1 = bf1[lane];
  float w0 = Wf2[lane], w1 = Wf2[64 + lane], w2 = Wf2[128 + lane];
  float bo = (lane < 3) ? bf2[lane] : 0.f;
  for (int e = gw; e < E; e += nw){
    int r0 = ei[e], c0 = ei[E + e];
    float4 a = *(const float4*)&ea[(size_t)e*4];
    float hsum = PQ[(size_t)r0*H + lane] + PQ[(size_t)c0*H + 64 + lane] + b1
               + a.x*wc.x + a.y*wc.y + a.z*wc.z + a.w*wc.w;
    float hd = fmaxf(hsum, 0.f);
    float v0 = hd*w0, v1 = hd*w1, v2 = hd*w2;
    #pragma unroll
    for (int off = 1; off < 64; off <<= 1){
      v0 += __shfl_xor(v0, off);
      v1 += __shfl_xor(v1, off);
      v2 += __shfl_xor(v2, off);
    }
    if (lane < 3) out[(size_t)e*3 + lane] = (lane == 0 ? v0 : (lane == 1 ? v1 : v2)) + bo;
  }
}

extern "C" void kernel_launch(void* const* d_in, const int* in_sizes, int n_in,
                              void* d_out, int out_size, void* d_ws, size_t ws_size,
                              hipStream_t stream)
{
  const float* x   = (const float*)d_in[0];
  const int*   ei  = (const int*)d_in[1];
  const float* ea  = (const float*)d_in[2];
  const float* h   = (const float*)d_in[3];
  const float* W1l = (const float*)d_in[4];
  const float* b1l = (const float*)d_in[5];
  const float* W1r = (const float*)d_in[6];
  const float* W2l = (const float*)d_in[7];
  const float* b2l = (const float*)d_in[8];
  const float* W2r = (const float*)d_in[9];
  const float* Wih = (const float*)d_in[10];
  const float* Whh = (const float*)d_in[11];
  const float* bih = (const float*)d_in[12];
  const float* bhh = (const float*)d_in[13];
  const float* Wd1 = (const float*)d_in[14];
  const float* bd1 = (const float*)d_in[15];
  const float* Wd2 = (const float*)d_in[16];
  const float* bd2 = (const float*)d_in[17];
  const float* Wf1 = (const float*)d_in[18];
  const float* bf1 = (const float*)d_in[19];
  const float* Wf2 = (const float*)d_in[20];
  const float* bf2 = (const float*)d_in[21];

  int N = in_sizes[0] / IN_DIM;
  int E = in_sizes[1] / 2;

  char* ws = (char*)d_ws;
  size_t off = 0;
  auto alloc = [&](size_t bytes) -> char* {
    char* p = ws + off;
    off = (off + bytes + 255) & ~(size_t)255;
    return p;
  };
  int* counts  = (int*)alloc((size_t)N*4);
  int* offsets = (int*)alloc((size_t)N*4);
  int* cursor  = (int*)alloc((size_t)N*4);
  int* bsum    = (int*)alloc(1024);
  int* csr     = (int*)alloc((size_t)E*4);
  // pool1 (aliased by PQ after lin2): aggx | x1bf | agg2bf  (32 MB >= 25.6 MB)
  float* aggx            = (float*)alloc((size_t)N*32*4);
  unsigned short* x1bf   = (unsigned short*)alloc((size_t)N*H*2);
  unsigned short* agg2bf = (unsigned short*)alloc((size_t)N*H*2);
  float* PQ = (float*)aggx;  // alias: written by k_pq after aggx/x1bf/agg2bf dead
  unsigned short* x2bf   = (unsigned short*)alloc((size_t)N*H*2);
  unsigned short* hbf    = (unsigned short*)alloc((size_t)N*H*2);
  unsigned short* hnewbf = (unsigned short*)alloc((size_t)N*H*2);
  unsigned short* W2l_bf = (unsigned short*)alloc(16384*2);
  unsigned short* W2r_bf = (unsigned short*)alloc(16384*2);
  unsigned short* Wih_bf = (unsigned short*)alloc(49152*2);
  unsigned short* Whh_bf = (unsigned short*)alloc(49152*2);
  unsigned short* V_bf   = (unsigned short*)alloc(16384*2);

  float* disp  = (float*)d_out;
  float* force = disp + (size_t)N*3;
  float* hnew  = force + (size_t)E*3;

  hipMemsetAsync(counts, 0, (size_t)N*4, stream);
  int nb = (N + 255) / 256;
  k_count  <<<2048, 256, 0, stream>>>(ei + E, counts, E);
  k_scanA  <<<nb, 256, 0, stream>>>(counts, offsets, bsum, N);
  k_scanB  <<<1, 256, 0, stream>>>(bsum, nb);
  k_scanC  <<<nb, 256, 0, stream>>>(offsets, cursor, bsum, N);
  k_scatter<<<2048, 256, 0, stream>>>(ei, cursor, csr, E);

  k_wconv  <<<192, 256, 0, stream>>>(W2l, W2r, Wih, Whh, Wf1,
                                     W2l_bf, W2r_bf, Wih_bf, Whh_bf, V_bf);
  k_hconv  <<<2048, 256, 0, stream>>>(h, hbf, N*32);

  k_aggx   <<<4096, 256, 0, stream>>>(x, csr, offsets, counts, aggx, N);
  k_lin1   <<<2048, 256, 0, stream>>>(aggx, x, W1l, b1l, W1r, x1bf, N);
  k_agg2   <<<4096, 256, 0, stream>>>(x1bf, csr, offsets, counts, agg2bf, N);
  k_mfma_dual<<<784, 256, 0, stream>>>(agg2bf, x1bf, W2l_bf, W2r_bf, b2l, x2bf, N);
  k_gru    <<<784, 256, 0, stream>>>(x2bf, hbf, h, Wih_bf, Whh_bf, bih, bhh, hnew, hnewbf, N);
  k_pq     <<<784, 256, 0, stream>>>(hnewbf, V_bf, PQ, N);
  k_disp   <<<1024, 256, 0, stream>>>(hnew, Wd1, bd1, Wd2, bd2, disp, N);
  k_force  <<<2048, 256, 0, stream>>>(ei, ea, PQ, Wf1, bf1, Wf2, bf2, force, E);
}

// Round 3
// 659.741 us; speedup vs baseline: 1.8258x; 1.4845x over previous
//
#include <hip/hip_runtime.h>
#include <hip/hip_bf16.h>

#define H 128
#define IN_DIM 30

typedef __attribute__((ext_vector_type(8))) short bf16x8;
typedef __attribute__((ext_vector_type(4))) float f32x4;

__device__ inline unsigned short f2bf(float f){
  unsigned int u = __builtin_bit_cast(unsigned int, f);
  unsigned int r = u + 0x7FFF + ((u >> 16) & 1);
  return (unsigned short)(r >> 16);
}
__device__ inline float bf2f(unsigned short b){
  unsigned int u = ((unsigned int)b) << 16;
  return __builtin_bit_cast(float, u);
}
__device__ inline bf16x8 ldfrag(const unsigned short* p){
  return *(const bf16x8*)p;
}

// ---------------- CSR build ----------------
__global__ void k_count(const int* __restrict__ col, int* __restrict__ counts, int E){
  for (int e = blockIdx.x*blockDim.x + threadIdx.x; e < E; e += gridDim.x*blockDim.x)
    atomicAdd(&counts[col[e]], 1);
}

__global__ void k_scanA(const int* __restrict__ counts, int* __restrict__ offsets,
                        int* __restrict__ bsum, int n){
  __shared__ int buf[256];
  int i = blockIdx.x*256 + threadIdx.x;
  int v = (i < n) ? counts[i] : 0;
  buf[threadIdx.x] = v; __syncthreads();
  for (int off = 1; off < 256; off <<= 1){
    int t = (threadIdx.x >= off) ? buf[threadIdx.x - off] : 0;
    __syncthreads();
    buf[threadIdx.x] += t;
    __syncthreads();
  }
  if (i < n) offsets[i] = buf[threadIdx.x] - v;
  if (threadIdx.x == 255) bsum[blockIdx.x] = buf[255];
}

__global__ void k_scanB(int* __restrict__ bsum, int nb){
  __shared__ int buf[256];
  int v = (threadIdx.x < nb) ? bsum[threadIdx.x] : 0;
  buf[threadIdx.x] = v; __syncthreads();
  for (int off = 1; off < 256; off <<= 1){
    int t = (threadIdx.x >= off) ? buf[threadIdx.x - off] : 0;
    __syncthreads();
    buf[threadIdx.x] += t;
    __syncthreads();
  }
  if (threadIdx.x < nb) bsum[threadIdx.x] = buf[threadIdx.x] - v;
}

__global__ void k_scanC(int* __restrict__ offsets, int* __restrict__ cursor,
                        const int* __restrict__ bsum, int n){
  int i = blockIdx.x*256 + threadIdx.x;
  if (i < n){ int o = offsets[i] + bsum[blockIdx.x]; offsets[i] = o; cursor[i] = o; }
}

__global__ void k_scatter(const int* __restrict__ ei, int* __restrict__ cursor,
                          int* __restrict__ csr, int E){
  for (int e = blockIdx.x*blockDim.x + threadIdx.x; e < E; e += gridDim.x*blockDim.x){
    int c = ei[E + e];
    int p = atomicAdd(&cursor[c], 1);
    csr[p] = ei[e];
  }
}

// ---------------- weight conversion to bf16 ----------------
__global__ void k_wconv(const float* __restrict__ W2l, const float* __restrict__ W2r,
                        const float* __restrict__ Wih, const float* __restrict__ Whh,
                        const float* __restrict__ Wf1,
                        unsigned short* __restrict__ W2l_bf, unsigned short* __restrict__ W2r_bf,
                        unsigned short* __restrict__ Wih_bf, unsigned short* __restrict__ Whh_bf,
                        unsigned short* __restrict__ V_bf){
  int stride = gridDim.x*blockDim.x;
  for (int i = blockIdx.x*blockDim.x + threadIdx.x; i < 49152; i += stride){
    if (i < 16384){
      W2l_bf[i] = f2bf(W2l[i]);
      W2r_bf[i] = f2bf(W2r[i]);
      int j = i >> 7, k = i & 127;
      V_bf[i] = f2bf(j < 64 ? Wf1[j*260 + k] : Wf1[(j-64)*260 + 128 + k]);
    }
    Wih_bf[i] = f2bf(Wih[i]);
    Whh_bf[i] = f2bf(Whh[i]);
  }
}

// ---------------- h f32 -> bf16 ----------------
__global__ void k_hconv(const float* __restrict__ h, unsigned short* __restrict__ hbf, int total4){
  int stride = gridDim.x*blockDim.x;
  for (int i = blockIdx.x*blockDim.x + threadIdx.x; i < total4; i += stride){
    float4 v = ((const float4*)h)[i];
    ushort4 o; o.x = f2bf(v.x); o.y = f2bf(v.y); o.z = f2bf(v.z); o.w = f2bf(v.w);
    ((ushort4*)hbf)[i] = o;
  }
}

// ---------------- aggx: mean of x (30-dim) rows; 2 edges per wave ----------------
__global__ __launch_bounds__(256) void k_aggx(
    const float* __restrict__ x, const int* __restrict__ csr,
    const int* __restrict__ offsets, const int* __restrict__ counts,
    float* __restrict__ aggx, int N)
{
  int t = blockIdx.x*blockDim.x + threadIdx.x;
  int gw = t >> 6, lane = t & 63;
  int nw = (gridDim.x*blockDim.x) >> 6;
  int half = lane >> 5, c = lane & 31;
  bool act = (c < IN_DIM);
  for (int d = gw; d < N; d += nw){
    int base = offsets[d], cnt = counts[d];
    float s = 0.f;
    for (int i = half; i < cnt; i += 2){
      int sr = csr[base + i];
      if (act) s += x[(size_t)sr*IN_DIM + c];
    }
    s += __shfl_xor(s, 32);
    if (lane < 32){
      float inv = 1.f / (float)(cnt > 0 ? cnt : 1);
      aggx[d*32 + c] = act ? s*inv : 0.f;
    }
  }
}

// ---------------- lin1: x1 = relu(aggx@W1l.T + b1l + x@W1r.T) -> bf16 ----------------
__global__ __launch_bounds__(256) void k_lin1(
    const float* __restrict__ aggx, const float* __restrict__ x,
    const float* __restrict__ W1l, const float* __restrict__ b1l,
    const float* __restrict__ W1r, unsigned short* __restrict__ x1bf, int N)
{
  int tid = threadIdx.x;
  int slot = tid >> 7, c = tid & 127;
  float wl[IN_DIM], wr[IN_DIM];
  #pragma unroll
  for (int k = 0; k < IN_DIM; k++){ wl[k] = W1l[c*IN_DIM + k]; wr[k] = W1r[c*IN_DIM + k]; }
  float bc = b1l[c];
  for (int d0 = blockIdx.x*2; d0 < N; d0 += gridDim.x*2){
    int d = d0 + slot;
    if (d >= N) continue;
    float s = bc;
    const float* ag = &aggx[d*32];
    const float* xd = &x[(size_t)d*IN_DIM];
    #pragma unroll
    for (int k = 0; k < IN_DIM; k++) s += ag[k]*wl[k] + xd[k]*wr[k];
    x1bf[(size_t)d*H + c] = f2bf(fmaxf(s, 0.f));
  }
}

// ---------------- agg2: mean of bf16 x1 rows; wave per node, 2 dims/lane ----------------
__global__ __launch_bounds__(256) void k_agg2(
    const unsigned short* __restrict__ x1bf, const int* __restrict__ csr,
    const int* __restrict__ offsets, const int* __restrict__ counts,
    unsigned short* __restrict__ agg2bf, int N)
{
  int t = blockIdx.x*blockDim.x + threadIdx.x;
  int gw = t >> 6, lane = t & 63;
  int nw = (gridDim.x*blockDim.x) >> 6;
  const unsigned int* x1u = (const unsigned int*)x1bf;
  unsigned int* agu = (unsigned int*)agg2bf;
  for (int d = gw; d < N; d += nw){
    int base = offsets[d], cnt = counts[d];
    float a0 = 0.f, a1 = 0.f;
    for (int i = 0; i < cnt; i++){
      int s = csr[base + i];
      unsigned int v = x1u[(size_t)s*64 + lane];
      a0 += bf2f((unsigned short)(v & 0xffff));
      a1 += bf2f((unsigned short)(v >> 16));
    }
    float inv = 1.f / (float)(cnt > 0 ? cnt : 1);
    unsigned int o = (unsigned int)f2bf(a0*inv) | ((unsigned int)f2bf(a1*inv) << 16);
    agu[(size_t)d*64 + lane] = o;
  }
}

// ---------------- dual MFMA: out = relu(A@Wa.T + bias + B@Wb.T) -> bf16 ----------------
__global__ __launch_bounds__(256) void k_mfma_dual(
    const unsigned short* __restrict__ Abf, const unsigned short* __restrict__ Bbf,
    const unsigned short* __restrict__ Wa, const unsigned short* __restrict__ Wb,
    const float* __restrict__ bias, unsigned short* __restrict__ outbf, int N)
{
  int nt = (N + 15) >> 4;
  int l = threadIdx.x & 63;
  int m16 = l & 15, g4 = l >> 4;
  for (int t = blockIdx.x*4 + (threadIdx.x >> 6); t < nt; t += gridDim.x*4){
    int row0 = t << 4;
    int rml = min(row0 + m16, N-1);
    bf16x8 aA[4], aB[4];
    #pragma unroll
    for (int kb = 0; kb < 4; kb++){
      aA[kb] = ldfrag(Abf + (size_t)rml*H + kb*32 + g4*8);
      aB[kb] = ldfrag(Bbf + (size_t)rml*H + kb*32 + g4*8);
    }
    #pragma unroll 1
    for (int ct = 0; ct < 8; ct++){
      int c0 = ct*16;
      float bv = bias[c0 + m16];
      f32x4 acc = {bv, bv, bv, bv};
      #pragma unroll
      for (int kb = 0; kb < 4; kb++){
        bf16x8 wa = ldfrag(Wa + (size_t)(c0 + m16)*H + kb*32 + g4*8);
        acc = __builtin_amdgcn_mfma_f32_16x16x32_bf16(aA[kb], wa, acc, 0, 0, 0);
        bf16x8 wb = ldfrag(Wb + (size_t)(c0 + m16)*H + kb*32 + g4*8);
        acc = __builtin_amdgcn_mfma_f32_16x16x32_bf16(aB[kb], wb, acc, 0, 0, 0);
      }
      #pragma unroll
      for (int j = 0; j < 4; j++){
        int row = row0 + g4*4 + j;
        if (row < N)
          outbf[(size_t)row*H + c0 + m16] = f2bf(fmaxf(acc[j], 0.f));
      }
    }
  }
}

// ---------------- fused GRU via MFMA ----------------
__global__ __launch_bounds__(256) void k_gru(
    const unsigned short* __restrict__ x2bf, const unsigned short* __restrict__ hbf,
    const float* __restrict__ h,
    const unsigned short* __restrict__ Wih_bf, const unsigned short* __restrict__ Whh_bf,
    const float* __restrict__ bih, const float* __restrict__ bhh,
    float* __restrict__ hnew, unsigned short* __restrict__ hnewbf, int N)
{
  int nt = (N + 15) >> 4;
  int l = threadIdx.x & 63;
  int m16 = l & 15, g4 = l >> 4;
  for (int t = blockIdx.x*4 + (threadIdx.x >> 6); t < nt; t += gridDim.x*4){
    int row0 = t << 4;
    int rml = min(row0 + m16, N-1);
    bf16x8 aX[4], aH[4];
    #pragma unroll
    for (int kb = 0; kb < 4; kb++){
      aX[kb] = ldfrag(x2bf + (size_t)rml*H + kb*32 + g4*8);
      aH[kb] = ldfrag(hbf  + (size_t)rml*H + kb*32 + g4*8);
    }
    #pragma unroll 1
    for (int ct = 0; ct < 8; ct++){
      int c0 = ct*16, col = c0 + m16;
      float bir = bih[col],      bhr = bhh[col];
      float biz = bih[H + col],  bhz = bhh[H + col];
      float bin = bih[2*H + col], bhn = bhh[2*H + col];
      f32x4 aRi = {bir,bir,bir,bir}, aRh = {bhr,bhr,bhr,bhr};
      f32x4 aZi = {biz,biz,biz,biz}, aZh = {bhz,bhz,bhz,bhz};
      f32x4 aNi = {bin,bin,bin,bin}, aNh = {bhn,bhn,bhn,bhn};
      #pragma unroll
      for (int kb = 0; kb < 4; kb++){
        int ko = kb*32 + g4*8;
        aRi = __builtin_amdgcn_mfma_f32_16x16x32_bf16(aX[kb], ldfrag(Wih_bf + (size_t)(col)*H + ko),       aRi, 0,0,0);
        aRh = __builtin_amdgcn_mfma_f32_16x16x32_bf16(aH[kb], ldfrag(Whh_bf + (size_t)(col)*H + ko),       aRh, 0,0,0);
        aZi = __builtin_amdgcn_mfma_f32_16x16x32_bf16(aX[kb], ldfrag(Wih_bf + (size_t)(H + col)*H + ko),   aZi, 0,0,0);
        aZh = __builtin_amdgcn_mfma_f32_16x16x32_bf16(aH[kb], ldfrag(Whh_bf + (size_t)(H + col)*H + ko),   aZh, 0,0,0);
        aNi = __builtin_amdgcn_mfma_f32_16x16x32_bf16(aX[kb], ldfrag(Wih_bf + (size_t)(2*H + col)*H + ko), aNi, 0,0,0);
        aNh = __builtin_amdgcn_mfma_f32_16x16x32_bf16(aH[kb], ldfrag(Whh_bf + (size_t)(2*H + col)*H + ko), aNh, 0,0,0);
      }
      #pragma unroll
      for (int j = 0; j < 4; j++){
        int row = row0 + g4*4 + j;
        if (row < N){
          float r = 1.f / (1.f + expf(-(aRi[j] + aRh[j])));
          float z = 1.f / (1.f + expf(-(aZi[j] + aZh[j])));
          float nn = tanhf(aNi[j] + r*aNh[j]);
          float hv = h[(size_t)row*H + col];
          float o = (1.f - z)*nn + z*hv;
          hnew[(size_t)row*H + col] = o;
          hnewbf[(size_t)row*H + col] = f2bf(o);
        }
      }
    }
  }
}

// ---------------- PQ = hnew @ V.T (f32 out, no bias) ----------------
__global__ __launch_bounds__(256) void k_pq(
    const unsigned short* __restrict__ hnewbf, const unsigned short* __restrict__ V_bf,
    float* __restrict__ PQ, int N)
{
  int nt = (N + 15) >> 4;
  int l = threadIdx.x & 63;
  int m16 = l & 15, g4 = l >> 4;
  for (int t = blockIdx.x*4 + (threadIdx.x >> 6); t < nt; t += gridDim.x*4){
    int row0 = t << 4;
    int rml = min(row0 + m16, N-1);
    bf16x8 aH[4];
    #pragma unroll
    for (int kb = 0; kb < 4; kb++)
      aH[kb] = ldfrag(hnewbf + (size_t)rml*H + kb*32 + g4*8);
    #pragma unroll 1
    for (int ct = 0; ct < 8; ct++){
      int c0 = ct*16;
      f32x4 acc = {0.f, 0.f, 0.f, 0.f};
      #pragma unroll
      for (int kb = 0; kb < 4; kb++){
        bf16x8 w = ldfrag(V_bf + (size_t)(c0 + m16)*H + kb*32 + g4*8);
        acc = __builtin_amdgcn_mfma_f32_16x16x32_bf16(aH[kb], w, acc, 0, 0, 0);
      }
      #pragma unroll
      for (int j = 0; j < 4; j++){
        int row = row0 + g4*4 + j;
        if (row < N)
          PQ[(size_t)row*H + c0 + m16] = acc[j];
      }
    }
  }
}

// ---------------- disp decoder ----------------
__global__ __launch_bounds__(256) void k_disp(
    const float* __restrict__ hnew, const float* __restrict__ Wd1,
    const float* __restrict__ bd1, const float* __restrict__ Wd2,
    const float* __restrict__ bd2, float* __restrict__ disp, int N)
{
  __shared__ __align__(16) float wd[32*132];
  int tid = threadIdx.x;
  for (int i = tid; i < 32*128; i += 256){
    int j = i >> 7, k = i & 127;
    wd[j*132 + k] = Wd1[i];
  }
  __syncthreads();
  int wave = tid >> 6, lane = tid & 63, half = lane >> 5, sub = lane & 31;
  int gw = blockIdx.x*4 + wave;
  int stride = gridDim.x*8;
  float b1  = bd1[sub];
  float w20 = Wd2[sub], w21 = Wd2[32 + sub], w22 = Wd2[64 + sub];
  for (int d0 = gw*2; d0 < N; d0 += stride){
    int d = d0 + half;
    if (d < N){
      float s = b1;
      const float* wr = &wd[sub*132];
      const float4* hv4 = (const float4*)&hnew[(size_t)d*H];
      #pragma unroll
      for (int k = 0; k < 32; k++){
        float4 hv = hv4[k];
        float4 w = *(const float4*)&wr[k*4];
        s += hv.x*w.x + hv.y*w.y + hv.z*w.z + hv.w*w.w;
      }
      float d1 = fmaxf(s, 0.f);
      float v0 = d1*w20, v1 = d1*w21, v2 = d1*w22;
      #pragma unroll
      for (int off = 1; off < 32; off <<= 1){
        v0 += __shfl_xor(v0, off);
        v1 += __shfl_xor(v1, off);
        v2 += __shfl_xor(v2, off);
      }
      if (sub < 3) disp[(size_t)d*3 + sub] = (sub == 0 ? v0 : (sub == 1 ? v1 : v2)) + bd2[sub];
    }
  }
}

// ---------------- force decoder per edge ----------------
__global__ __launch_bounds__(256) void k_force(
    const int* __restrict__ ei, const float* __restrict__ ea,
    const float* __restrict__ PQ,
    const float* __restrict__ Wf1, const float* __restrict__ bf1,
    const float* __restrict__ Wf2, const float* __restrict__ bf2,
    float* __restrict__ out, int E)
{
  int t = blockIdx.x*blockDim.x + threadIdx.x;
  int gw = t >> 6, lane = t & 63;
  int nw = (gridDim.x*blockDim.x) >> 6;
  float4 wc = *(const float4*)&Wf1[lane*260 + 256];
  float b1 = bf1[lane];
  float w0 = Wf2[lane], w1 = Wf2[64 + lane], w2 = Wf2[128 + lane];
  float bo = (lane < 3) ? bf2[lane] : 0.f;
  for (int e = gw; e < E; e += nw){
    int r0 = ei[e], c0 = ei[E + e];
    float4 a = *(const float4*)&ea[(size_t)e*4];
    float hsum = PQ[(size_t)r0*H + lane] + PQ[(size_t)c0*H + 64 + lane] + b1
               + a.x*wc.x + a.y*wc.y + a.z*wc.z + a.w*wc.w;
    float hd = fmaxf(hsum, 0.f);
    float v0 = hd*w0, v1 = hd*w1, v2 = hd*w2;
    #pragma unroll
    for (int off = 1; off < 64; off <<= 1){
      v0 += __shfl_xor(v0, off);
      v1 += __shfl_xor(v1, off);
      v2 += __shfl_xor(v2, off);
    }
    if (lane < 3) out[(size_t)e*3 + lane] = (lane == 0 ? v0 : (lane == 1 ? v1 : v2)) + bo;
  }
}

extern "C" void kernel_launch(void* const* d_in, const int* in_sizes, int n_in,
                              void* d_out, int out_size, void* d_ws, size_t ws_size,
                              hipStream_t stream)
{
  const float* x   = (const float*)d_in[0];
  const int*   ei  = (const int*)d_in[1];
  const float* ea  = (const float*)d_in[2];
  const float* h   = (const float*)d_in[3];
  const float* W1l = (const float*)d_in[4];
  const float* b1l = (const float*)d_in[5];
  const float* W1r = (const float*)d_in[6];
  const float* W2l = (const float*)d_in[7];
  const float* b2l = (const float*)d_in[8];
  const float* W2r = (const float*)d_in[9];
  const float* Wih = (const float*)d_in[10];
  const float* Whh = (const float*)d_in[11];
  const float* bih = (const float*)d_in[12];
  const float* bhh = (const float*)d_in[13];
  const float* Wd1 = (const float*)d_in[14];
  const float* bd1 = (const float*)d_in[15];
  const float* Wd2 = (const float*)d_in[16];
  const float* bd2 = (const float*)d_in[17];
  const float* Wf1 = (const float*)d_in[18];
  const float* bf1 = (const float*)d_in[19];
  const float* Wf2 = (const float*)d_in[20];
  const float* bf2 = (const float*)d_in[21];

  int N = in_sizes[0] / IN_DIM;
  int E = in_sizes[1] / 2;

  char* ws = (char*)d_ws;
  size_t off = 0;
  auto alloc = [&](size_t bytes) -> char* {
    char* p = ws + off;
    off = (off + bytes + 255) & ~(size_t)255;
    return p;
  };
  int* counts  = (int*)alloc((size_t)N*4);
  int* offsets = (int*)alloc((size_t)N*4);
  int* cursor  = (int*)alloc((size_t)N*4);
  int* bsum    = (int*)alloc(1024);
  int* csr     = (int*)alloc((size_t)E*4);
  // pool1 (aliased by PQ after lin2): aggx | x1bf | agg2bf  (32 MB >= 25.6 MB)
  float* aggx            = (float*)alloc((size_t)N*32*4);
  unsigned short* x1bf   = (unsigned short*)alloc((size_t)N*H*2);
  unsigned short* agg2bf = (unsigned short*)alloc((size_t)N*H*2);
  float* PQ = (float*)aggx;  // alias: written by k_pq after aggx/x1bf/agg2bf dead
  unsigned short* x2bf   = (unsigned short*)alloc((size_t)N*H*2);
  unsigned short* hbf    = (unsigned short*)alloc((size_t)N*H*2);
  unsigned short* hnewbf = (unsigned short*)alloc((size_t)N*H*2);
  unsigned short* W2l_bf = (unsigned short*)alloc(16384*2);
  unsigned short* W2r_bf = (unsigned short*)alloc(16384*2);
  unsigned short* Wih_bf = (unsigned short*)alloc(49152*2);
  unsigned short* Whh_bf = (unsigned short*)alloc(49152*2);
  unsigned short* V_bf   = (unsigned short*)alloc(16384*2);

  float* disp  = (float*)d_out;
  float* force = disp + (size_t)N*3;
  float* hnew  = force + (size_t)E*3;

  hipMemsetAsync(counts, 0, (size_t)N*4, stream);
  int nb = (N + 255) / 256;
  k_count  <<<2048, 256, 0, stream>>>(ei + E, counts, E);
  k_scanA  <<<nb, 256, 0, stream>>>(counts, offsets, bsum, N);
  k_scanB  <<<1, 256, 0, stream>>>(bsum, nb);
  k_scanC  <<<nb, 256, 0, stream>>>(offsets, cursor, bsum, N);
  k_scatter<<<2048, 256, 0, stream>>>(ei, cursor, csr, E);

  k_wconv  <<<192, 256, 0, stream>>>(W2l, W2r, Wih, Whh, Wf1,
                                     W2l_bf, W2r_bf, Wih_bf, Whh_bf, V_bf);
  k_hconv  <<<2048, 256, 0, stream>>>(h, hbf, N*32);

  k_aggx   <<<4096, 256, 0, stream>>>(x, csr, offsets, counts, aggx, N);
  k_lin1   <<<2048, 256, 0, stream>>>(aggx, x, W1l, b1l, W1r, x1bf, N);
  k_agg2   <<<4096, 256, 0, stream>>>(x1bf, csr, offsets, counts, agg2bf, N);
  k_mfma_dual<<<784, 256, 0, stream>>>(agg2bf, x1bf, W2l_bf, W2r_bf, b2l, x2bf, N);
  k_gru    <<<784, 256, 0, stream>>>(x2bf, hbf, h, Wih_bf, Whh_bf, bih, bhh, hnew, hnewbf, N);
  k_pq     <<<784, 256, 0, stream>>>(hnewbf, V_bf, PQ, N);
  k_disp   <<<1024, 256, 0, stream>>>(hnew, Wd1, bd1, Wd2, bd2, disp, N);
  k_force  <<<2048, 256, 0, stream>>>(ei, ea, PQ, Wf1, bf1, Wf2, bf2, force, E);
}

// Round 4
// 486.208 us; speedup vs baseline: 2.4775x; 1.3569x over previous
//
#include <hip/hip_runtime.h>
#include <hip/hip_bf16.h>

#define H 128
#define IN_DIM 30

typedef __attribute__((ext_vector_type(8))) short bf16x8;
typedef __attribute__((ext_vector_type(8))) unsigned short u16x8;
typedef __attribute__((ext_vector_type(4))) float f32x4;

__device__ inline unsigned short f2bf(float f){
  unsigned int u = __builtin_bit_cast(unsigned int, f);
  unsigned int r = u + 0x7FFF + ((u >> 16) & 1);
  return (unsigned short)(r >> 16);
}
__device__ inline float bf2f(unsigned short b){
  unsigned int u = ((unsigned int)b) << 16;
  return __builtin_bit_cast(float, u);
}
__device__ inline bf16x8 ldfrag(const unsigned short* p){
  return *(const bf16x8*)p;
}

// ---------------- CSR build ----------------
__global__ void k_count(const int* __restrict__ col, int* __restrict__ counts, int E){
  for (int e = blockIdx.x*blockDim.x + threadIdx.x; e < E; e += gridDim.x*blockDim.x)
    atomicAdd(&counts[col[e]], 1);
}

__global__ void k_scanA(const int* __restrict__ counts, int* __restrict__ offsets,
                        int* __restrict__ bsum, int n){
  __shared__ int buf[256];
  int i = blockIdx.x*256 + threadIdx.x;
  int v = (i < n) ? counts[i] : 0;
  buf[threadIdx.x] = v; __syncthreads();
  for (int off = 1; off < 256; off <<= 1){
    int t = (threadIdx.x >= off) ? buf[threadIdx.x - off] : 0;
    __syncthreads();
    buf[threadIdx.x] += t;
    __syncthreads();
  }
  if (i < n) offsets[i] = buf[threadIdx.x] - v;
  if (threadIdx.x == 255) bsum[blockIdx.x] = buf[255];
}

__global__ void k_scanB(int* __restrict__ bsum, int nb){
  __shared__ int buf[256];
  int v = (threadIdx.x < nb) ? bsum[threadIdx.x] : 0;
  buf[threadIdx.x] = v; __syncthreads();
  for (int off = 1; off < 256; off <<= 1){
    int t = (threadIdx.x >= off) ? buf[threadIdx.x - off] : 0;
    __syncthreads();
    buf[threadIdx.x] += t;
    __syncthreads();
  }
  if (threadIdx.x < nb) bsum[threadIdx.x] = buf[threadIdx.x] - v;
}

__global__ void k_scanC(int* __restrict__ offsets, int* __restrict__ cursor,
                        const int* __restrict__ bsum, int n){
  int i = blockIdx.x*256 + threadIdx.x;
  if (i < n){ int o = offsets[i] + bsum[blockIdx.x]; offsets[i] = o; cursor[i] = o; }
}

__global__ void k_scatter(const int* __restrict__ ei, int* __restrict__ cursor,
                          int* __restrict__ csr, int E){
  for (int e = blockIdx.x*blockDim.x + threadIdx.x; e < E; e += gridDim.x*blockDim.x){
    int c = ei[E + e];
    int p = atomicAdd(&cursor[c], 1);
    csr[p] = ei[e];
  }
}

// ---------------- weight conversion to bf16 ----------------
// V2 layout [160][128]: rows 0..63 = Wf1 P-part, 64..127 = Wf1 Q-part, 128..159 = Wd1
__global__ void k_wconv(const float* __restrict__ W2l, const float* __restrict__ W2r,
                        const float* __restrict__ Wih, const float* __restrict__ Whh,
                        const float* __restrict__ Wf1, const float* __restrict__ Wd1,
                        unsigned short* __restrict__ W2l_bf, unsigned short* __restrict__ W2r_bf,
                        unsigned short* __restrict__ Wih_bf, unsigned short* __restrict__ Whh_bf,
                        unsigned short* __restrict__ V2_bf){
  int stride = gridDim.x*blockDim.x;
  for (int i = blockIdx.x*blockDim.x + threadIdx.x; i < 49152; i += stride){
    if (i < 16384){
      W2l_bf[i] = f2bf(W2l[i]);
      W2r_bf[i] = f2bf(W2r[i]);
    }
    if (i < 20480){
      int j = i >> 7, k = i & 127;
      float v;
      if (j < 64)        v = Wf1[j*260 + k];
      else if (j < 128)  v = Wf1[(j-64)*260 + 128 + k];
      else               v = Wd1[(j-128)*128 + k];
      V2_bf[i] = f2bf(v);
    }
    Wih_bf[i] = f2bf(Wih[i]);
    Whh_bf[i] = f2bf(Whh[i]);
  }
}

// ---------------- h f32 -> bf16 ----------------
__global__ void k_hconv(const float* __restrict__ h, unsigned short* __restrict__ hbf, int total4){
  int stride = gridDim.x*blockDim.x;
  for (int i = blockIdx.x*blockDim.x + threadIdx.x; i < total4; i += stride){
    float4 v = ((const float4*)h)[i];
    ushort4 o; o.x = f2bf(v.x); o.y = f2bf(v.y); o.z = f2bf(v.z); o.w = f2bf(v.w);
    ((ushort4*)hbf)[i] = o;
  }
}

// ---------------- aggx: mean of x (30-dim) rows ----------------
__global__ __launch_bounds__(256) void k_aggx(
    const float* __restrict__ x, const int* __restrict__ csr,
    const int* __restrict__ offsets, const int* __restrict__ counts,
    float* __restrict__ aggx, int N)
{
  int t = blockIdx.x*blockDim.x + threadIdx.x;
  int gw = t >> 6, lane = t & 63;
  int nw = (gridDim.x*blockDim.x) >> 6;
  int half = lane >> 5, c = lane & 31;
  bool act = (c < IN_DIM);
  for (int d = gw; d < N; d += nw){
    int base = offsets[d], cnt = counts[d];
    float s = 0.f;
    for (int i = half; i < cnt; i += 2){
      int sr = csr[base + i];
      if (act) s += x[(size_t)sr*IN_DIM + c];
    }
    s += __shfl_xor(s, 32);
    if (lane < 32){
      float inv = 1.f / (float)(cnt > 0 ? cnt : 1);
      aggx[d*32 + c] = act ? s*inv : 0.f;
    }
  }
}

// ---------------- lin1 ----------------
__global__ __launch_bounds__(256) void k_lin1(
    const float* __restrict__ aggx, const float* __restrict__ x,
    const float* __restrict__ W1l, const float* __restrict__ b1l,
    const float* __restrict__ W1r, unsigned short* __restrict__ x1bf, int N)
{
  int tid = threadIdx.x;
  int slot = tid >> 7, c = tid & 127;
  float wl[IN_DIM], wr[IN_DIM];
  #pragma unroll
  for (int k = 0; k < IN_DIM; k++){ wl[k] = W1l[c*IN_DIM + k]; wr[k] = W1r[c*IN_DIM + k]; }
  float bc = b1l[c];
  for (int d0 = blockIdx.x*2; d0 < N; d0 += gridDim.x*2){
    int d = d0 + slot;
    if (d >= N) continue;
    float s = bc;
    const float* ag = &aggx[d*32];
    const float* xd = &x[(size_t)d*IN_DIM];
    #pragma unroll
    for (int k = 0; k < IN_DIM; k++) s += ag[k]*wl[k] + xd[k]*wr[k];
    x1bf[(size_t)d*H + c] = f2bf(fmaxf(s, 0.f));
  }
}

// ---------------- agg2 ----------------
__global__ __launch_bounds__(256) void k_agg2(
    const unsigned short* __restrict__ x1bf, const int* __restrict__ csr,
    const int* __restrict__ offsets, const int* __restrict__ counts,
    unsigned short* __restrict__ agg2bf, int N)
{
  int t = blockIdx.x*blockDim.x + threadIdx.x;
  int gw = t >> 6, lane = t & 63;
  int nw = (gridDim.x*blockDim.x) >> 6;
  const unsigned int* x1u = (const unsigned int*)x1bf;
  unsigned int* agu = (unsigned int*)agg2bf;
  for (int d = gw; d < N; d += nw){
    int base = offsets[d], cnt = counts[d];
    float a0 = 0.f, a1 = 0.f;
    int i = 0;
    for (; i + 1 < cnt; i += 2){
      int s0 = csr[base + i], s1 = csr[base + i + 1];
      unsigned int v0 = x1u[(size_t)s0*64 + lane];
      unsigned int v1 = x1u[(size_t)s1*64 + lane];
      a0 += bf2f((unsigned short)(v0 & 0xffff)) + bf2f((unsigned short)(v1 & 0xffff));
      a1 += bf2f((unsigned short)(v0 >> 16))    + bf2f((unsigned short)(v1 >> 16));
    }
    if (i < cnt){
      unsigned int v = x1u[(size_t)csr[base + i]*64 + lane];
      a0 += bf2f((unsigned short)(v & 0xffff));
      a1 += bf2f((unsigned short)(v >> 16));
    }
    float inv = 1.f / (float)(cnt > 0 ? cnt : 1);
    unsigned int o = (unsigned int)f2bf(a0*inv) | ((unsigned int)f2bf(a1*inv) << 16);
    agu[(size_t)d*64 + lane] = o;
  }
}

// ---------------- dual MFMA: out = relu(A@Wa.T + bias + B@Wb.T) -> bf16 ----------------
__global__ __launch_bounds__(256) void k_mfma_dual(
    const unsigned short* __restrict__ Abf, const unsigned short* __restrict__ Bbf,
    const unsigned short* __restrict__ Wa, const unsigned short* __restrict__ Wb,
    const float* __restrict__ bias, unsigned short* __restrict__ outbf, int N)
{
  int nt = (N + 15) >> 4;
  int l = threadIdx.x & 63;
  int m16 = l & 15, g4 = l >> 4;
  for (int t = blockIdx.x*4 + (threadIdx.x >> 6); t < nt; t += gridDim.x*4){
    int row0 = t << 4;
    int rml = min(row0 + m16, N-1);
    bf16x8 aA[4], aB[4];
    #pragma unroll
    for (int kb = 0; kb < 4; kb++){
      aA[kb] = ldfrag(Abf + (size_t)rml*H + kb*32 + g4*8);
      aB[kb] = ldfrag(Bbf + (size_t)rml*H + kb*32 + g4*8);
    }
    #pragma unroll 1
    for (int ct = 0; ct < 8; ct++){
      int c0 = ct*16;
      float bv = bias[c0 + m16];
      f32x4 acc = {bv, bv, bv, bv};
      #pragma unroll
      for (int kb = 0; kb < 4; kb++){
        bf16x8 wa = ldfrag(Wa + (size_t)(c0 + m16)*H + kb*32 + g4*8);
        acc = __builtin_amdgcn_mfma_f32_16x16x32_bf16(aA[kb], wa, acc, 0, 0, 0);
        bf16x8 wb = ldfrag(Wb + (size_t)(c0 + m16)*H + kb*32 + g4*8);
        acc = __builtin_amdgcn_mfma_f32_16x16x32_bf16(aB[kb], wb, acc, 0, 0, 0);
      }
      #pragma unroll
      for (int j = 0; j < 4; j++){
        int row = row0 + g4*4 + j;
        if (row < N)
          outbf[(size_t)row*H + c0 + m16] = f2bf(fmaxf(acc[j], 0.f));
      }
    }
  }
}

// ---------------- fused GRU via MFMA ----------------
__global__ __launch_bounds__(256) void k_gru(
    const unsigned short* __restrict__ x2bf, const unsigned short* __restrict__ hbf,
    const float* __restrict__ h,
    const unsigned short* __restrict__ Wih_bf, const unsigned short* __restrict__ Whh_bf,
    const float* __restrict__ bih, const float* __restrict__ bhh,
    float* __restrict__ hnew, unsigned short* __restrict__ hnewbf, int N)
{
  int nt = (N + 15) >> 4;
  int l = threadIdx.x & 63;
  int m16 = l & 15, g4 = l >> 4;
  for (int t = blockIdx.x*4 + (threadIdx.x >> 6); t < nt; t += gridDim.x*4){
    int row0 = t << 4;
    int rml = min(row0 + m16, N-1);
    bf16x8 aX[4], aH[4];
    #pragma unroll
    for (int kb = 0; kb < 4; kb++){
      aX[kb] = ldfrag(x2bf + (size_t)rml*H + kb*32 + g4*8);
      aH[kb] = ldfrag(hbf  + (size_t)rml*H + kb*32 + g4*8);
    }
    #pragma unroll 1
    for (int ct = 0; ct < 8; ct++){
      int c0 = ct*16, col = c0 + m16;
      float bir = bih[col],      bhr = bhh[col];
      float biz = bih[H + col],  bhz = bhh[H + col];
      float bin = bih[2*H + col], bhn = bhh[2*H + col];
      f32x4 aRi = {bir,bir,bir,bir}, aRh = {bhr,bhr,bhr,bhr};
      f32x4 aZi = {biz,biz,biz,biz}, aZh = {bhz,bhz,bhz,bhz};
      f32x4 aNi = {bin,bin,bin,bin}, aNh = {bhn,bhn,bhn,bhn};
      #pragma unroll
      for (int kb = 0; kb < 4; kb++){
        int ko = kb*32 + g4*8;
        aRi = __builtin_amdgcn_mfma_f32_16x16x32_bf16(aX[kb], ldfrag(Wih_bf + (size_t)(col)*H + ko),       aRi, 0,0,0);
        aRh = __builtin_amdgcn_mfma_f32_16x16x32_bf16(aH[kb], ldfrag(Whh_bf + (size_t)(col)*H + ko),       aRh, 0,0,0);
        aZi = __builtin_amdgcn_mfma_f32_16x16x32_bf16(aX[kb], ldfrag(Wih_bf + (size_t)(H + col)*H + ko),   aZi, 0,0,0);
        aZh = __builtin_amdgcn_mfma_f32_16x16x32_bf16(aH[kb], ldfrag(Whh_bf + (size_t)(H + col)*H + ko),   aZh, 0,0,0);
        aNi = __builtin_amdgcn_mfma_f32_16x16x32_bf16(aX[kb], ldfrag(Wih_bf + (size_t)(2*H + col)*H + ko), aNi, 0,0,0);
        aNh = __builtin_amdgcn_mfma_f32_16x16x32_bf16(aH[kb], ldfrag(Whh_bf + (size_t)(2*H + col)*H + ko), aNh, 0,0,0);
      }
      #pragma unroll
      for (int j = 0; j < 4; j++){
        int row = row0 + g4*4 + j;
        if (row < N){
          float r = 1.f / (1.f + expf(-(aRi[j] + aRh[j])));
          float z = 1.f / (1.f + expf(-(aZi[j] + aZh[j])));
          float nn = tanhf(aNi[j] + r*aNh[j]);
          float hv = h[(size_t)row*H + col];
          float o = (1.f - z)*nn + z*hv;
          hnew[(size_t)row*H + col] = o;
          hnewbf[(size_t)row*H + col] = f2bf(o);
        }
      }
    }
  }
}

// ---------------- proj: [PQ(128 cols, bf16) | D1(32 cols, relu, f32)] = hnew @ V2.T ----------------
__global__ __launch_bounds__(256) void k_proj(
    const unsigned short* __restrict__ hnewbf, const unsigned short* __restrict__ V2_bf,
    const float* __restrict__ bd1,
    unsigned short* __restrict__ PQbf, float* __restrict__ D1, int N)
{
  int nt = (N + 15) >> 4;
  int l = threadIdx.x & 63;
  int m16 = l & 15, g4 = l >> 4;
  for (int t = blockIdx.x*4 + (threadIdx.x >> 6); t < nt; t += gridDim.x*4){
    int row0 = t << 4;
    int rml = min(row0 + m16, N-1);
    bf16x8 aH[4];
    #pragma unroll
    for (int kb = 0; kb < 4; kb++)
      aH[kb] = ldfrag(hnewbf + (size_t)rml*H + kb*32 + g4*8);
    #pragma unroll 1
    for (int ct = 0; ct < 10; ct++){
      int c0 = ct*16;
      f32x4 acc = {0.f, 0.f, 0.f, 0.f};
      #pragma unroll
      for (int kb = 0; kb < 4; kb++){
        bf16x8 w = ldfrag(V2_bf + (size_t)(c0 + m16)*H + kb*32 + g4*8);
        acc = __builtin_amdgcn_mfma_f32_16x16x32_bf16(aH[kb], w, acc, 0, 0, 0);
      }
      if (ct < 8){
        #pragma unroll
        for (int j = 0; j < 4; j++){
          int row = row0 + g4*4 + j;
          if (row < N)
            PQbf[(size_t)row*H + c0 + m16] = f2bf(acc[j]);
        }
      } else {
        int dc = c0 + m16 - 128;
        float bv = bd1[dc];
        #pragma unroll
        for (int j = 0; j < 4; j++){
          int row = row0 + g4*4 + j;
          if (row < N)
            D1[(size_t)row*32 + dc] = fmaxf(acc[j] + bv, 0.f);
        }
      }
    }
  }
}

// ---------------- disp from D1: 32-lane group per node ----------------
__global__ __launch_bounds__(256) void k_disp2(
    const float* __restrict__ D1, const float* __restrict__ Wd2,
    const float* __restrict__ bd2, float* __restrict__ disp, int N)
{
  int t = blockIdx.x*blockDim.x + threadIdx.x;
  int gh = t >> 5, sub = t & 31;
  int nh = (gridDim.x*blockDim.x) >> 5;
  float w0 = Wd2[sub], w1 = Wd2[32 + sub], w2 = Wd2[64 + sub];
  float bo = (sub < 3) ? bd2[sub] : 0.f;
  for (int d = gh; d < N; d += nh){
    float v = D1[(size_t)d*32 + sub];
    float v0 = v*w0, v1 = v*w1, v2 = v*w2;
    #pragma unroll
    for (int off = 1; off < 32; off <<= 1){
      v0 += __shfl_xor(v0, off, 32);
      v1 += __shfl_xor(v1, off, 32);
      v2 += __shfl_xor(v2, off, 32);
    }
    if (sub < 3) disp[(size_t)d*3 + sub] = (sub == 0 ? v0 : (sub == 1 ? v1 : v2)) + bo;
  }
}

// ---------------- force decoder: MFMA over 16-edge tiles ----------------
__global__ __launch_bounds__(256) void k_force(
    const int* __restrict__ ei, const float* __restrict__ ea,
    const unsigned short* __restrict__ PQbf,
    const float* __restrict__ Wf1, const float* __restrict__ bf1,
    const float* __restrict__ Wf2, const float* __restrict__ bf2,
    float* __restrict__ out, int E)
{
  int l = threadIdx.x & 63;
  int r = l & 15, g = l >> 4;
  // per-lane constants for this lane's k-slices: k = kb*32 + g*8 + j
  float4 wc[2][8];
  float b1r[2][8];
  bf16x8 bfr[2];
  float bo = (r < 3) ? bf2[r] : 0.f;
  #pragma unroll
  for (int kb = 0; kb < 2; kb++){
    bf16x8 bf_;
    #pragma unroll
    for (int j = 0; j < 8; j++){
      int k = kb*32 + g*8 + j;
      wc[kb][j] = *(const float4*)&Wf1[k*260 + 256];
      b1r[kb][j] = bf1[k];
      bf_[j] = (r < 3) ? (short)f2bf(Wf2[r*64 + k]) : (short)0;
    }
    bfr[kb] = bf_;
  }
  int nt = (E + 15) >> 4;
  for (int t = blockIdx.x*4 + (threadIdx.x >> 6); t < nt; t += gridDim.x*4){
    int e = t*16 + r;
    int ec = min(e, E-1);
    int r0 = ei[ec], c0 = ei[E + ec];
    float4 a4 = *(const float4*)&ea[(size_t)ec*4];
    bf16x8 afr[2];
    #pragma unroll
    for (int kb = 0; kb < 2; kb++){
      u16x8 p8 = *(const u16x8*)&PQbf[(size_t)r0*H + kb*32 + g*8];
      u16x8 q8 = *(const u16x8*)&PQbf[(size_t)c0*H + 64 + kb*32 + g*8];
      bf16x8 af;
      #pragma unroll
      for (int j = 0; j < 8; j++){
        float pre = bf2f(p8[j]) + bf2f(q8[j]) + b1r[kb][j]
                  + a4.x*wc[kb][j].x + a4.y*wc[kb][j].y
                  + a4.z*wc[kb][j].z + a4.w*wc[kb][j].w;
        af[j] = (short)f2bf(fmaxf(pre, 0.f));
      }
      afr[kb] = af;
    }
    f32x4 acc = {0.f, 0.f, 0.f, 0.f};
    acc = __builtin_amdgcn_mfma_f32_16x16x32_bf16(afr[0], bfr[0], acc, 0, 0, 0);
    acc = __builtin_amdgcn_mfma_f32_16x16x32_bf16(afr[1], bfr[1], acc, 0, 0, 0);
    if (r < 3){
      #pragma unroll
      for (int j = 0; j < 4; j++){
        int erow = t*16 + g*4 + j;
        if (erow < E) out[(size_t)erow*3 + r] = acc[j] + bo;
      }
    }
  }
}

extern "C" void kernel_launch(void* const* d_in, const int* in_sizes, int n_in,
                              void* d_out, int out_size, void* d_ws, size_t ws_size,
                              hipStream_t stream)
{
  const float* x   = (const float*)d_in[0];
  const int*   ei  = (const int*)d_in[1];
  const float* ea  = (const float*)d_in[2];
  const float* h   = (const float*)d_in[3];
  const float* W1l = (const float*)d_in[4];
  const float* b1l = (const float*)d_in[5];
  const float* W1r = (const float*)d_in[6];
  const float* W2l = (const float*)d_in[7];
  const float* b2l = (const float*)d_in[8];
  const float* W2r = (const float*)d_in[9];
  const float* Wih = (const float*)d_in[10];
  const float* Whh = (const float*)d_in[11];
  const float* bih = (const float*)d_in[12];
  const float* bhh = (const float*)d_in[13];
  const float* Wd1 = (const float*)d_in[14];
  const float* bd1 = (const float*)d_in[15];
  const float* Wd2 = (const float*)d_in[16];
  const float* bd2 = (const float*)d_in[17];
  const float* Wf1 = (const float*)d_in[18];
  const float* bf1 = (const float*)d_in[19];
  const float* Wf2 = (const float*)d_in[20];
  const float* bf2 = (const float*)d_in[21];

  int N = in_sizes[0] / IN_DIM;
  int E = in_sizes[1] / 2;

  char* ws = (char*)d_ws;
  size_t off = 0;
  auto alloc = [&](size_t bytes) -> char* {
    char* p = ws + off;
    off = (off + bytes + 255) & ~(size_t)255;
    return p;
  };
  int* counts  = (int*)alloc((size_t)N*4);
  int* offsets = (int*)alloc((size_t)N*4);
  int* cursor  = (int*)alloc((size_t)N*4);
  int* bsum    = (int*)alloc(1024);
  int* csr     = (int*)alloc((size_t)E*4);
  // pool: aggx(6.4MB) | x1bf(12.8MB) | agg2bf(12.8MB); reused post-GRU:
  //   PQbf (12.8MB) over aggx+x1bf; D1 (6.4MB) over agg2bf
  float* aggx            = (float*)alloc((size_t)N*32*4);
  unsigned short* x1bf   = (unsigned short*)alloc((size_t)N*H*2);
  unsigned short* agg2bf = (unsigned short*)alloc((size_t)N*H*2);
  unsigned short* PQbf = (unsigned short*)aggx;
  float* D1            = (float*)agg2bf;
  unsigned short* x2bf   = (unsigned short*)alloc((size_t)N*H*2);
  unsigned short* hbf    = (unsigned short*)alloc((size_t)N*H*2);
  unsigned short* hnewbf = (unsigned short*)alloc((size_t)N*H*2);
  unsigned short* W2l_bf = (unsigned short*)alloc(16384*2);
  unsigned short* W2r_bf = (unsigned short*)alloc(16384*2);
  unsigned short* Wih_bf = (unsigned short*)alloc(49152*2);
  unsigned short* Whh_bf = (unsigned short*)alloc(49152*2);
  unsigned short* V2_bf  = (unsigned short*)alloc(20480*2);

  float* disp  = (float*)d_out;
  float* force = disp + (size_t)N*3;
  float* hnew  = force + (size_t)E*3;

  hipMemsetAsync(counts, 0, (size_t)N*4, stream);
  int nb = (N + 255) / 256;
  k_count  <<<2048, 256, 0, stream>>>(ei + E, counts, E);
  k_scanA  <<<nb, 256, 0, stream>>>(counts, offsets, bsum, N);
  k_scanB  <<<1, 256, 0, stream>>>(bsum, nb);
  k_scanC  <<<nb, 256, 0, stream>>>(offsets, cursor, bsum, N);
  k_scatter<<<2048, 256, 0, stream>>>(ei, cursor, csr, E);

  k_wconv  <<<192, 256, 0, stream>>>(W2l, W2r, Wih, Whh, Wf1, Wd1,
                                     W2l_bf, W2r_bf, Wih_bf, Whh_bf, V2_bf);
  k_hconv  <<<2048, 256, 0, stream>>>(h, hbf, N*32);

  k_aggx   <<<4096, 256, 0, stream>>>(x, csr, offsets, counts, aggx, N);
  k_lin1   <<<2048, 256, 0, stream>>>(aggx, x, W1l, b1l, W1r, x1bf, N);
  k_agg2   <<<4096, 256, 0, stream>>>(x1bf, csr, offsets, counts, agg2bf, N);
  k_mfma_dual<<<784, 256, 0, stream>>>(agg2bf, x1bf, W2l_bf, W2r_bf, b2l, x2bf, N);
  k_gru    <<<784, 256, 0, stream>>>(x2bf, hbf, h, Wih_bf, Whh_bf, bih, bhh, hnew, hnewbf, N);
  k_proj   <<<784, 256, 0, stream>>>(hnewbf, V2_bf, bd1, PQbf, D1, N);
  k_disp2  <<<1024, 256, 0, stream>>>(D1, Wd2, bd2, disp, N);
  k_force  <<<2048, 256, 0, stream>>>(ei, ea, PQbf, Wf1, bf1, Wf2, bf2, force, E);
}

// Round 5
// 412.836 us; speedup vs baseline: 2.9178x; 1.1777x over previous
//
#include <hip/hip_runtime.h>
#include <hip/hip_bf16.h>

#define H 128
#define IN_DIM 30
#define LDSP 136  // padded row stride (ushorts) for staged activations

typedef __attribute__((ext_vector_type(8))) short bf16x8;
typedef __attribute__((ext_vector_type(8))) unsigned short u16x8;
typedef __attribute__((ext_vector_type(4))) float f32x4;

__device__ inline unsigned short f2bf(float f){
  unsigned int u = __builtin_bit_cast(unsigned int, f);
  unsigned int r = u + 0x7FFF + ((u >> 16) & 1);
  return (unsigned short)(r >> 16);
}
__device__ inline float bf2f(unsigned short b){
  unsigned int u = ((unsigned int)b) << 16;
  return __builtin_bit_cast(float, u);
}
__device__ inline bf16x8 ldfrag(const unsigned short* p){
  return *(const bf16x8*)p;
}

// ---------------- CSR build ----------------
__global__ void k_count(const int* __restrict__ col, int* __restrict__ counts, int E){
  for (int e = blockIdx.x*blockDim.x + threadIdx.x; e < E; e += gridDim.x*blockDim.x)
    atomicAdd(&counts[col[e]], 1);
}

__global__ void k_scanA(const int* __restrict__ counts, int* __restrict__ offsets,
                        int* __restrict__ bsum, int n){
  __shared__ int buf[256];
  int i = blockIdx.x*256 + threadIdx.x;
  int v = (i < n) ? counts[i] : 0;
  buf[threadIdx.x] = v; __syncthreads();
  for (int off = 1; off < 256; off <<= 1){
    int t = (threadIdx.x >= off) ? buf[threadIdx.x - off] : 0;
    __syncthreads();
    buf[threadIdx.x] += t;
    __syncthreads();
  }
  if (i < n) offsets[i] = buf[threadIdx.x] - v;
  if (threadIdx.x == 255) bsum[blockIdx.x] = buf[255];
}

__global__ void k_scanB(int* __restrict__ bsum, int nb){
  __shared__ int buf[256];
  int v = (threadIdx.x < nb) ? bsum[threadIdx.x] : 0;
  buf[threadIdx.x] = v; __syncthreads();
  for (int off = 1; off < 256; off <<= 1){
    int t = (threadIdx.x >= off) ? buf[threadIdx.x - off] : 0;
    __syncthreads();
    buf[threadIdx.x] += t;
    __syncthreads();
  }
  if (threadIdx.x < nb) bsum[threadIdx.x] = buf[threadIdx.x] - v;
}

__global__ void k_scanC(int* __restrict__ offsets, int* __restrict__ cursor,
                        const int* __restrict__ bsum, int n){
  int i = blockIdx.x*256 + threadIdx.x;
  if (i < n){ int o = offsets[i] + bsum[blockIdx.x]; offsets[i] = o; cursor[i] = o; }
}

__global__ void k_scatter(const int* __restrict__ ei, int* __restrict__ cursor,
                          int* __restrict__ csr, int E){
  for (int e = blockIdx.x*blockDim.x + threadIdx.x; e < E; e += gridDim.x*blockDim.x){
    int c = ei[E + e];
    int p = atomicAdd(&cursor[c], 1);
    csr[p] = ei[e];
  }
}

// ---------------- weight conversion to bf16 ----------------
// V2 layout [160][128]: rows 0..63 = Wf1 P-part, 64..127 = Wf1 Q-part, 128..159 = Wd1
__global__ void k_wconv(const float* __restrict__ W2l, const float* __restrict__ W2r,
                        const float* __restrict__ Wih, const float* __restrict__ Whh,
                        const float* __restrict__ Wf1, const float* __restrict__ Wd1,
                        unsigned short* __restrict__ W2l_bf, unsigned short* __restrict__ W2r_bf,
                        unsigned short* __restrict__ Wih_bf, unsigned short* __restrict__ Whh_bf,
                        unsigned short* __restrict__ V2_bf){
  int stride = gridDim.x*blockDim.x;
  for (int i = blockIdx.x*blockDim.x + threadIdx.x; i < 49152; i += stride){
    if (i < 16384){
      W2l_bf[i] = f2bf(W2l[i]);
      W2r_bf[i] = f2bf(W2r[i]);
    }
    if (i < 20480){
      int j = i >> 7, k = i & 127;
      float v;
      if (j < 64)        v = Wf1[j*260 + k];
      else if (j < 128)  v = Wf1[(j-64)*260 + 128 + k];
      else               v = Wd1[(j-128)*128 + k];
      V2_bf[i] = f2bf(v);
    }
    Wih_bf[i] = f2bf(Wih[i]);
    Whh_bf[i] = f2bf(Whh[i]);
  }
}

// ---------------- h f32 -> bf16 ----------------
__global__ void k_hconv(const float* __restrict__ h, unsigned short* __restrict__ hbf, int total4){
  int stride = gridDim.x*blockDim.x;
  for (int i = blockIdx.x*blockDim.x + threadIdx.x; i < total4; i += stride){
    float4 v = ((const float4*)h)[i];
    ushort4 o; o.x = f2bf(v.x); o.y = f2bf(v.y); o.z = f2bf(v.z); o.w = f2bf(v.w);
    ((ushort4*)hbf)[i] = o;
  }
}

// ---------------- aggx: mean of x (30-dim) rows ----------------
__global__ __launch_bounds__(256) void k_aggx(
    const float* __restrict__ x, const int* __restrict__ csr,
    const int* __restrict__ offsets, const int* __restrict__ counts,
    float* __restrict__ aggx, int N)
{
  int t = blockIdx.x*blockDim.x + threadIdx.x;
  int gw = t >> 6, lane = t & 63;
  int nw = (gridDim.x*blockDim.x) >> 6;
  int half = lane >> 5, c = lane & 31;
  bool act = (c < IN_DIM);
  for (int d = gw; d < N; d += nw){
    int base = offsets[d], cnt = counts[d];
    float s = 0.f;
    for (int i = half; i < cnt; i += 2){
      int sr = csr[base + i];
      if (act) s += x[(size_t)sr*IN_DIM + c];
    }
    s += __shfl_xor(s, 32);
    if (lane < 32){
      float inv = 1.f / (float)(cnt > 0 ? cnt : 1);
      aggx[d*32 + c] = act ? s*inv : 0.f;
    }
  }
}

// ---------------- lin1 ----------------
__global__ __launch_bounds__(256) void k_lin1(
    const float* __restrict__ aggx, const float* __restrict__ x,
    const float* __restrict__ W1l, const float* __restrict__ b1l,
    const float* __restrict__ W1r, unsigned short* __restrict__ x1bf, int N)
{
  int tid = threadIdx.x;
  int slot = tid >> 7, c = tid & 127;
  float wl[IN_DIM], wr[IN_DIM];
  #pragma unroll
  for (int k = 0; k < IN_DIM; k++){ wl[k] = W1l[c*IN_DIM + k]; wr[k] = W1r[c*IN_DIM + k]; }
  float bc = b1l[c];
  for (int d0 = blockIdx.x*2; d0 < N; d0 += gridDim.x*2){
    int d = d0 + slot;
    if (d >= N) continue;
    float s = bc;
    const float* ag = &aggx[d*32];
    const float* xd = &x[(size_t)d*IN_DIM];
    #pragma unroll
    for (int k = 0; k < IN_DIM; k++) s += ag[k]*wl[k] + xd[k]*wr[k];
    x1bf[(size_t)d*H + c] = f2bf(fmaxf(s, 0.f));
  }
}

// ---------------- agg2 ----------------
__global__ __launch_bounds__(256) void k_agg2(
    const unsigned short* __restrict__ x1bf, const int* __restrict__ csr,
    const int* __restrict__ offsets, const int* __restrict__ counts,
    unsigned short* __restrict__ agg2bf, int N)
{
  int t = blockIdx.x*blockDim.x + threadIdx.x;
  int gw = t >> 6, lane = t & 63;
  int nw = (gridDim.x*blockDim.x) >> 6;
  const unsigned int* x1u = (const unsigned int*)x1bf;
  unsigned int* agu = (unsigned int*)agg2bf;
  for (int d = gw; d < N; d += nw){
    int base = offsets[d], cnt = counts[d];
    float a0 = 0.f, a1 = 0.f;
    int i = 0;
    for (; i + 1 < cnt; i += 2){
      int s0 = csr[base + i], s1 = csr[base + i + 1];
      unsigned int v0 = x1u[(size_t)s0*64 + lane];
      unsigned int v1 = x1u[(size_t)s1*64 + lane];
      a0 += bf2f((unsigned short)(v0 & 0xffff)) + bf2f((unsigned short)(v1 & 0xffff));
      a1 += bf2f((unsigned short)(v0 >> 16))    + bf2f((unsigned short)(v1 >> 16));
    }
    if (i < cnt){
      unsigned int v = x1u[(size_t)csr[base + i]*64 + lane];
      a0 += bf2f((unsigned short)(v & 0xffff));
      a1 += bf2f((unsigned short)(v >> 16));
    }
    float inv = 1.f / (float)(cnt > 0 ? cnt : 1);
    unsigned int o = (unsigned int)f2bf(a0*inv) | ((unsigned int)f2bf(a1*inv) << 16);
    agu[(size_t)d*64 + lane] = o;
  }
}

// ============ strip GEMM kernels: 512 thr, 128-row strips, LDS-staged A ============
// wave w owns output cols [w*16, w*16+16); weight fragments live in registers.

// ---------------- SAGE2: x2 = relu(agg2@W2l.T + b2l + x1@W2r.T) ----------------
__global__ __launch_bounds__(512) void k_dual2(
    const unsigned short* __restrict__ Abf, const unsigned short* __restrict__ Bbf,
    const unsigned short* __restrict__ Wa, const unsigned short* __restrict__ Wb,
    const float* __restrict__ bias, unsigned short* __restrict__ outbf, int N)
{
  __shared__ unsigned short sA[128*LDSP];
  __shared__ unsigned short sB[128*LDSP];
  int tid = threadIdx.x;
  int wid = tid >> 6, l = tid & 63, m16 = l & 15, g4 = l >> 4;
  int col = wid*16 + m16;
  bf16x8 wa[4], wb[4];
  #pragma unroll
  for (int kb = 0; kb < 4; kb++){
    wa[kb] = ldfrag(Wa + (size_t)col*H + kb*32 + g4*8);
    wb[kb] = ldfrag(Wb + (size_t)col*H + kb*32 + g4*8);
  }
  float bc = bias[col];
  int nstrips = (N + 127) >> 7;
  for (int s = blockIdx.x; s < nstrips; s += gridDim.x){
    int base = s << 7;
    __syncthreads();
    for (int c = tid; c < 4096; c += 512){
      int mat = c >> 11, cc = c & 2047;
      int row = cc >> 4, co = cc & 15;
      int gr = min(base + row, N-1);
      u16x8 v = *(const u16x8*)((mat ? Bbf : Abf) + (size_t)gr*H + co*8);
      *(u16x8*)&((mat ? sB : sA)[row*LDSP + co*8]) = v;
    }
    __syncthreads();
    #pragma unroll 1
    for (int rt = 0; rt < 8; rt++){
      int rb = rt*16;
      f32x4 acc = {bc, bc, bc, bc};
      #pragma unroll
      for (int kb = 0; kb < 4; kb++){
        bf16x8 a = *(const bf16x8*)&sA[(rb + m16)*LDSP + kb*32 + g4*8];
        acc = __builtin_amdgcn_mfma_f32_16x16x32_bf16(a, wa[kb], acc, 0, 0, 0);
        bf16x8 b = *(const bf16x8*)&sB[(rb + m16)*LDSP + kb*32 + g4*8];
        acc = __builtin_amdgcn_mfma_f32_16x16x32_bf16(b, wb[kb], acc, 0, 0, 0);
      }
      #pragma unroll
      for (int j = 0; j < 4; j++){
        int row = base + rb + g4*4 + j;
        if (row < N)
          outbf[(size_t)row*H + col] = f2bf(fmaxf(acc[j], 0.f));
      }
    }
  }
}

// ---------------- fused GRU ----------------
__global__ __launch_bounds__(512) void k_gru2(
    const unsigned short* __restrict__ x2bf, const unsigned short* __restrict__ hbf,
    const float* __restrict__ h,
    const unsigned short* __restrict__ Wih_bf, const unsigned short* __restrict__ Whh_bf,
    const float* __restrict__ bih, const float* __restrict__ bhh,
    float* __restrict__ hnew, unsigned short* __restrict__ hnewbf, int N)
{
  __shared__ unsigned short sX[128*LDSP];
  __shared__ unsigned short sH[128*LDSP];
  int tid = threadIdx.x;
  int wid = tid >> 6, l = tid & 63, m16 = l & 15, g4 = l >> 4;
  int col = wid*16 + m16;
  bf16x8 wih[3][4], whh[3][4];
  #pragma unroll
  for (int g = 0; g < 3; g++){
    #pragma unroll
    for (int kb = 0; kb < 4; kb++){
      wih[g][kb] = ldfrag(Wih_bf + (size_t)(g*H + col)*H + kb*32 + g4*8);
      whh[g][kb] = ldfrag(Whh_bf + (size_t)(g*H + col)*H + kb*32 + g4*8);
    }
  }
  float bir = bih[col],       bhr = bhh[col];
  float biz = bih[H + col],   bhz = bhh[H + col];
  float bin = bih[2*H + col], bhn = bhh[2*H + col];
  int nstrips = (N + 127) >> 7;
  for (int s = blockIdx.x; s < nstrips; s += gridDim.x){
    int base = s << 7;
    __syncthreads();
    for (int c = tid; c < 4096; c += 512){
      int mat = c >> 11, cc = c & 2047;
      int row = cc >> 4, co = cc & 15;
      int gr = min(base + row, N-1);
      u16x8 v = *(const u16x8*)((mat ? hbf : x2bf) + (size_t)gr*H + co*8);
      *(u16x8*)&((mat ? sH : sX)[row*LDSP + co*8]) = v;
    }
    __syncthreads();
    #pragma unroll 1
    for (int rt = 0; rt < 8; rt++){
      int rb = rt*16;
      bf16x8 aX[4], aH[4];
      #pragma unroll
      for (int kb = 0; kb < 4; kb++){
        aX[kb] = *(const bf16x8*)&sX[(rb + m16)*LDSP + kb*32 + g4*8];
        aH[kb] = *(const bf16x8*)&sH[(rb + m16)*LDSP + kb*32 + g4*8];
      }
      f32x4 aRi = {bir,bir,bir,bir}, aRh = {bhr,bhr,bhr,bhr};
      f32x4 aZi = {biz,biz,biz,biz}, aZh = {bhz,bhz,bhz,bhz};
      f32x4 aNi = {bin,bin,bin,bin}, aNh = {bhn,bhn,bhn,bhn};
      #pragma unroll
      for (int kb = 0; kb < 4; kb++){
        aRi = __builtin_amdgcn_mfma_f32_16x16x32_bf16(aX[kb], wih[0][kb], aRi, 0,0,0);
        aRh = __builtin_amdgcn_mfma_f32_16x16x32_bf16(aH[kb], whh[0][kb], aRh, 0,0,0);
        aZi = __builtin_amdgcn_mfma_f32_16x16x32_bf16(aX[kb], wih[1][kb], aZi, 0,0,0);
        aZh = __builtin_amdgcn_mfma_f32_16x16x32_bf16(aH[kb], whh[1][kb], aZh, 0,0,0);
        aNi = __builtin_amdgcn_mfma_f32_16x16x32_bf16(aX[kb], wih[2][kb], aNi, 0,0,0);
        aNh = __builtin_amdgcn_mfma_f32_16x16x32_bf16(aH[kb], whh[2][kb], aNh, 0,0,0);
      }
      #pragma unroll
      for (int j = 0; j < 4; j++){
        int row = base + rb + g4*4 + j;
        if (row < N){
          float r = 1.f / (1.f + expf(-(aRi[j] + aRh[j])));
          float z = 1.f / (1.f + expf(-(aZi[j] + aZh[j])));
          float nn = tanhf(aNi[j] + r*aNh[j]);
          float hv = h[(size_t)row*H + col];
          float o = (1.f - z)*nn + z*hv;
          hnew[(size_t)row*H + col] = o;
          hnewbf[(size_t)row*H + col] = f2bf(o);
        }
      }
    }
  }
}

// ---------------- proj: PQ (bf16, cols 0..127) and D1 (relu f32, V2 rows 128..159) ----------------
__global__ __launch_bounds__(512) void k_proj2(
    const unsigned short* __restrict__ hnewbf, const unsigned short* __restrict__ V2_bf,
    const float* __restrict__ bd1,
    unsigned short* __restrict__ PQbf, float* __restrict__ D1, int N)
{
  __shared__ unsigned short sHn[128*LDSP];
  int tid = threadIdx.x;
  int wid = tid >> 6, l = tid & 63, m16 = l & 15, g4 = l >> 4;
  int col = wid*16 + m16;
  bf16x8 v1[4], v2[4];
  #pragma unroll
  for (int kb = 0; kb < 4; kb++)
    v1[kb] = ldfrag(V2_bf + (size_t)col*H + kb*32 + g4*8);
  int dc = wid*16 + m16;  // D1 col for wid<2
  float bdv = 0.f;
  if (wid < 2){
    #pragma unroll
    for (int kb = 0; kb < 4; kb++)
      v2[kb] = ldfrag(V2_bf + (size_t)(128 + dc)*H + kb*32 + g4*8);
    bdv = bd1[dc];
  }
  int nstrips = (N + 127) >> 7;
  for (int s = blockIdx.x; s < nstrips; s += gridDim.x){
    int base = s << 7;
    __syncthreads();
    for (int c = tid; c < 2048; c += 512){
      int row = c >> 4, co = c & 15;
      int gr = min(base + row, N-1);
      u16x8 v = *(const u16x8*)(hnewbf + (size_t)gr*H + co*8);
      *(u16x8*)&(sHn[row*LDSP + co*8]) = v;
    }
    __syncthreads();
    #pragma unroll 1
    for (int rt = 0; rt < 8; rt++){
      int rb = rt*16;
      bf16x8 aH[4];
      #pragma unroll
      for (int kb = 0; kb < 4; kb++)
        aH[kb] = *(const bf16x8*)&sHn[(rb + m16)*LDSP + kb*32 + g4*8];
      f32x4 acc = {0.f, 0.f, 0.f, 0.f};
      #pragma unroll
      for (int kb = 0; kb < 4; kb++)
        acc = __builtin_amdgcn_mfma_f32_16x16x32_bf16(aH[kb], v1[kb], acc, 0, 0, 0);
      #pragma unroll
      for (int j = 0; j < 4; j++){
        int row = base + rb + g4*4 + j;
        if (row < N)
          PQbf[(size_t)row*H + col] = f2bf(acc[j]);
      }
      if (wid < 2){
        f32x4 acc2 = {0.f, 0.f, 0.f, 0.f};
        #pragma unroll
        for (int kb = 0; kb < 4; kb++)
          acc2 = __builtin_amdgcn_mfma_f32_16x16x32_bf16(aH[kb], v2[kb], acc2, 0, 0, 0);
        #pragma unroll
        for (int j = 0; j < 4; j++){
          int row = base + rb + g4*4 + j;
          if (row < N)
            D1[(size_t)row*32 + dc] = fmaxf(acc2[j] + bdv, 0.f);
        }
      }
    }
  }
}

// ---------------- disp from D1: 32-lane group per node ----------------
__global__ __launch_bounds__(256) void k_disp2(
    const float* __restrict__ D1, const float* __restrict__ Wd2,
    const float* __restrict__ bd2, float* __restrict__ disp, int N)
{
  int t = blockIdx.x*blockDim.x + threadIdx.x;
  int gh = t >> 5, sub = t & 31;
  int nh = (gridDim.x*blockDim.x) >> 5;
  float w0 = Wd2[sub], w1 = Wd2[32 + sub], w2 = Wd2[64 + sub];
  float bo = (sub < 3) ? bd2[sub] : 0.f;
  for (int d = gh; d < N; d += nh){
    float v = D1[(size_t)d*32 + sub];
    float v0 = v*w0, v1 = v*w1, v2 = v*w2;
    #pragma unroll
    for (int off = 1; off < 32; off <<= 1){
      v0 += __shfl_xor(v0, off, 32);
      v1 += __shfl_xor(v1, off, 32);
      v2 += __shfl_xor(v2, off, 32);
    }
    if (sub < 3) disp[(size_t)d*3 + sub] = (sub == 0 ? v0 : (sub == 1 ? v1 : v2)) + bo;
  }
}

// ---------------- force decoder: MFMA over 16-edge tiles ----------------
__global__ __launch_bounds__(256) void k_force(
    const int* __restrict__ ei, const float* __restrict__ ea,
    const unsigned short* __restrict__ PQbf,
    const float* __restrict__ Wf1, const float* __restrict__ bf1,
    const float* __restrict__ Wf2, const float* __restrict__ bf2,
    float* __restrict__ out, int E)
{
  int l = threadIdx.x & 63;
  int r = l & 15, g = l >> 4;
  float4 wc[2][8];
  float b1r[2][8];
  bf16x8 bfr[2];
  float bo = (r < 3) ? bf2[r] : 0.f;
  #pragma unroll
  for (int kb = 0; kb < 2; kb++){
    bf16x8 bf_;
    #pragma unroll
    for (int j = 0; j < 8; j++){
      int k = kb*32 + g*8 + j;
      wc[kb][j] = *(const float4*)&Wf1[k*260 + 256];
      b1r[kb][j] = bf1[k];
      bf_[j] = (r < 3) ? (short)f2bf(Wf2[r*64 + k]) : (short)0;
    }
    bfr[kb] = bf_;
  }
  int nt = (E + 15) >> 4;
  for (int t = blockIdx.x*4 + (threadIdx.x >> 6); t < nt; t += gridDim.x*4){
    int e = t*16 + r;
    int ec = min(e, E-1);
    int r0 = ei[ec], c0 = ei[E + ec];
    float4 a4 = *(const float4*)&ea[(size_t)ec*4];
    bf16x8 afr[2];
    #pragma unroll
    for (int kb = 0; kb < 2; kb++){
      u16x8 p8 = *(const u16x8*)&PQbf[(size_t)r0*H + kb*32 + g*8];
      u16x8 q8 = *(const u16x8*)&PQbf[(size_t)c0*H + 64 + kb*32 + g*8];
      bf16x8 af;
      #pragma unroll
      for (int j = 0; j < 8; j++){
        float pre = bf2f(p8[j]) + bf2f(q8[j]) + b1r[kb][j]
                  + a4.x*wc[kb][j].x + a4.y*wc[kb][j].y
                  + a4.z*wc[kb][j].z + a4.w*wc[kb][j].w;
        af[j] = (short)f2bf(fmaxf(pre, 0.f));
      }
      afr[kb] = af;
    }
    f32x4 acc = {0.f, 0.f, 0.f, 0.f};
    acc = __builtin_amdgcn_mfma_f32_16x16x32_bf16(afr[0], bfr[0], acc, 0, 0, 0);
    acc = __builtin_amdgcn_mfma_f32_16x16x32_bf16(afr[1], bfr[1], acc, 0, 0, 0);
    if (r < 3){
      #pragma unroll
      for (int j = 0; j < 4; j++){
        int erow = t*16 + g*4 + j;
        if (erow < E) out[(size_t)erow*3 + r] = acc[j] + bo;
      }
    }
  }
}

extern "C" void kernel_launch(void* const* d_in, const int* in_sizes, int n_in,
                              void* d_out, int out_size, void* d_ws, size_t ws_size,
                              hipStream_t stream)
{
  const float* x   = (const float*)d_in[0];
  const int*   ei  = (const int*)d_in[1];
  const float* ea  = (const float*)d_in[2];
  const float* h   = (const float*)d_in[3];
  const float* W1l = (const float*)d_in[4];
  const float* b1l = (const float*)d_in[5];
  const float* W1r = (const float*)d_in[6];
  const float* W2l = (const float*)d_in[7];
  const float* b2l = (const float*)d_in[8];
  const float* W2r = (const float*)d_in[9];
  const float* Wih = (const float*)d_in[10];
  const float* Whh = (const float*)d_in[11];
  const float* bih = (const float*)d_in[12];
  const float* bhh = (const float*)d_in[13];
  const float* Wd1 = (const float*)d_in[14];
  const float* bd1 = (const float*)d_in[15];
  const float* Wd2 = (const float*)d_in[16];
  const float* bd2 = (const float*)d_in[17];
  const float* Wf1 = (const float*)d_in[18];
  const float* bf1 = (const float*)d_in[19];
  const float* Wf2 = (const float*)d_in[20];
  const float* bf2 = (const float*)d_in[21];

  int N = in_sizes[0] / IN_DIM;
  int E = in_sizes[1] / 2;

  char* ws = (char*)d_ws;
  size_t off = 0;
  auto alloc = [&](size_t bytes) -> char* {
    char* p = ws + off;
    off = (off + bytes + 255) & ~(size_t)255;
    return p;
  };
  int* counts  = (int*)alloc((size_t)N*4);
  int* offsets = (int*)alloc((size_t)N*4);
  int* cursor  = (int*)alloc((size_t)N*4);
  int* bsum    = (int*)alloc(1024);
  int* csr     = (int*)alloc((size_t)E*4);
  // pool: aggx(6.4MB) | x1bf(12.8MB) | agg2bf(12.8MB); reused post-GRU:
  //   PQbf (12.8MB) over aggx+x1bf; D1 (6.4MB) over agg2bf
  float* aggx            = (float*)alloc((size_t)N*32*4);
  unsigned short* x1bf   = (unsigned short*)alloc((size_t)N*H*2);
  unsigned short* agg2bf = (unsigned short*)alloc((size_t)N*H*2);
  unsigned short* PQbf = (unsigned short*)aggx;
  float* D1            = (float*)agg2bf;
  unsigned short* x2bf   = (unsigned short*)alloc((size_t)N*H*2);
  unsigned short* hbf    = (unsigned short*)alloc((size_t)N*H*2);
  unsigned short* hnewbf = (unsigned short*)alloc((size_t)N*H*2);
  unsigned short* W2l_bf = (unsigned short*)alloc(16384*2);
  unsigned short* W2r_bf = (unsigned short*)alloc(16384*2);
  unsigned short* Wih_bf = (unsigned short*)alloc(49152*2);
  unsigned short* Whh_bf = (unsigned short*)alloc(49152*2);
  unsigned short* V2_bf  = (unsigned short*)alloc(20480*2);

  float* disp  = (float*)d_out;
  float* force = disp + (size_t)N*3;
  float* hnew  = force + (size_t)E*3;

  hipMemsetAsync(counts, 0, (size_t)N*4, stream);
  int nb = (N + 255) / 256;
  k_count  <<<2048, 256, 0, stream>>>(ei + E, counts, E);
  k_scanA  <<<nb, 256, 0, stream>>>(counts, offsets, bsum, N);
  k_scanB  <<<1, 256, 0, stream>>>(bsum, nb);
  k_scanC  <<<nb, 256, 0, stream>>>(offsets, cursor, bsum, N);
  k_scatter<<<2048, 256, 0, stream>>>(ei, cursor, csr, E);

  k_wconv  <<<192, 256, 0, stream>>>(W2l, W2r, Wih, Whh, Wf1, Wd1,
                                     W2l_bf, W2r_bf, Wih_bf, Whh_bf, V2_bf);
  k_hconv  <<<2048, 256, 0, stream>>>(h, hbf, N*32);

  k_aggx   <<<4096, 256, 0, stream>>>(x, csr, offsets, counts, aggx, N);
  k_lin1   <<<2048, 256, 0, stream>>>(aggx, x, W1l, b1l, W1r, x1bf, N);
  k_agg2   <<<4096, 256, 0, stream>>>(x1bf, csr, offsets, counts, agg2bf, N);

  int nstrips = (N + 127) / 128;
  k_dual2  <<<nstrips, 512, 0, stream>>>(agg2bf, x1bf, W2l_bf, W2r_bf, b2l, x2bf, N);
  k_gru2   <<<nstrips, 512, 0, stream>>>(x2bf, hbf, h, Wih_bf, Whh_bf, bih, bhh, hnew, hnewbf, N);
  k_proj2  <<<nstrips, 512, 0, stream>>>(hnewbf, V2_bf, bd1, PQbf, D1, N);
  k_disp2  <<<1024, 256, 0, stream>>>(D1, Wd2, bd2, disp, N);
  k_force  <<<2048, 256, 0, stream>>>(ei, ea, PQbf, Wf1, bf1, Wf2, bf2, force, E);
}

// Round 6
// 396.339 us; speedup vs baseline: 3.0392x; 1.0416x over previous
//
#include <hip/hip_runtime.h>
#include <hip/hip_bf16.h>

#define H 128
#define IN_DIM 30
#define LDSP 136  // padded row stride (ushorts) for staged activations

typedef __attribute__((ext_vector_type(8))) short bf16x8;
typedef __attribute__((ext_vector_type(8))) unsigned short u16x8;
typedef __attribute__((ext_vector_type(4))) float f32x4;

__device__ inline unsigned short f2bf(float f){
  unsigned int u = __builtin_bit_cast(unsigned int, f);
  unsigned int r = u + 0x7FFF + ((u >> 16) & 1);
  return (unsigned short)(r >> 16);
}
__device__ inline float bf2f(unsigned short b){
  unsigned int u = ((unsigned int)b) << 16;
  return __builtin_bit_cast(float, u);
}
__device__ inline bf16x8 ldfrag(const unsigned short* p){
  return *(const bf16x8*)p;
}

// ---------------- CSR build ----------------
__global__ void k_count(const int* __restrict__ col, int* __restrict__ counts, int E){
  for (int e = blockIdx.x*blockDim.x + threadIdx.x; e < E; e += gridDim.x*blockDim.x)
    atomicAdd(&counts[col[e]], 1);
}

__global__ void k_scanA(const int* __restrict__ counts, int* __restrict__ offsets,
                        int* __restrict__ bsum, int n){
  __shared__ int buf[256];
  int i = blockIdx.x*256 + threadIdx.x;
  int v = (i < n) ? counts[i] : 0;
  buf[threadIdx.x] = v; __syncthreads();
  for (int off = 1; off < 256; off <<= 1){
    int t = (threadIdx.x >= off) ? buf[threadIdx.x - off] : 0;
    __syncthreads();
    buf[threadIdx.x] += t;
    __syncthreads();
  }
  if (i < n) offsets[i] = buf[threadIdx.x] - v;
  if (threadIdx.x == 255) bsum[blockIdx.x] = buf[255];
}

__global__ void k_scanB(int* __restrict__ bsum, int nb){
  __shared__ int buf[256];
  int v = (threadIdx.x < nb) ? bsum[threadIdx.x] : 0;
  buf[threadIdx.x] = v; __syncthreads();
  for (int off = 1; off < 256; off <<= 1){
    int t = (threadIdx.x >= off) ? buf[threadIdx.x - off] : 0;
    __syncthreads();
    buf[threadIdx.x] += t;
    __syncthreads();
  }
  if (threadIdx.x < nb) bsum[threadIdx.x] = buf[threadIdx.x] - v;
}

__global__ void k_scanC(int* __restrict__ offsets, int* __restrict__ cursor,
                        const int* __restrict__ bsum, int n){
  int i = blockIdx.x*256 + threadIdx.x;
  if (i < n){ int o = offsets[i] + bsum[blockIdx.x]; offsets[i] = o; cursor[i] = o; }
}

__global__ void k_scatter(const int* __restrict__ ei, const float* __restrict__ ea,
                          int* __restrict__ cursor,
                          int* __restrict__ csr_src, int* __restrict__ csr_dst,
                          int* __restrict__ csr_eid, float* __restrict__ ea_csr, int E){
  for (int e = blockIdx.x*blockDim.x + threadIdx.x; e < E; e += gridDim.x*blockDim.x){
    int c = ei[E + e];
    int p = atomicAdd(&cursor[c], 1);
    csr_src[p] = ei[e];
    csr_dst[p] = c;
    csr_eid[p] = e;
    *(float4*)&ea_csr[(size_t)p*4] = *(const float4*)&ea[(size_t)e*4];
  }
}

// ---------------- weight conversion to bf16 ----------------
// V2 layout [160][128]: rows 0..63 = Wf1 P-part, 64..127 = Wf1 Q-part, 128..159 = Wd1
__global__ void k_wconv(const float* __restrict__ W2l, const float* __restrict__ W2r,
                        const float* __restrict__ Wih, const float* __restrict__ Whh,
                        const float* __restrict__ Wf1, const float* __restrict__ Wd1,
                        unsigned short* __restrict__ W2l_bf, unsigned short* __restrict__ W2r_bf,
                        unsigned short* __restrict__ Wih_bf, unsigned short* __restrict__ Whh_bf,
                        unsigned short* __restrict__ V2_bf){
  int stride = gridDim.x*blockDim.x;
  for (int i = blockIdx.x*blockDim.x + threadIdx.x; i < 49152; i += stride){
    if (i < 16384){
      W2l_bf[i] = f2bf(W2l[i]);
      W2r_bf[i] = f2bf(W2r[i]);
    }
    if (i < 20480){
      int j = i >> 7, k = i & 127;
      float v;
      if (j < 64)        v = Wf1[j*260 + k];
      else if (j < 128)  v = Wf1[(j-64)*260 + 128 + k];
      else               v = Wd1[(j-128)*128 + k];
      V2_bf[i] = f2bf(v);
    }
    Wih_bf[i] = f2bf(Wih[i]);
    Whh_bf[i] = f2bf(Whh[i]);
  }
}

// ---------------- aggx: mean of x (30-dim) rows ----------------
__global__ __launch_bounds__(256) void k_aggx(
    const float* __restrict__ x, const int* __restrict__ csr_src,
    const int* __restrict__ offsets, const int* __restrict__ counts,
    float* __restrict__ aggx, int N)
{
  int t = blockIdx.x*blockDim.x + threadIdx.x;
  int gw = t >> 6, lane = t & 63;
  int nw = (gridDim.x*blockDim.x) >> 6;
  int half = lane >> 5, c = lane & 31;
  bool act = (c < IN_DIM);
  for (int d = gw; d < N; d += nw){
    int base = offsets[d], cnt = counts[d];
    float s = 0.f;
    for (int i = half; i < cnt; i += 2){
      int sr = csr_src[base + i];
      if (act) s += x[(size_t)sr*IN_DIM + c];
    }
    s += __shfl_xor(s, 32);
    if (lane < 32){
      float inv = 1.f / (float)(cnt > 0 ? cnt : 1);
      aggx[d*32 + c] = act ? s*inv : 0.f;
    }
  }
}

// ---------------- lin1 ----------------
__global__ __launch_bounds__(256) void k_lin1(
    const float* __restrict__ aggx, const float* __restrict__ x,
    const float* __restrict__ W1l, const float* __restrict__ b1l,
    const float* __restrict__ W1r, unsigned short* __restrict__ x1bf, int N)
{
  int tid = threadIdx.x;
  int slot = tid >> 7, c = tid & 127;
  float wl[IN_DIM], wr[IN_DIM];
  #pragma unroll
  for (int k = 0; k < IN_DIM; k++){ wl[k] = W1l[c*IN_DIM + k]; wr[k] = W1r[c*IN_DIM + k]; }
  float bc = b1l[c];
  for (int d0 = blockIdx.x*2; d0 < N; d0 += gridDim.x*2){
    int d = d0 + slot;
    if (d >= N) continue;
    float s = bc;
    const float* ag = &aggx[d*32];
    const float* xd = &x[(size_t)d*IN_DIM];
    #pragma unroll
    for (int k = 0; k < IN_DIM; k++) s += ag[k]*wl[k] + xd[k]*wr[k];
    x1bf[(size_t)d*H + c] = f2bf(fmaxf(s, 0.f));
  }
}

// ---------------- agg2 ----------------
__global__ __launch_bounds__(256) void k_agg2(
    const unsigned short* __restrict__ x1bf, const int* __restrict__ csr_src,
    const int* __restrict__ offsets, const int* __restrict__ counts,
    unsigned short* __restrict__ agg2bf, int N)
{
  int t = blockIdx.x*blockDim.x + threadIdx.x;
  int gw = t >> 6, lane = t & 63;
  int nw = (gridDim.x*blockDim.x) >> 6;
  const unsigned int* x1u = (const unsigned int*)x1bf;
  unsigned int* agu = (unsigned int*)agg2bf;
  for (int d = gw; d < N; d += nw){
    int base = offsets[d], cnt = counts[d];
    float a0 = 0.f, a1 = 0.f;
    int i = 0;
    for (; i + 3 < cnt; i += 4){
      int s0 = csr_src[base + i],     s1 = csr_src[base + i + 1];
      int s2 = csr_src[base + i + 2], s3 = csr_src[base + i + 3];
      unsigned int v0 = x1u[(size_t)s0*64 + lane];
      unsigned int v1 = x1u[(size_t)s1*64 + lane];
      unsigned int v2 = x1u[(size_t)s2*64 + lane];
      unsigned int v3 = x1u[(size_t)s3*64 + lane];
      a0 += bf2f((unsigned short)(v0 & 0xffff)) + bf2f((unsigned short)(v1 & 0xffff))
          + bf2f((unsigned short)(v2 & 0xffff)) + bf2f((unsigned short)(v3 & 0xffff));
      a1 += bf2f((unsigned short)(v0 >> 16)) + bf2f((unsigned short)(v1 >> 16))
          + bf2f((unsigned short)(v2 >> 16)) + bf2f((unsigned short)(v3 >> 16));
    }
    for (; i < cnt; i++){
      unsigned int v = x1u[(size_t)csr_src[base + i]*64 + lane];
      a0 += bf2f((unsigned short)(v & 0xffff));
      a1 += bf2f((unsigned short)(v >> 16));
    }
    float inv = 1.f / (float)(cnt > 0 ? cnt : 1);
    unsigned int o = (unsigned int)f2bf(a0*inv) | ((unsigned int)f2bf(a1*inv) << 16);
    agu[(size_t)d*64 + lane] = o;
  }
}

// ============ strip GEMM kernels: 512 thr, 128-row strips, LDS-staged A ============

// ---------------- SAGE2: x2 = relu(agg2@W2l.T + b2l + x1@W2r.T) ----------------
__global__ __launch_bounds__(512) void k_dual2(
    const unsigned short* __restrict__ Abf, const unsigned short* __restrict__ Bbf,
    const unsigned short* __restrict__ Wa, const unsigned short* __restrict__ Wb,
    const float* __restrict__ bias, unsigned short* __restrict__ outbf, int N)
{
  __shared__ unsigned short sA[128*LDSP];
  __shared__ unsigned short sB[128*LDSP];
  int tid = threadIdx.x;
  int wid = tid >> 6, l = tid & 63, m16 = l & 15, g4 = l >> 4;
  int col = wid*16 + m16;
  bf16x8 wa[4], wb[4];
  #pragma unroll
  for (int kb = 0; kb < 4; kb++){
    wa[kb] = ldfrag(Wa + (size_t)col*H + kb*32 + g4*8);
    wb[kb] = ldfrag(Wb + (size_t)col*H + kb*32 + g4*8);
  }
  float bc = bias[col];
  int nstrips = (N + 127) >> 7;
  for (int s = blockIdx.x; s < nstrips; s += gridDim.x){
    int base = s << 7;
    __syncthreads();
    for (int c = tid; c < 4096; c += 512){
      int mat = c >> 11, cc = c & 2047;
      int row = cc >> 4, co = cc & 15;
      int gr = min(base + row, N-1);
      u16x8 v = *(const u16x8*)((mat ? Bbf : Abf) + (size_t)gr*H + co*8);
      *(u16x8*)&((mat ? sB : sA)[row*LDSP + co*8]) = v;
    }
    __syncthreads();
    #pragma unroll 1
    for (int rt = 0; rt < 8; rt++){
      int rb = rt*16;
      f32x4 acc = {bc, bc, bc, bc};
      #pragma unroll
      for (int kb = 0; kb < 4; kb++){
        bf16x8 a = *(const bf16x8*)&sA[(rb + m16)*LDSP + kb*32 + g4*8];
        acc = __builtin_amdgcn_mfma_f32_16x16x32_bf16(a, wa[kb], acc, 0, 0, 0);
        bf16x8 b = *(const bf16x8*)&sB[(rb + m16)*LDSP + kb*32 + g4*8];
        acc = __builtin_amdgcn_mfma_f32_16x16x32_bf16(b, wb[kb], acc, 0, 0, 0);
      }
      #pragma unroll
      for (int j = 0; j < 4; j++){
        int row = base + rb + g4*4 + j;
        if (row < N)
          outbf[(size_t)row*H + col] = f2bf(fmaxf(acc[j], 0.f));
      }
    }
  }
}

// ---------------- fused GRU (stages h f32 -> bf16 inline) ----------------
__global__ __launch_bounds__(512) void k_gru2(
    const unsigned short* __restrict__ x2bf, const float* __restrict__ h,
    const unsigned short* __restrict__ Wih_bf, const unsigned short* __restrict__ Whh_bf,
    const float* __restrict__ bih, const float* __restrict__ bhh,
    float* __restrict__ hnew, unsigned short* __restrict__ hnewbf, int N)
{
  __shared__ unsigned short sX[128*LDSP];
  __shared__ unsigned short sH[128*LDSP];
  int tid = threadIdx.x;
  int wid = tid >> 6, l = tid & 63, m16 = l & 15, g4 = l >> 4;
  int col = wid*16 + m16;
  bf16x8 wih[3][4], whh[3][4];
  #pragma unroll
  for (int g = 0; g < 3; g++){
    #pragma unroll
    for (int kb = 0; kb < 4; kb++){
      wih[g][kb] = ldfrag(Wih_bf + (size_t)(g*H + col)*H + kb*32 + g4*8);
      whh[g][kb] = ldfrag(Whh_bf + (size_t)(g*H + col)*H + kb*32 + g4*8);
    }
  }
  float bir = bih[col],       bhr = bhh[col];
  float biz = bih[H + col],   bhz = bhh[H + col];
  float bin = bih[2*H + col], bhn = bhh[2*H + col];
  int nstrips = (N + 127) >> 7;
  for (int s = blockIdx.x; s < nstrips; s += gridDim.x){
    int base = s << 7;
    __syncthreads();
    for (int c = tid; c < 4096; c += 512){
      int mat = c >> 11, cc = c & 2047;
      int row = cc >> 4, co = cc & 15;
      int gr = min(base + row, N-1);
      if (mat == 0){
        u16x8 v = *(const u16x8*)(x2bf + (size_t)gr*H + co*8);
        *(u16x8*)&sX[row*LDSP + co*8] = v;
      } else {
        float4 f0 = *(const float4*)(h + (size_t)gr*H + co*8);
        float4 f1 = *(const float4*)(h + (size_t)gr*H + co*8 + 4);
        u16x8 v;
        v[0] = f2bf(f0.x); v[1] = f2bf(f0.y); v[2] = f2bf(f0.z); v[3] = f2bf(f0.w);
        v[4] = f2bf(f1.x); v[5] = f2bf(f1.y); v[6] = f2bf(f1.z); v[7] = f2bf(f1.w);
        *(u16x8*)&sH[row*LDSP + co*8] = v;
      }
    }
    __syncthreads();
    #pragma unroll 1
    for (int rt = 0; rt < 8; rt++){
      int rb = rt*16;
      bf16x8 aX[4], aH[4];
      #pragma unroll
      for (int kb = 0; kb < 4; kb++){
        aX[kb] = *(const bf16x8*)&sX[(rb + m16)*LDSP + kb*32 + g4*8];
        aH[kb] = *(const bf16x8*)&sH[(rb + m16)*LDSP + kb*32 + g4*8];
      }
      f32x4 aRi = {bir,bir,bir,bir}, aRh = {bhr,bhr,bhr,bhr};
      f32x4 aZi = {biz,biz,biz,biz}, aZh = {bhz,bhz,bhz,bhz};
      f32x4 aNi = {bin,bin,bin,bin}, aNh = {bhn,bhn,bhn,bhn};
      #pragma unroll
      for (int kb = 0; kb < 4; kb++){
        aRi = __builtin_amdgcn_mfma_f32_16x16x32_bf16(aX[kb], wih[0][kb], aRi, 0,0,0);
        aRh = __builtin_amdgcn_mfma_f32_16x16x32_bf16(aH[kb], whh[0][kb], aRh, 0,0,0);
        aZi = __builtin_amdgcn_mfma_f32_16x16x32_bf16(aX[kb], wih[1][kb], aZi, 0,0,0);
        aZh = __builtin_amdgcn_mfma_f32_16x16x32_bf16(aH[kb], whh[1][kb], aZh, 0,0,0);
        aNi = __builtin_amdgcn_mfma_f32_16x16x32_bf16(aX[kb], wih[2][kb], aNi, 0,0,0);
        aNh = __builtin_amdgcn_mfma_f32_16x16x32_bf16(aH[kb], whh[2][kb], aNh, 0,0,0);
      }
      #pragma unroll
      for (int j = 0; j < 4; j++){
        int row = base + rb + g4*4 + j;
        if (row < N){
          float r = 1.f / (1.f + expf(-(aRi[j] + aRh[j])));
          float z = 1.f / (1.f + expf(-(aZi[j] + aZh[j])));
          float nn = tanhf(aNi[j] + r*aNh[j]);
          float hv = bf2f(sH[(rb + g4*4 + j)*LDSP + col]);
          float o = (1.f - z)*nn + z*hv;
          hnew[(size_t)row*H + col] = o;
          hnewbf[(size_t)row*H + col] = f2bf(o);
        }
      }
    }
  }
}

// ---------------- proj: PQ (bf16, cols 0..127) and D1 (relu f32, V2 rows 128..159) ----------------
__global__ __launch_bounds__(512) void k_proj2(
    const unsigned short* __restrict__ hnewbf, const unsigned short* __restrict__ V2_bf,
    const float* __restrict__ bd1,
    unsigned short* __restrict__ PQbf, float* __restrict__ D1, int N)
{
  __shared__ unsigned short sHn[128*LDSP];
  int tid = threadIdx.x;
  int wid = tid >> 6, l = tid & 63, m16 = l & 15, g4 = l >> 4;
  int col = wid*16 + m16;
  bf16x8 v1[4], v2[4];
  #pragma unroll
  for (int kb = 0; kb < 4; kb++)
    v1[kb] = ldfrag(V2_bf + (size_t)col*H + kb*32 + g4*8);
  int dc = wid*16 + m16;
  float bdv = 0.f;
  if (wid < 2){
    #pragma unroll
    for (int kb = 0; kb < 4; kb++)
      v2[kb] = ldfrag(V2_bf + (size_t)(128 + dc)*H + kb*32 + g4*8);
    bdv = bd1[dc];
  }
  int nstrips = (N + 127) >> 7;
  for (int s = blockIdx.x; s < nstrips; s += gridDim.x){
    int base = s << 7;
    __syncthreads();
    for (int c = tid; c < 2048; c += 512){
      int row = c >> 4, co = c & 15;
      int gr = min(base + row, N-1);
      u16x8 v = *(const u16x8*)(hnewbf + (size_t)gr*H + co*8);
      *(u16x8*)&(sHn[row*LDSP + co*8]) = v;
    }
    __syncthreads();
    #pragma unroll 1
    for (int rt = 0; rt < 8; rt++){
      int rb = rt*16;
      bf16x8 aH[4];
      #pragma unroll
      for (int kb = 0; kb < 4; kb++)
        aH[kb] = *(const bf16x8*)&sHn[(rb + m16)*LDSP + kb*32 + g4*8];
      f32x4 acc = {0.f, 0.f, 0.f, 0.f};
      #pragma unroll
      for (int kb = 0; kb < 4; kb++)
        acc = __builtin_amdgcn_mfma_f32_16x16x32_bf16(aH[kb], v1[kb], acc, 0, 0, 0);
      #pragma unroll
      for (int j = 0; j < 4; j++){
        int row = base + rb + g4*4 + j;
        if (row < N)
          PQbf[(size_t)row*H + col] = f2bf(acc[j]);
      }
      if (wid < 2){
        f32x4 acc2 = {0.f, 0.f, 0.f, 0.f};
        #pragma unroll
        for (int kb = 0; kb < 4; kb++)
          acc2 = __builtin_amdgcn_mfma_f32_16x16x32_bf16(aH[kb], v2[kb], acc2, 0, 0, 0);
        #pragma unroll
        for (int j = 0; j < 4; j++){
          int row = base + rb + g4*4 + j;
          if (row < N)
            D1[(size_t)row*32 + dc] = fmaxf(acc2[j] + bdv, 0.f);
        }
      }
    }
  }
}

// ---------------- disp from D1: 32-lane group per node ----------------
__global__ __launch_bounds__(256) void k_disp2(
    const float* __restrict__ D1, const float* __restrict__ Wd2,
    const float* __restrict__ bd2, float* __restrict__ disp, int N)
{
  int t = blockIdx.x*blockDim.x + threadIdx.x;
  int gh = t >> 5, sub = t & 31;
  int nh = (gridDim.x*blockDim.x) >> 5;
  float w0 = Wd2[sub], w1 = Wd2[32 + sub], w2 = Wd2[64 + sub];
  float bo = (sub < 3) ? bd2[sub] : 0.f;
  for (int d = gh; d < N; d += nh){
    float v = D1[(size_t)d*32 + sub];
    float v0 = v*w0, v1 = v*w1, v2 = v*w2;
    #pragma unroll
    for (int off = 1; off < 32; off <<= 1){
      v0 += __shfl_xor(v0, off, 32);
      v1 += __shfl_xor(v1, off, 32);
      v2 += __shfl_xor(v2, off, 32);
    }
    if (sub < 3) disp[(size_t)d*3 + sub] = (sub == 0 ? v0 : (sub == 1 ? v1 : v2)) + bo;
  }
}

// ---------------- force decoder: MFMA over 16-edge tiles, CSR (dst-sorted) order ----------------
__global__ __launch_bounds__(256) void k_force2(
    const int* __restrict__ csr_src, const int* __restrict__ csr_dst,
    const int* __restrict__ csr_eid, const float* __restrict__ ea_csr,
    const unsigned short* __restrict__ PQbf,
    const float* __restrict__ Wf1, const float* __restrict__ bf1,
    const float* __restrict__ Wf2, const float* __restrict__ bf2,
    float* __restrict__ out, int E)
{
  int l = threadIdx.x & 63;
  int r = l & 15, g = l >> 4;
  float4 wc[2][8];
  float b1r[2][8];
  bf16x8 bfr[2];
  float bo = (r < 3) ? bf2[r] : 0.f;
  #pragma unroll
  for (int kb = 0; kb < 2; kb++){
    bf16x8 bf_;
    #pragma unroll
    for (int j = 0; j < 8; j++){
      int k = kb*32 + g*8 + j;
      wc[kb][j] = *(const float4*)&Wf1[k*260 + 256];
      b1r[kb][j] = bf1[k];
      bf_[j] = (r < 3) ? (short)f2bf(Wf2[r*64 + k]) : (short)0;
    }
    bfr[kb] = bf_;
  }
  int nt = (E + 15) >> 4;
  for (int t = blockIdx.x*4 + (threadIdx.x >> 6); t < nt; t += gridDim.x*4){
    int p = t*16 + r;
    int pc = min(p, E-1);
    int src = csr_src[pc], dst = csr_dst[pc];
    float4 a4 = *(const float4*)&ea_csr[(size_t)pc*4];
    bf16x8 afr[2];
    #pragma unroll
    for (int kb = 0; kb < 2; kb++){
      u16x8 p8 = *(const u16x8*)&PQbf[(size_t)src*H + kb*32 + g*8];
      u16x8 q8 = *(const u16x8*)&PQbf[(size_t)dst*H + 64 + kb*32 + g*8];
      bf16x8 af;
      #pragma unroll
      for (int j = 0; j < 8; j++){
        float pre = bf2f(p8[j]) + bf2f(q8[j]) + b1r[kb][j]
                  + a4.x*wc[kb][j].x + a4.y*wc[kb][j].y
                  + a4.z*wc[kb][j].z + a4.w*wc[kb][j].w;
        af[j] = (short)f2bf(fmaxf(pre, 0.f));
      }
      afr[kb] = af;
    }
    f32x4 acc = {0.f, 0.f, 0.f, 0.f};
    acc = __builtin_amdgcn_mfma_f32_16x16x32_bf16(afr[0], bfr[0], acc, 0, 0, 0);
    acc = __builtin_amdgcn_mfma_f32_16x16x32_bf16(afr[1], bfr[1], acc, 0, 0, 0);
    if (r < 3){
      #pragma unroll
      for (int j = 0; j < 4; j++){
        int pos = t*16 + g*4 + j;
        if (pos < E){
          int eo = csr_eid[pos];
          out[(size_t)eo*3 + r] = acc[j] + bo;
        }
      }
    }
  }
}

extern "C" void kernel_launch(void* const* d_in, const int* in_sizes, int n_in,
                              void* d_out, int out_size, void* d_ws, size_t ws_size,
                              hipStream_t stream)
{
  const float* x   = (const float*)d_in[0];
  const int*   ei  = (const int*)d_in[1];
  const float* ea  = (const float*)d_in[2];
  const float* h   = (const float*)d_in[3];
  const float* W1l = (const float*)d_in[4];
  const float* b1l = (const float*)d_in[5];
  const float* W1r = (const float*)d_in[6];
  const float* W2l = (const float*)d_in[7];
  const float* b2l = (const float*)d_in[8];
  const float* W2r = (const float*)d_in[9];
  const float* Wih = (const float*)d_in[10];
  const float* Whh = (const float*)d_in[11];
  const float* bih = (const float*)d_in[12];
  const float* bhh = (const float*)d_in[13];
  const float* Wd1 = (const float*)d_in[14];
  const float* bd1 = (const float*)d_in[15];
  const float* Wd2 = (const float*)d_in[16];
  const float* bd2 = (const float*)d_in[17];
  const float* Wf1 = (const float*)d_in[18];
  const float* bf1 = (const float*)d_in[19];
  const float* Wf2 = (const float*)d_in[20];
  const float* bf2 = (const float*)d_in[21];

  int N = in_sizes[0] / IN_DIM;
  int E = in_sizes[1] / 2;

  char* ws = (char*)d_ws;
  size_t off = 0;
  auto alloc = [&](size_t bytes) -> char* {
    char* p = ws + off;
    off = (off + bytes + 255) & ~(size_t)255;
    return p;
  };
  int* counts   = (int*)alloc((size_t)N*4);
  int* offsets  = (int*)alloc((size_t)N*4);
  int* cursor   = (int*)alloc((size_t)N*4);
  int* bsum     = (int*)alloc(1024);
  int* csr_src  = (int*)alloc((size_t)E*4);
  int* csr_dst  = (int*)alloc((size_t)E*4);
  int* csr_eid  = (int*)alloc((size_t)E*4);
  float* ea_csr = (float*)alloc((size_t)E*16);
  // pool: aggx(6.4MB) | x1bf(12.8MB) | agg2bf(12.8MB); reused post-GRU:
  //   PQbf (12.8MB) over aggx+x1bf; D1 (6.4MB) over agg2bf
  float* aggx            = (float*)alloc((size_t)N*32*4);
  unsigned short* x1bf   = (unsigned short*)alloc((size_t)N*H*2);
  unsigned short* agg2bf = (unsigned short*)alloc((size_t)N*H*2);
  unsigned short* PQbf = (unsigned short*)aggx;
  float* D1            = (float*)agg2bf;
  unsigned short* x2bf   = (unsigned short*)alloc((size_t)N*H*2);
  unsigned short* hnewbf = (unsigned short*)alloc((size_t)N*H*2);
  unsigned short* W2l_bf = (unsigned short*)alloc(16384*2);
  unsigned short* W2r_bf = (unsigned short*)alloc(16384*2);
  unsigned short* Wih_bf = (unsigned short*)alloc(49152*2);
  unsigned short* Whh_bf = (unsigned short*)alloc(49152*2);
  unsigned short* V2_bf  = (unsigned short*)alloc(20480*2);

  float* disp  = (float*)d_out;
  float* force = disp + (size_t)N*3;
  float* hnew  = force + (size_t)E*3;

  hipMemsetAsync(counts, 0, (size_t)N*4, stream);
  int nb = (N + 255) / 256;
  k_count  <<<2048, 256, 0, stream>>>(ei + E, counts, E);
  k_scanA  <<<nb, 256, 0, stream>>>(counts, offsets, bsum, N);
  k_scanB  <<<1, 256, 0, stream>>>(bsum, nb);
  k_scanC  <<<nb, 256, 0, stream>>>(offsets, cursor, bsum, N);
  k_scatter<<<2048, 256, 0, stream>>>(ei, ea, cursor, csr_src, csr_dst, csr_eid, ea_csr, E);

  k_wconv  <<<192, 256, 0, stream>>>(W2l, W2r, Wih, Whh, Wf1, Wd1,
                                     W2l_bf, W2r_bf, Wih_bf, Whh_bf, V2_bf);

  k_aggx   <<<4096, 256, 0, stream>>>(x, csr_src, offsets, counts, aggx, N);
  k_lin1   <<<2048, 256, 0, stream>>>(aggx, x, W1l, b1l, W1r, x1bf, N);
  k_agg2   <<<4096, 256, 0, stream>>>(x1bf, csr_src, offsets, counts, agg2bf, N);

  int nstrips = (N + 127) / 128;
  k_dual2  <<<nstrips, 512, 0, stream>>>(agg2bf, x1bf, W2l_bf, W2r_bf, b2l, x2bf, N);
  k_gru2   <<<nstrips, 512, 0, stream>>>(x2bf, h, Wih_bf, Whh_bf, bih, bhh, hnew, hnewbf, N);
  k_proj2  <<<nstrips, 512, 0, stream>>>(hnewbf, V2_bf, bd1, PQbf, D1, N);
  k_disp2  <<<1024, 256, 0, stream>>>(D1, Wd2, bd2, disp, N);
  k_force2 <<<2048, 256, 0, stream>>>(csr_src, csr_dst, csr_eid, ea_csr, PQbf,
                                      Wf1, bf1, Wf2, bf2, force, E);
}

// Round 7
// 380.348 us; speedup vs baseline: 3.1670x; 1.0420x over previous
//
#include <hip/hip_runtime.h>
#include <hip/hip_bf16.h>

#define H 128
#define IN_DIM 30
#define LDSP 136  // padded row stride (ushorts) for staged activations

typedef __attribute__((ext_vector_type(8))) short bf16x8;
typedef __attribute__((ext_vector_type(8))) unsigned short u16x8;
typedef __attribute__((ext_vector_type(4))) float f32x4;

__device__ inline unsigned short f2bf(float f){
  unsigned int u = __builtin_bit_cast(unsigned int, f);
  unsigned int r = u + 0x7FFF + ((u >> 16) & 1);
  return (unsigned short)(r >> 16);
}
__device__ inline float bf2f(unsigned short b){
  unsigned int u = ((unsigned int)b) << 16;
  return __builtin_bit_cast(float, u);
}
__device__ inline bf16x8 ldfrag(const unsigned short* p){
  return *(const bf16x8*)p;
}

// ---------------- CSR build ----------------
__global__ void k_count(const int* __restrict__ col, int* __restrict__ counts, int E){
  for (int e = blockIdx.x*blockDim.x + threadIdx.x; e < E; e += gridDim.x*blockDim.x)
    atomicAdd(&counts[col[e]], 1);
}

__global__ void k_scanA(const int* __restrict__ counts, int* __restrict__ offsets,
                        int* __restrict__ bsum, int n){
  __shared__ int buf[256];
  int i = blockIdx.x*256 + threadIdx.x;
  int v = (i < n) ? counts[i] : 0;
  buf[threadIdx.x] = v; __syncthreads();
  for (int off = 1; off < 256; off <<= 1){
    int t = (threadIdx.x >= off) ? buf[threadIdx.x - off] : 0;
    __syncthreads();
    buf[threadIdx.x] += t;
    __syncthreads();
  }
  if (i < n) offsets[i] = buf[threadIdx.x] - v;
  if (threadIdx.x == 255) bsum[blockIdx.x] = buf[255];
}

__global__ void k_scanB(int* __restrict__ bsum, int nb){
  __shared__ int buf[256];
  int v = (threadIdx.x < nb) ? bsum[threadIdx.x] : 0;
  buf[threadIdx.x] = v; __syncthreads();
  for (int off = 1; off < 256; off <<= 1){
    int t = (threadIdx.x >= off) ? buf[threadIdx.x - off] : 0;
    __syncthreads();
    buf[threadIdx.x] += t;
    __syncthreads();
  }
  if (threadIdx.x < nb) bsum[threadIdx.x] = buf[threadIdx.x] - v;
}

__global__ void k_scanC(int* __restrict__ offsets, int* __restrict__ cursor,
                        const int* __restrict__ bsum, int n){
  int i = blockIdx.x*256 + threadIdx.x;
  if (i < n){ int o = offsets[i] + bsum[blockIdx.x]; offsets[i] = o; cursor[i] = o; }
}

__global__ void k_scatter(const int* __restrict__ ei, int* __restrict__ cursor,
                          int* __restrict__ csr, int E){
  for (int e = blockIdx.x*blockDim.x + threadIdx.x; e < E; e += gridDim.x*blockDim.x){
    int c = ei[E + e];
    int p = atomicAdd(&cursor[c], 1);
    csr[p] = ei[e];
  }
}

// ---------------- weight conversion to bf16 ----------------
// V2 layout [160][128]: rows 0..63 = Wf1 P-part, 64..127 = Wf1 Q-part, 128..159 = Wd1
__global__ void k_wconv(const float* __restrict__ W2l, const float* __restrict__ W2r,
                        const float* __restrict__ Wih, const float* __restrict__ Whh,
                        const float* __restrict__ Wf1, const float* __restrict__ Wd1,
                        unsigned short* __restrict__ W2l_bf, unsigned short* __restrict__ W2r_bf,
                        unsigned short* __restrict__ Wih_bf, unsigned short* __restrict__ Whh_bf,
                        unsigned short* __restrict__ V2_bf){
  int stride = gridDim.x*blockDim.x;
  for (int i = blockIdx.x*blockDim.x + threadIdx.x; i < 49152; i += stride){
    if (i < 16384){
      W2l_bf[i] = f2bf(W2l[i]);
      W2r_bf[i] = f2bf(W2r[i]);
    }
    if (i < 20480){
      int j = i >> 7, k = i & 127;
      float v;
      if (j < 64)        v = Wf1[j*260 + k];
      else if (j < 128)  v = Wf1[(j-64)*260 + 128 + k];
      else               v = Wd1[(j-128)*128 + k];
      V2_bf[i] = f2bf(v);
    }
    Wih_bf[i] = f2bf(Wih[i]);
    Whh_bf[i] = f2bf(Whh[i]);
  }
}

// ---------------- aggx: mean of x (30-dim) rows ----------------
__global__ __launch_bounds__(256) void k_aggx(
    const float* __restrict__ x, const int* __restrict__ csr,
    const int* __restrict__ offsets, const int* __restrict__ counts,
    float* __restrict__ aggx, int N)
{
  int t = blockIdx.x*blockDim.x + threadIdx.x;
  int gw = t >> 6, lane = t & 63;
  int nw = (gridDim.x*blockDim.x) >> 6;
  int half = lane >> 5, c = lane & 31;
  bool act = (c < IN_DIM);
  for (int d = gw; d < N; d += nw){
    int base = offsets[d], cnt = counts[d];
    float s = 0.f;
    for (int i = half; i < cnt; i += 2){
      int sr = csr[base + i];
      if (act) s += x[(size_t)sr*IN_DIM + c];
    }
    s += __shfl_xor(s, 32);
    if (lane < 32){
      float inv = 1.f / (float)(cnt > 0 ? cnt : 1);
      aggx[d*32 + c] = act ? s*inv : 0.f;
    }
  }
}

// ---------------- lin1 ----------------
__global__ __launch_bounds__(256) void k_lin1(
    const float* __restrict__ aggx, const float* __restrict__ x,
    const float* __restrict__ W1l, const float* __restrict__ b1l,
    const float* __restrict__ W1r, unsigned short* __restrict__ x1bf, int N)
{
  int tid = threadIdx.x;
  int slot = tid >> 7, c = tid & 127;
  float wl[IN_DIM], wr[IN_DIM];
  #pragma unroll
  for (int k = 0; k < IN_DIM; k++){ wl[k] = W1l[c*IN_DIM + k]; wr[k] = W1r[c*IN_DIM + k]; }
  float bc = b1l[c];
  for (int d0 = blockIdx.x*2; d0 < N; d0 += gridDim.x*2){
    int d = d0 + slot;
    if (d >= N) continue;
    float s = bc;
    const float* ag = &aggx[d*32];
    const float* xd = &x[(size_t)d*IN_DIM];
    #pragma unroll
    for (int k = 0; k < IN_DIM; k++) s += ag[k]*wl[k] + xd[k]*wr[k];
    x1bf[(size_t)d*H + c] = f2bf(fmaxf(s, 0.f));
  }
}

// ---------------- agg2 ----------------
__global__ __launch_bounds__(256) void k_agg2(
    const unsigned short* __restrict__ x1bf, const int* __restrict__ csr,
    const int* __restrict__ offsets, const int* __restrict__ counts,
    unsigned short* __restrict__ agg2bf, int N)
{
  int t = blockIdx.x*blockDim.x + threadIdx.x;
  int gw = t >> 6, lane = t & 63;
  int nw = (gridDim.x*blockDim.x) >> 6;
  const unsigned int* x1u = (const unsigned int*)x1bf;
  unsigned int* agu = (unsigned int*)agg2bf;
  for (int d = gw; d < N; d += nw){
    int base = offsets[d], cnt = counts[d];
    float a0 = 0.f, a1 = 0.f;
    int i = 0;
    for (; i + 3 < cnt; i += 4){
      int s0 = csr[base + i],     s1 = csr[base + i + 1];
      int s2 = csr[base + i + 2], s3 = csr[base + i + 3];
      unsigned int v0 = x1u[(size_t)s0*64 + lane];
      unsigned int v1 = x1u[(size_t)s1*64 + lane];
      unsigned int v2 = x1u[(size_t)s2*64 + lane];
      unsigned int v3 = x1u[(size_t)s3*64 + lane];
      a0 += bf2f((unsigned short)(v0 & 0xffff)) + bf2f((unsigned short)(v1 & 0xffff))
          + bf2f((unsigned short)(v2 & 0xffff)) + bf2f((unsigned short)(v3 & 0xffff));
      a1 += bf2f((unsigned short)(v0 >> 16)) + bf2f((unsigned short)(v1 >> 16))
          + bf2f((unsigned short)(v2 >> 16)) + bf2f((unsigned short)(v3 >> 16));
    }
    for (; i < cnt; i++){
      unsigned int v = x1u[(size_t)csr[base + i]*64 + lane];
      a0 += bf2f((unsigned short)(v & 0xffff));
      a1 += bf2f((unsigned short)(v >> 16));
    }
    float inv = 1.f / (float)(cnt > 0 ? cnt : 1);
    unsigned int o = (unsigned int)f2bf(a0*inv) | ((unsigned int)f2bf(a1*inv) << 16);
    agu[(size_t)d*64 + lane] = o;
  }
}

// ============ strip GEMM kernels: 512 thr, 128-row strips, LDS-staged A ============

// ---------------- SAGE2: x2 = relu(agg2@W2l.T + b2l + x1@W2r.T) ----------------
__global__ __launch_bounds__(512) void k_dual2(
    const unsigned short* __restrict__ Abf, const unsigned short* __restrict__ Bbf,
    const unsigned short* __restrict__ Wa, const unsigned short* __restrict__ Wb,
    const float* __restrict__ bias, unsigned short* __restrict__ outbf, int N)
{
  __shared__ unsigned short sA[128*LDSP];
  __shared__ unsigned short sB[128*LDSP];
  int tid = threadIdx.x;
  int wid = tid >> 6, l = tid & 63, m16 = l & 15, g4 = l >> 4;
  int col = wid*16 + m16;
  bf16x8 wa[4], wb[4];
  #pragma unroll
  for (int kb = 0; kb < 4; kb++){
    wa[kb] = ldfrag(Wa + (size_t)col*H + kb*32 + g4*8);
    wb[kb] = ldfrag(Wb + (size_t)col*H + kb*32 + g4*8);
  }
  float bc = bias[col];
  int nstrips = (N + 127) >> 7;
  for (int s = blockIdx.x; s < nstrips; s += gridDim.x){
    int base = s << 7;
    __syncthreads();
    for (int c = tid; c < 4096; c += 512){
      int mat = c >> 11, cc = c & 2047;
      int row = cc >> 4, co = cc & 15;
      int gr = min(base + row, N-1);
      u16x8 v = *(const u16x8*)((mat ? Bbf : Abf) + (size_t)gr*H + co*8);
      *(u16x8*)&((mat ? sB : sA)[row*LDSP + co*8]) = v;
    }
    __syncthreads();
    #pragma unroll 1
    for (int rt = 0; rt < 8; rt++){
      int rb = rt*16;
      f32x4 acc = {bc, bc, bc, bc};
      #pragma unroll
      for (int kb = 0; kb < 4; kb++){
        bf16x8 a = *(const bf16x8*)&sA[(rb + m16)*LDSP + kb*32 + g4*8];
        acc = __builtin_amdgcn_mfma_f32_16x16x32_bf16(a, wa[kb], acc, 0, 0, 0);
        bf16x8 b = *(const bf16x8*)&sB[(rb + m16)*LDSP + kb*32 + g4*8];
        acc = __builtin_amdgcn_mfma_f32_16x16x32_bf16(b, wb[kb], acc, 0, 0, 0);
      }
      #pragma unroll
      for (int j = 0; j < 4; j++){
        int row = base + rb + g4*4 + j;
        if (row < N)
          outbf[(size_t)row*H + col] = f2bf(fmaxf(acc[j], 0.f));
      }
    }
  }
}

// ---------------- fused GRU (stages h f32 -> bf16 inline) ----------------
__global__ __launch_bounds__(512) void k_gru2(
    const unsigned short* __restrict__ x2bf, const float* __restrict__ h,
    const unsigned short* __restrict__ Wih_bf, const unsigned short* __restrict__ Whh_bf,
    const float* __restrict__ bih, const float* __restrict__ bhh,
    float* __restrict__ hnew, unsigned short* __restrict__ hnewbf, int N)
{
  __shared__ unsigned short sX[128*LDSP];
  __shared__ unsigned short sH[128*LDSP];
  int tid = threadIdx.x;
  int wid = tid >> 6, l = tid & 63, m16 = l & 15, g4 = l >> 4;
  int col = wid*16 + m16;
  bf16x8 wih[3][4], whh[3][4];
  #pragma unroll
  for (int g = 0; g < 3; g++){
    #pragma unroll
    for (int kb = 0; kb < 4; kb++){
      wih[g][kb] = ldfrag(Wih_bf + (size_t)(g*H + col)*H + kb*32 + g4*8);
      whh[g][kb] = ldfrag(Whh_bf + (size_t)(g*H + col)*H + kb*32 + g4*8);
    }
  }
  float bir = bih[col],       bhr = bhh[col];
  float biz = bih[H + col],   bhz = bhh[H + col];
  float bin = bih[2*H + col], bhn = bhh[2*H + col];
  int nstrips = (N + 127) >> 7;
  for (int s = blockIdx.x; s < nstrips; s += gridDim.x){
    int base = s << 7;
    __syncthreads();
    for (int c = tid; c < 4096; c += 512){
      int mat = c >> 11, cc = c & 2047;
      int row = cc >> 4, co = cc & 15;
      int gr = min(base + row, N-1);
      if (mat == 0){
        u16x8 v = *(const u16x8*)(x2bf + (size_t)gr*H + co*8);
        *(u16x8*)&sX[row*LDSP + co*8] = v;
      } else {
        float4 f0 = *(const float4*)(h + (size_t)gr*H + co*8);
        float4 f1 = *(const float4*)(h + (size_t)gr*H + co*8 + 4);
        u16x8 v;
        v[0] = f2bf(f0.x); v[1] = f2bf(f0.y); v[2] = f2bf(f0.z); v[3] = f2bf(f0.w);
        v[4] = f2bf(f1.x); v[5] = f2bf(f1.y); v[6] = f2bf(f1.z); v[7] = f2bf(f1.w);
        *(u16x8*)&sH[row*LDSP + co*8] = v;
      }
    }
    __syncthreads();
    #pragma unroll 1
    for (int rt = 0; rt < 8; rt++){
      int rb = rt*16;
      bf16x8 aX[4], aH[4];
      #pragma unroll
      for (int kb = 0; kb < 4; kb++){
        aX[kb] = *(const bf16x8*)&sX[(rb + m16)*LDSP + kb*32 + g4*8];
        aH[kb] = *(const bf16x8*)&sH[(rb + m16)*LDSP + kb*32 + g4*8];
      }
      f32x4 aRi = {bir,bir,bir,bir}, aRh = {bhr,bhr,bhr,bhr};
      f32x4 aZi = {biz,biz,biz,biz}, aZh = {bhz,bhz,bhz,bhz};
      f32x4 aNi = {bin,bin,bin,bin}, aNh = {bhn,bhn,bhn,bhn};
      #pragma unroll
      for (int kb = 0; kb < 4; kb++){
        aRi = __builtin_amdgcn_mfma_f32_16x16x32_bf16(aX[kb], wih[0][kb], aRi, 0,0,0);
        aRh = __builtin_amdgcn_mfma_f32_16x16x32_bf16(aH[kb], whh[0][kb], aRh, 0,0,0);
        aZi = __builtin_amdgcn_mfma_f32_16x16x32_bf16(aX[kb], wih[1][kb], aZi, 0,0,0);
        aZh = __builtin_amdgcn_mfma_f32_16x16x32_bf16(aH[kb], whh[1][kb], aZh, 0,0,0);
        aNi = __builtin_amdgcn_mfma_f32_16x16x32_bf16(aX[kb], wih[2][kb], aNi, 0,0,0);
        aNh = __builtin_amdgcn_mfma_f32_16x16x32_bf16(aH[kb], whh[2][kb], aNh, 0,0,0);
      }
      #pragma unroll
      for (int j = 0; j < 4; j++){
        int row = base + rb + g4*4 + j;
        if (row < N){
          float r = 1.f / (1.f + expf(-(aRi[j] + aRh[j])));
          float z = 1.f / (1.f + expf(-(aZi[j] + aZh[j])));
          float nn = tanhf(aNi[j] + r*aNh[j]);
          float hv = bf2f(sH[(rb + g4*4 + j)*LDSP + col]);
          float o = (1.f - z)*nn + z*hv;
          hnew[(size_t)row*H + col] = o;
          hnewbf[(size_t)row*H + col] = f2bf(o);
        }
      }
    }
  }
}

// ---------------- proj: PQ (bf16, cols 0..127) and D1 (relu f32, V2 rows 128..159) ----------------
__global__ __launch_bounds__(512) void k_proj2(
    const unsigned short* __restrict__ hnewbf, const unsigned short* __restrict__ V2_bf,
    const float* __restrict__ bd1,
    unsigned short* __restrict__ PQbf, float* __restrict__ D1, int N)
{
  __shared__ unsigned short sHn[128*LDSP];
  int tid = threadIdx.x;
  int wid = tid >> 6, l = tid & 63, m16 = l & 15, g4 = l >> 4;
  int col = wid*16 + m16;
  bf16x8 v1[4], v2[4];
  #pragma unroll
  for (int kb = 0; kb < 4; kb++)
    v1[kb] = ldfrag(V2_bf + (size_t)col*H + kb*32 + g4*8);
  int dc = wid*16 + m16;
  float bdv = 0.f;
  if (wid < 2){
    #pragma unroll
    for (int kb = 0; kb < 4; kb++)
      v2[kb] = ldfrag(V2_bf + (size_t)(128 + dc)*H + kb*32 + g4*8);
    bdv = bd1[dc];
  }
  int nstrips = (N + 127) >> 7;
  for (int s = blockIdx.x; s < nstrips; s += gridDim.x){
    int base = s << 7;
    __syncthreads();
    for (int c = tid; c < 2048; c += 512){
      int row = c >> 4, co = c & 15;
      int gr = min(base + row, N-1);
      u16x8 v = *(const u16x8*)(hnewbf + (size_t)gr*H + co*8);
      *(u16x8*)&(sHn[row*LDSP + co*8]) = v;
    }
    __syncthreads();
    #pragma unroll 1
    for (int rt = 0; rt < 8; rt++){
      int rb = rt*16;
      bf16x8 aH[4];
      #pragma unroll
      for (int kb = 0; kb < 4; kb++)
        aH[kb] = *(const bf16x8*)&sHn[(rb + m16)*LDSP + kb*32 + g4*8];
      f32x4 acc = {0.f, 0.f, 0.f, 0.f};
      #pragma unroll
      for (int kb = 0; kb < 4; kb++)
        acc = __builtin_amdgcn_mfma_f32_16x16x32_bf16(aH[kb], v1[kb], acc, 0, 0, 0);
      #pragma unroll
      for (int j = 0; j < 4; j++){
        int row = base + rb + g4*4 + j;
        if (row < N)
          PQbf[(size_t)row*H + col] = f2bf(acc[j]);
      }
      if (wid < 2){
        f32x4 acc2 = {0.f, 0.f, 0.f, 0.f};
        #pragma unroll
        for (int kb = 0; kb < 4; kb++)
          acc2 = __builtin_amdgcn_mfma_f32_16x16x32_bf16(aH[kb], v2[kb], acc2, 0, 0, 0);
        #pragma unroll
        for (int j = 0; j < 4; j++){
          int row = base + rb + g4*4 + j;
          if (row < N)
            D1[(size_t)row*32 + dc] = fmaxf(acc2[j] + bdv, 0.f);
        }
      }
    }
  }
}

// ---------------- disp from D1: 32-lane group per node ----------------
__global__ __launch_bounds__(256) void k_disp2(
    const float* __restrict__ D1, const float* __restrict__ Wd2,
    const float* __restrict__ bd2, float* __restrict__ disp, int N)
{
  int t = blockIdx.x*blockDim.x + threadIdx.x;
  int gh = t >> 5, sub = t & 31;
  int nh = (gridDim.x*blockDim.x) >> 5;
  float w0 = Wd2[sub], w1 = Wd2[32 + sub], w2 = Wd2[64 + sub];
  float bo = (sub < 3) ? bd2[sub] : 0.f;
  for (int d = gh; d < N; d += nh){
    float v = D1[(size_t)d*32 + sub];
    float v0 = v*w0, v1 = v*w1, v2 = v*w2;
    #pragma unroll
    for (int off = 1; off < 32; off <<= 1){
      v0 += __shfl_xor(v0, off, 32);
      v1 += __shfl_xor(v1, off, 32);
      v2 += __shfl_xor(v2, off, 32);
    }
    if (sub < 3) disp[(size_t)d*3 + sub] = (sub == 0 ? v0 : (sub == 1 ? v1 : v2)) + bo;
  }
}

// ---------------- force decoder: MFMA over 16-edge tiles, 3-stage pipelined gathers ----------------
__global__ __launch_bounds__(256) void k_force(
    const int* __restrict__ ei, const float* __restrict__ ea,
    const unsigned short* __restrict__ PQbf,
    const float* __restrict__ Wf1, const float* __restrict__ bf1,
    const float* __restrict__ Wf2, const float* __restrict__ bf2,
    float* __restrict__ out, int E)
{
  int l = threadIdx.x & 63;
  int r = l & 15, g = l >> 4;
  float4 wc0[8], wc1[8];
  float b1r0[8], b1r1[8];
  bf16x8 bfr0, bfr1;
  float bo = (r < 3) ? bf2[r] : 0.f;
  #pragma unroll
  for (int j = 0; j < 8; j++){
    int k0 = g*8 + j, k1 = 32 + g*8 + j;
    wc0[j] = *(const float4*)&Wf1[k0*260 + 256];
    wc1[j] = *(const float4*)&Wf1[k1*260 + 256];
    b1r0[j] = bf1[k0];
    b1r1[j] = bf1[k1];
    bfr0[j] = (r < 3) ? (short)f2bf(Wf2[r*64 + k0]) : (short)0;
    bfr1[j] = (r < 3) ? (short)f2bf(Wf2[r*64 + k1]) : (short)0;
  }
  int nt = (E + 15) >> 4;
  int stride = gridDim.x*4;
  int t = blockIdx.x*4 + (threadIdx.x >> 6);
  if (t >= nt) return;

  // stage A: current (gathers done); stage B: next (idx done); stage C: next-next idx
  int pcA = min(t*16 + r, E-1);
  int sA = ei[pcA], dA = ei[E + pcA];
  float4 aA = *(const float4*)&ea[(size_t)pcA*4];
  u16x8 pA0 = *(const u16x8*)&PQbf[(size_t)sA*H + g*8];
  u16x8 pA1 = *(const u16x8*)&PQbf[(size_t)sA*H + 32 + g*8];
  u16x8 qA0 = *(const u16x8*)&PQbf[(size_t)dA*H + 64 + g*8];
  u16x8 qA1 = *(const u16x8*)&PQbf[(size_t)dA*H + 96 + g*8];
  int t2 = t + stride;
  int sB = 0, dB = 0; float4 aB = {0.f,0.f,0.f,0.f};
  if (t2 < nt){
    int pcB = min(t2*16 + r, E-1);
    sB = ei[pcB]; dB = ei[E + pcB];
    aB = *(const float4*)&ea[(size_t)pcB*4];
  }
  while (true){
    // issue gathers for t2 (idx already in flight)
    u16x8 pB0, pB1, qB0, qB1;
    if (t2 < nt){
      pB0 = *(const u16x8*)&PQbf[(size_t)sB*H + g*8];
      pB1 = *(const u16x8*)&PQbf[(size_t)sB*H + 32 + g*8];
      qB0 = *(const u16x8*)&PQbf[(size_t)dB*H + 64 + g*8];
      qB1 = *(const u16x8*)&PQbf[(size_t)dB*H + 96 + g*8];
    }
    // issue idx loads for t3
    int t3 = t2 + stride;
    int sC = 0, dC = 0; float4 aC = {0.f,0.f,0.f,0.f};
    if (t3 < nt){
      int pcC = min(t3*16 + r, E-1);
      sC = ei[pcC]; dC = ei[E + pcC];
      aC = *(const float4*)&ea[(size_t)pcC*4];
    }
    // compute current tile t
    {
      bf16x8 af0, af1;
      #pragma unroll
      for (int j = 0; j < 8; j++){
        float pre0 = bf2f((unsigned short)pA0[j]) + bf2f((unsigned short)qA0[j]) + b1r0[j]
                   + aA.x*wc0[j].x + aA.y*wc0[j].y + aA.z*wc0[j].z + aA.w*wc0[j].w;
        af0[j] = (short)f2bf(fmaxf(pre0, 0.f));
        float pre1 = bf2f((unsigned short)pA1[j]) + bf2f((unsigned short)qA1[j]) + b1r1[j]
                   + aA.x*wc1[j].x + aA.y*wc1[j].y + aA.z*wc1[j].z + aA.w*wc1[j].w;
        af1[j] = (short)f2bf(fmaxf(pre1, 0.f));
      }
      f32x4 acc = {0.f, 0.f, 0.f, 0.f};
      acc = __builtin_amdgcn_mfma_f32_16x16x32_bf16(af0, bfr0, acc, 0, 0, 0);
      acc = __builtin_amdgcn_mfma_f32_16x16x32_bf16(af1, bfr1, acc, 0, 0, 0);
      if (r < 3){
        #pragma unroll
        for (int j = 0; j < 4; j++){
          int erow = t*16 + g*4 + j;
          if (erow < E) out[(size_t)erow*3 + r] = acc[j] + bo;
        }
      }
    }
    if (t2 >= nt) break;
    // rotate stages
    t = t2; t2 = t3;
    aA = aB; pA0 = pB0; pA1 = pB1; qA0 = qB0; qA1 = qB1;
    sB = sC; dB = dC; aB = aC;
  }
}

extern "C" void kernel_launch(void* const* d_in, const int* in_sizes, int n_in,
                              void* d_out, int out_size, void* d_ws, size_t ws_size,
                              hipStream_t stream)
{
  const float* x   = (const float*)d_in[0];
  const int*   ei  = (const int*)d_in[1];
  const float* ea  = (const float*)d_in[2];
  const float* h   = (const float*)d_in[3];
  const float* W1l = (const float*)d_in[4];
  const float* b1l = (const float*)d_in[5];
  const float* W1r = (const float*)d_in[6];
  const float* W2l = (const float*)d_in[7];
  const float* b2l = (const float*)d_in[8];
  const float* W2r = (const float*)d_in[9];
  const float* Wih = (const float*)d_in[10];
  const float* Whh = (const float*)d_in[11];
  const float* bih = (const float*)d_in[12];
  const float* bhh = (const float*)d_in[13];
  const float* Wd1 = (const float*)d_in[14];
  const float* bd1 = (const float*)d_in[15];
  const float* Wd2 = (const float*)d_in[16];
  const float* bd2 = (const float*)d_in[17];
  const float* Wf1 = (const float*)d_in[18];
  const float* bf1 = (const float*)d_in[19];
  const float* Wf2 = (const float*)d_in[20];
  const float* bf2 = (const float*)d_in[21];

  int N = in_sizes[0] / IN_DIM;
  int E = in_sizes[1] / 2;

  char* ws = (char*)d_ws;
  size_t off = 0;
  auto alloc = [&](size_t bytes) -> char* {
    char* p = ws + off;
    off = (off + bytes + 255) & ~(size_t)255;
    return p;
  };
  int* counts  = (int*)alloc((size_t)N*4);
  int* offsets = (int*)alloc((size_t)N*4);
  int* cursor  = (int*)alloc((size_t)N*4);
  int* bsum    = (int*)alloc(1024);
  int* csr     = (int*)alloc((size_t)E*4);
  // pool: aggx(6.4MB) | x1bf(12.8MB) | agg2bf(12.8MB); reused post-GRU:
  //   PQbf (12.8MB) over aggx+x1bf; D1 (6.4MB) over agg2bf
  float* aggx            = (float*)alloc((size_t)N*32*4);
  unsigned short* x1bf   = (unsigned short*)alloc((size_t)N*H*2);
  unsigned short* agg2bf = (unsigned short*)alloc((size_t)N*H*2);
  unsigned short* PQbf = (unsigned short*)aggx;
  float* D1            = (float*)agg2bf;
  unsigned short* x2bf   = (unsigned short*)alloc((size_t)N*H*2);
  unsigned short* hnewbf = (unsigned short*)alloc((size_t)N*H*2);
  unsigned short* W2l_bf = (unsigned short*)alloc(16384*2);
  unsigned short* W2r_bf = (unsigned short*)alloc(16384*2);
  unsigned short* Wih_bf = (unsigned short*)alloc(49152*2);
  unsigned short* Whh_bf = (unsigned short*)alloc(49152*2);
  unsigned short* V2_bf  = (unsigned short*)alloc(20480*2);

  float* disp  = (float*)d_out;
  float* force = disp + (size_t)N*3;
  float* hnew  = force + (size_t)E*3;

  hipMemsetAsync(counts, 0, (size_t)N*4, stream);
  int nb = (N + 255) / 256;
  k_count  <<<2048, 256, 0, stream>>>(ei + E, counts, E);
  k_scanA  <<<nb, 256, 0, stream>>>(counts, offsets, bsum, N);
  k_scanB  <<<1, 256, 0, stream>>>(bsum, nb);
  k_scanC  <<<nb, 256, 0, stream>>>(offsets, cursor, bsum, N);
  k_scatter<<<2048, 256, 0, stream>>>(ei, cursor, csr, E);

  k_wconv  <<<192, 256, 0, stream>>>(W2l, W2r, Wih, Whh, Wf1, Wd1,
                                     W2l_bf, W2r_bf, Wih_bf, Whh_bf, V2_bf);

  k_aggx   <<<4096, 256, 0, stream>>>(x, csr, offsets, counts, aggx, N);
  k_lin1   <<<2048, 256, 0, stream>>>(aggx, x, W1l, b1l, W1r, x1bf, N);
  k_agg2   <<<4096, 256, 0, stream>>>(x1bf, csr, offsets, counts, agg2bf, N);

  int nstrips = (N + 127) / 128;
  k_dual2  <<<nstrips, 512, 0, stream>>>(agg2bf, x1bf, W2l_bf, W2r_bf, b2l, x2bf, N);
  k_gru2   <<<nstrips, 512, 0, stream>>>(x2bf, h, Wih_bf, Whh_bf, bih, bhh, hnew, hnewbf, N);
  k_proj2  <<<nstrips, 512, 0, stream>>>(hnewbf, V2_bf, bd1, PQbf, D1, N);
  k_disp2  <<<1024, 256, 0, stream>>>(D1, Wd2, bd2, disp, N);
  k_force  <<<2048, 256, 0, stream>>>(ei, ea, PQbf, Wf1, bf1, Wf2, bf2, force, E);
}

// Round 8
// 363.778 us; speedup vs baseline: 3.3113x; 1.0456x over previous
//
#include <hip/hip_runtime.h>
#include <hip/hip_bf16.h>

#define H 128
#define IN_DIM 30
#define LDSP 136  // padded row stride (ushorts) for staged activations

typedef __attribute__((ext_vector_type(8))) short bf16x8;
typedef __attribute__((ext_vector_type(8))) unsigned short u16x8;
typedef __attribute__((ext_vector_type(4))) float f32x4;

__device__ inline unsigned short f2bf(float f){
  unsigned int u = __builtin_bit_cast(unsigned int, f);
  unsigned int r = u + 0x7FFF + ((u >> 16) & 1);
  return (unsigned short)(r >> 16);
}
__device__ inline float bf2f(unsigned short b){
  unsigned int u = ((unsigned int)b) << 16;
  return __builtin_bit_cast(float, u);
}
__device__ inline bf16x8 ldfrag(const unsigned short* p){
  return *(const bf16x8*)p;
}

// ---------------- CSR build (XCD-partitioned: block b owns node range of partition b&7) ----------------
__global__ void k_count(const int* __restrict__ col, int* __restrict__ counts,
                        int E, int npp){
  int part = blockIdx.x & 7;
  int inst = blockIdx.x >> 3;
  int ninst = gridDim.x >> 3;
  int lo = part*npp, hi = lo + npp;
  for (int e = inst*blockDim.x + threadIdx.x; e < E; e += ninst*blockDim.x){
    int c = col[e];
    if (c >= lo && c < hi) atomicAdd(&counts[c], 1);
  }
}

__global__ void k_scanA(const int* __restrict__ counts, int* __restrict__ offsets,
                        int* __restrict__ bsum, int n){
  __shared__ int buf[256];
  int i = blockIdx.x*256 + threadIdx.x;
  int v = (i < n) ? counts[i] : 0;
  buf[threadIdx.x] = v; __syncthreads();
  for (int off = 1; off < 256; off <<= 1){
    int t = (threadIdx.x >= off) ? buf[threadIdx.x - off] : 0;
    __syncthreads();
    buf[threadIdx.x] += t;
    __syncthreads();
  }
  if (i < n) offsets[i] = buf[threadIdx.x] - v;
  if (threadIdx.x == 255) bsum[blockIdx.x] = buf[255];
}

__global__ void k_scanB(int* __restrict__ bsum, int nb){
  __shared__ int buf[256];
  int v = (threadIdx.x < nb) ? bsum[threadIdx.x] : 0;
  buf[threadIdx.x] = v; __syncthreads();
  for (int off = 1; off < 256; off <<= 1){
    int t = (threadIdx.x >= off) ? buf[threadIdx.x - off] : 0;
    __syncthreads();
    buf[threadIdx.x] += t;
    __syncthreads();
  }
  if (threadIdx.x < nb) bsum[threadIdx.x] = buf[threadIdx.x] - v;
}

__global__ void k_scanC(int* __restrict__ offsets, int* __restrict__ cursor,
                        const int* __restrict__ bsum, int n){
  int i = blockIdx.x*256 + threadIdx.x;
  if (i < n){ int o = offsets[i] + bsum[blockIdx.x]; offsets[i] = o; cursor[i] = o; }
}

__global__ void k_scatter(const int* __restrict__ ei, int* __restrict__ cursor,
                          int* __restrict__ csr, int E, int npp){
  int part = blockIdx.x & 7;
  int inst = blockIdx.x >> 3;
  int ninst = gridDim.x >> 3;
  int lo = part*npp, hi = lo + npp;
  for (int e = inst*blockDim.x + threadIdx.x; e < E; e += ninst*blockDim.x){
    int c = ei[E + e];
    if (c >= lo && c < hi){
      int p = atomicAdd(&cursor[c], 1);
      csr[p] = ei[e];
    }
  }
}

// ---------------- weight conversion to bf16 ----------------
// V2 layout [160][128]: rows 0..63 = Wf1 P-part, 64..127 = Wf1 Q-part, 128..159 = Wd1
__global__ void k_wconv(const float* __restrict__ W2l, const float* __restrict__ W2r,
                        const float* __restrict__ Wih, const float* __restrict__ Whh,
                        const float* __restrict__ Wf1, const float* __restrict__ Wd1,
                        unsigned short* __restrict__ W2l_bf, unsigned short* __restrict__ W2r_bf,
                        unsigned short* __restrict__ Wih_bf, unsigned short* __restrict__ Whh_bf,
                        unsigned short* __restrict__ V2_bf){
  int stride = gridDim.x*blockDim.x;
  for (int i = blockIdx.x*blockDim.x + threadIdx.x; i < 49152; i += stride){
    if (i < 16384){
      W2l_bf[i] = f2bf(W2l[i]);
      W2r_bf[i] = f2bf(W2r[i]);
    }
    if (i < 20480){
      int j = i >> 7, k = i & 127;
      float v;
      if (j < 64)        v = Wf1[j*260 + k];
      else if (j < 128)  v = Wf1[(j-64)*260 + 128 + k];
      else               v = Wd1[(j-128)*128 + k];
      V2_bf[i] = f2bf(v);
    }
    Wih_bf[i] = f2bf(Wih[i]);
    Whh_bf[i] = f2bf(Whh[i]);
  }
}

// ---------------- aggx: mean of x (30-dim) rows ----------------
__global__ __launch_bounds__(256) void k_aggx(
    const float* __restrict__ x, const int* __restrict__ csr,
    const int* __restrict__ offsets, const int* __restrict__ counts,
    float* __restrict__ aggx, int N)
{
  int t = blockIdx.x*blockDim.x + threadIdx.x;
  int gw = t >> 6, lane = t & 63;
  int nw = (gridDim.x*blockDim.x) >> 6;
  int half = lane >> 5, c = lane & 31;
  bool act = (c < IN_DIM);
  for (int d = gw; d < N; d += nw){
    int base = offsets[d], cnt = counts[d];
    float s = 0.f;
    for (int i = half; i < cnt; i += 2){
      int sr = csr[base + i];
      if (act) s += x[(size_t)sr*IN_DIM + c];
    }
    s += __shfl_xor(s, 32);
    if (lane < 32){
      float inv = 1.f / (float)(cnt > 0 ? cnt : 1);
      aggx[d*32 + c] = act ? s*inv : 0.f;
    }
  }
}

// ---------------- lin1 ----------------
__global__ __launch_bounds__(256) void k_lin1(
    const float* __restrict__ aggx, const float* __restrict__ x,
    const float* __restrict__ W1l, const float* __restrict__ b1l,
    const float* __restrict__ W1r, unsigned short* __restrict__ x1bf, int N)
{
  int tid = threadIdx.x;
  int slot = tid >> 7, c = tid & 127;
  float wl[IN_DIM], wr[IN_DIM];
  #pragma unroll
  for (int k = 0; k < IN_DIM; k++){ wl[k] = W1l[c*IN_DIM + k]; wr[k] = W1r[c*IN_DIM + k]; }
  float bc = b1l[c];
  for (int d0 = blockIdx.x*2; d0 < N; d0 += gridDim.x*2){
    int d = d0 + slot;
    if (d >= N) continue;
    float s = bc;
    const float* ag = &aggx[d*32];
    const float* xd = &x[(size_t)d*IN_DIM];
    #pragma unroll
    for (int k = 0; k < IN_DIM; k++) s += ag[k]*wl[k] + xd[k]*wr[k];
    x1bf[(size_t)d*H + c] = f2bf(fmaxf(s, 0.f));
  }
}

// ---------------- agg2 ----------------
__global__ __launch_bounds__(256) void k_agg2(
    const unsigned short* __restrict__ x1bf, const int* __restrict__ csr,
    const int* __restrict__ offsets, const int* __restrict__ counts,
    unsigned short* __restrict__ agg2bf, int N)
{
  int t = blockIdx.x*blockDim.x + threadIdx.x;
  int gw = t >> 6, lane = t & 63;
  int nw = (gridDim.x*blockDim.x) >> 6;
  const unsigned int* x1u = (const unsigned int*)x1bf;
  unsigned int* agu = (unsigned int*)agg2bf;
  for (int d = gw; d < N; d += nw){
    int base = offsets[d], cnt = counts[d];
    float a0 = 0.f, a1 = 0.f;
    int i = 0;
    for (; i + 3 < cnt; i += 4){
      int s0 = csr[base + i],     s1 = csr[base + i + 1];
      int s2 = csr[base + i + 2], s3 = csr[base + i + 3];
      unsigned int v0 = x1u[(size_t)s0*64 + lane];
      unsigned int v1 = x1u[(size_t)s1*64 + lane];
      unsigned int v2 = x1u[(size_t)s2*64 + lane];
      unsigned int v3 = x1u[(size_t)s3*64 + lane];
      a0 += bf2f((unsigned short)(v0 & 0xffff)) + bf2f((unsigned short)(v1 & 0xffff))
          + bf2f((unsigned short)(v2 & 0xffff)) + bf2f((unsigned short)(v3 & 0xffff));
      a1 += bf2f((unsigned short)(v0 >> 16)) + bf2f((unsigned short)(v1 >> 16))
          + bf2f((unsigned short)(v2 >> 16)) + bf2f((unsigned short)(v3 >> 16));
    }
    for (; i < cnt; i++){
      unsigned int v = x1u[(size_t)csr[base + i]*64 + lane];
      a0 += bf2f((unsigned short)(v & 0xffff));
      a1 += bf2f((unsigned short)(v >> 16));
    }
    float inv = 1.f / (float)(cnt > 0 ? cnt : 1);
    unsigned int o = (unsigned int)f2bf(a0*inv) | ((unsigned int)f2bf(a1*inv) << 16);
    agu[(size_t)d*64 + lane] = o;
  }
}

// ============ strip GEMM kernels: 512 thr, 128-row strips, LDS-staged A ============

// ---------------- SAGE2: x2 = relu(agg2@W2l.T + b2l + x1@W2r.T) ----------------
__global__ __launch_bounds__(512) void k_dual2(
    const unsigned short* __restrict__ Abf, const unsigned short* __restrict__ Bbf,
    const unsigned short* __restrict__ Wa, const unsigned short* __restrict__ Wb,
    const float* __restrict__ bias, unsigned short* __restrict__ outbf, int N)
{
  __shared__ unsigned short sA[128*LDSP];
  __shared__ unsigned short sB[128*LDSP];
  int tid = threadIdx.x;
  int wid = tid >> 6, l = tid & 63, m16 = l & 15, g4 = l >> 4;
  int col = wid*16 + m16;
  bf16x8 wa[4], wb[4];
  #pragma unroll
  for (int kb = 0; kb < 4; kb++){
    wa[kb] = ldfrag(Wa + (size_t)col*H + kb*32 + g4*8);
    wb[kb] = ldfrag(Wb + (size_t)col*H + kb*32 + g4*8);
  }
  float bc = bias[col];
  int nstrips = (N + 127) >> 7;
  for (int s = blockIdx.x; s < nstrips; s += gridDim.x){
    int base = s << 7;
    __syncthreads();
    for (int c = tid; c < 4096; c += 512){
      int mat = c >> 11, cc = c & 2047;
      int row = cc >> 4, co = cc & 15;
      int gr = min(base + row, N-1);
      u16x8 v = *(const u16x8*)((mat ? Bbf : Abf) + (size_t)gr*H + co*8);
      *(u16x8*)&((mat ? sB : sA)[row*LDSP + co*8]) = v;
    }
    __syncthreads();
    #pragma unroll 1
    for (int rt = 0; rt < 8; rt++){
      int rb = rt*16;
      f32x4 acc = {bc, bc, bc, bc};
      #pragma unroll
      for (int kb = 0; kb < 4; kb++){
        bf16x8 a = *(const bf16x8*)&sA[(rb + m16)*LDSP + kb*32 + g4*8];
        acc = __builtin_amdgcn_mfma_f32_16x16x32_bf16(a, wa[kb], acc, 0, 0, 0);
        bf16x8 b = *(const bf16x8*)&sB[(rb + m16)*LDSP + kb*32 + g4*8];
        acc = __builtin_amdgcn_mfma_f32_16x16x32_bf16(b, wb[kb], acc, 0, 0, 0);
      }
      #pragma unroll
      for (int j = 0; j < 4; j++){
        int row = base + rb + g4*4 + j;
        if (row < N)
          outbf[(size_t)row*H + col] = f2bf(fmaxf(acc[j], 0.f));
      }
    }
  }
}

// ---------------- fused GRU (stages h f32 -> bf16 inline) ----------------
__global__ __launch_bounds__(512) void k_gru2(
    const unsigned short* __restrict__ x2bf, const float* __restrict__ h,
    const unsigned short* __restrict__ Wih_bf, const unsigned short* __restrict__ Whh_bf,
    const float* __restrict__ bih, const float* __restrict__ bhh,
    float* __restrict__ hnew, unsigned short* __restrict__ hnewbf, int N)
{
  __shared__ unsigned short sX[128*LDSP];
  __shared__ unsigned short sH[128*LDSP];
  int tid = threadIdx.x;
  int wid = tid >> 6, l = tid & 63, m16 = l & 15, g4 = l >> 4;
  int col = wid*16 + m16;
  bf16x8 wih[3][4], whh[3][4];
  #pragma unroll
  for (int g = 0; g < 3; g++){
    #pragma unroll
    for (int kb = 0; kb < 4; kb++){
      wih[g][kb] = ldfrag(Wih_bf + (size_t)(g*H + col)*H + kb*32 + g4*8);
      whh[g][kb] = ldfrag(Whh_bf + (size_t)(g*H + col)*H + kb*32 + g4*8);
    }
  }
  float bir = bih[col],       bhr = bhh[col];
  float biz = bih[H + col],   bhz = bhh[H + col];
  float bin = bih[2*H + col], bhn = bhh[2*H + col];
  int nstrips = (N + 127) >> 7;
  for (int s = blockIdx.x; s < nstrips; s += gridDim.x){
    int base = s << 7;
    __syncthreads();
    for (int c = tid; c < 4096; c += 512){
      int mat = c >> 11, cc = c & 2047;
      int row = cc >> 4, co = cc & 15;
      int gr = min(base + row, N-1);
      if (mat == 0){
        u16x8 v = *(const u16x8*)(x2bf + (size_t)gr*H + co*8);
        *(u16x8*)&sX[row*LDSP + co*8] = v;
      } else {
        float4 f0 = *(const float4*)(h + (size_t)gr*H + co*8);
        float4 f1 = *(const float4*)(h + (size_t)gr*H + co*8 + 4);
        u16x8 v;
        v[0] = f2bf(f0.x); v[1] = f2bf(f0.y); v[2] = f2bf(f0.z); v[3] = f2bf(f0.w);
        v[4] = f2bf(f1.x); v[5] = f2bf(f1.y); v[6] = f2bf(f1.z); v[7] = f2bf(f1.w);
        *(u16x8*)&sH[row*LDSP + co*8] = v;
      }
    }
    __syncthreads();
    #pragma unroll 1
    for (int rt = 0; rt < 8; rt++){
      int rb = rt*16;
      bf16x8 aX[4], aH[4];
      #pragma unroll
      for (int kb = 0; kb < 4; kb++){
        aX[kb] = *(const bf16x8*)&sX[(rb + m16)*LDSP + kb*32 + g4*8];
        aH[kb] = *(const bf16x8*)&sH[(rb + m16)*LDSP + kb*32 + g4*8];
      }
      f32x4 aRi = {bir,bir,bir,bir}, aRh = {bhr,bhr,bhr,bhr};
      f32x4 aZi = {biz,biz,biz,biz}, aZh = {bhz,bhz,bhz,bhz};
      f32x4 aNi = {bin,bin,bin,bin}, aNh = {bhn,bhn,bhn,bhn};
      #pragma unroll
      for (int kb = 0; kb < 4; kb++){
        aRi = __builtin_amdgcn_mfma_f32_16x16x32_bf16(aX[kb], wih[0][kb], aRi, 0,0,0);
        aRh = __builtin_amdgcn_mfma_f32_16x16x32_bf16(aH[kb], whh[0][kb], aRh, 0,0,0);
        aZi = __builtin_amdgcn_mfma_f32_16x16x32_bf16(aX[kb], wih[1][kb], aZi, 0,0,0);
        aZh = __builtin_amdgcn_mfma_f32_16x16x32_bf16(aH[kb], whh[1][kb], aZh, 0,0,0);
        aNi = __builtin_amdgcn_mfma_f32_16x16x32_bf16(aX[kb], wih[2][kb], aNi, 0,0,0);
        aNh = __builtin_amdgcn_mfma_f32_16x16x32_bf16(aH[kb], whh[2][kb], aNh, 0,0,0);
      }
      #pragma unroll
      for (int j = 0; j < 4; j++){
        int row = base + rb + g4*4 + j;
        if (row < N){
          float r = 1.f / (1.f + expf(-(aRi[j] + aRh[j])));
          float z = 1.f / (1.f + expf(-(aZi[j] + aZh[j])));
          float nn = tanhf(aNi[j] + r*aNh[j]);
          float hv = bf2f(sH[(rb + g4*4 + j)*LDSP + col]);
          float o = (1.f - z)*nn + z*hv;
          hnew[(size_t)row*H + col] = o;
          hnewbf[(size_t)row*H + col] = f2bf(o);
        }
      }
    }
  }
}

// ---------------- proj: PQ (bf16, cols 0..127) and D1 (relu f32, V2 rows 128..159) ----------------
__global__ __launch_bounds__(512) void k_proj2(
    const unsigned short* __restrict__ hnewbf, const unsigned short* __restrict__ V2_bf,
    const float* __restrict__ bd1,
    unsigned short* __restrict__ PQbf, float* __restrict__ D1, int N)
{
  __shared__ unsigned short sHn[128*LDSP];
  int tid = threadIdx.x;
  int wid = tid >> 6, l = tid & 63, m16 = l & 15, g4 = l >> 4;
  int col = wid*16 + m16;
  bf16x8 v1[4], v2[4];
  #pragma unroll
  for (int kb = 0; kb < 4; kb++)
    v1[kb] = ldfrag(V2_bf + (size_t)col*H + kb*32 + g4*8);
  int dc = wid*16 + m16;
  float bdv = 0.f;
  if (wid < 2){
    #pragma unroll
    for (int kb = 0; kb < 4; kb++)
      v2[kb] = ldfrag(V2_bf + (size_t)(128 + dc)*H + kb*32 + g4*8);
    bdv = bd1[dc];
  }
  int nstrips = (N + 127) >> 7;
  for (int s = blockIdx.x; s < nstrips; s += gridDim.x){
    int base = s << 7;
    __syncthreads();
    for (int c = tid; c < 2048; c += 512){
      int row = c >> 4, co = c & 15;
      int gr = min(base + row, N-1);
      u16x8 v = *(const u16x8*)(hnewbf + (size_t)gr*H + co*8);
      *(u16x8*)&(sHn[row*LDSP + co*8]) = v;
    }
    __syncthreads();
    #pragma unroll 1
    for (int rt = 0; rt < 8; rt++){
      int rb = rt*16;
      bf16x8 aH[4];
      #pragma unroll
      for (int kb = 0; kb < 4; kb++)
        aH[kb] = *(const bf16x8*)&sHn[(rb + m16)*LDSP + kb*32 + g4*8];
      f32x4 acc = {0.f, 0.f, 0.f, 0.f};
      #pragma unroll
      for (int kb = 0; kb < 4; kb++)
        acc = __builtin_amdgcn_mfma_f32_16x16x32_bf16(aH[kb], v1[kb], acc, 0, 0, 0);
      #pragma unroll
      for (int j = 0; j < 4; j++){
        int row = base + rb + g4*4 + j;
        if (row < N)
          PQbf[(size_t)row*H + col] = f2bf(acc[j]);
      }
      if (wid < 2){
        f32x4 acc2 = {0.f, 0.f, 0.f, 0.f};
        #pragma unroll
        for (int kb = 0; kb < 4; kb++)
          acc2 = __builtin_amdgcn_mfma_f32_16x16x32_bf16(aH[kb], v2[kb], acc2, 0, 0, 0);
        #pragma unroll
        for (int j = 0; j < 4; j++){
          int row = base + rb + g4*4 + j;
          if (row < N)
            D1[(size_t)row*32 + dc] = fmaxf(acc2[j] + bdv, 0.f);
        }
      }
    }
  }
}

// ---------------- disp from D1: 32-lane group per node ----------------
__global__ __launch_bounds__(256) void k_disp2(
    const float* __restrict__ D1, const float* __restrict__ Wd2,
    const float* __restrict__ bd2, float* __restrict__ disp, int N)
{
  int t = blockIdx.x*blockDim.x + threadIdx.x;
  int gh = t >> 5, sub = t & 31;
  int nh = (gridDim.x*blockDim.x) >> 5;
  float w0 = Wd2[sub], w1 = Wd2[32 + sub], w2 = Wd2[64 + sub];
  float bo = (sub < 3) ? bd2[sub] : 0.f;
  for (int d = gh; d < N; d += nh){
    float v = D1[(size_t)d*32 + sub];
    float v0 = v*w0, v1 = v*w1, v2 = v*w2;
    #pragma unroll
    for (int off = 1; off < 32; off <<= 1){
      v0 += __shfl_xor(v0, off, 32);
      v1 += __shfl_xor(v1, off, 32);
      v2 += __shfl_xor(v2, off, 32);
    }
    if (sub < 3) disp[(size_t)d*3 + sub] = (sub == 0 ? v0 : (sub == 1 ? v1 : v2)) + bo;
  }
}

// ---------------- force decoder: MFMA over 16-edge tiles, 3-stage pipelined gathers ----------------
__global__ __launch_bounds__(256) void k_force(
    const int* __restrict__ ei, const float* __restrict__ ea,
    const unsigned short* __restrict__ PQbf,
    const float* __restrict__ Wf1, const float* __restrict__ bf1,
    const float* __restrict__ Wf2, const float* __restrict__ bf2,
    float* __restrict__ out, int E)
{
  int l = threadIdx.x & 63;
  int r = l & 15, g = l >> 4;
  float4 wc0[8], wc1[8];
  float b1r0[8], b1r1[8];
  bf16x8 bfr0, bfr1;
  float bo = (r < 3) ? bf2[r] : 0.f;
  #pragma unroll
  for (int j = 0; j < 8; j++){
    int k0 = g*8 + j, k1 = 32 + g*8 + j;
    wc0[j] = *(const float4*)&Wf1[k0*260 + 256];
    wc1[j] = *(const float4*)&Wf1[k1*260 + 256];
    b1r0[j] = bf1[k0];
    b1r1[j] = bf1[k1];
    bfr0[j] = (r < 3) ? (short)f2bf(Wf2[r*64 + k0]) : (short)0;
    bfr1[j] = (r < 3) ? (short)f2bf(Wf2[r*64 + k1]) : (short)0;
  }
  int nt = (E + 15) >> 4;
  int stride = gridDim.x*4;
  int t = blockIdx.x*4 + (threadIdx.x >> 6);
  if (t >= nt) return;

  int pcA = min(t*16 + r, E-1);
  int sA = ei[pcA], dA = ei[E + pcA];
  float4 aA = *(const float4*)&ea[(size_t)pcA*4];
  u16x8 pA0 = *(const u16x8*)&PQbf[(size_t)sA*H + g*8];
  u16x8 pA1 = *(const u16x8*)&PQbf[(size_t)sA*H + 32 + g*8];
  u16x8 qA0 = *(const u16x8*)&PQbf[(size_t)dA*H + 64 + g*8];
  u16x8 qA1 = *(const u16x8*)&PQbf[(size_t)dA*H + 96 + g*8];
  int t2 = t + stride;
  int sB = 0, dB = 0; float4 aB = {0.f,0.f,0.f,0.f};
  if (t2 < nt){
    int pcB = min(t2*16 + r, E-1);
    sB = ei[pcB]; dB = ei[E + pcB];
    aB = *(const float4*)&ea[(size_t)pcB*4];
  }
  while (true){
    u16x8 pB0, pB1, qB0, qB1;
    if (t2 < nt){
      pB0 = *(const u16x8*)&PQbf[(size_t)sB*H + g*8];
      pB1 = *(const u16x8*)&PQbf[(size_t)sB*H + 32 + g*8];
      qB0 = *(const u16x8*)&PQbf[(size_t)dB*H + 64 + g*8];
      qB1 = *(const u16x8*)&PQbf[(size_t)dB*H + 96 + g*8];
    }
    int t3 = t2 + stride;
    int sC = 0, dC = 0; float4 aC = {0.f,0.f,0.f,0.f};
    if (t3 < nt){
      int pcC = min(t3*16 + r, E-1);
      sC = ei[pcC]; dC = ei[E + pcC];
      aC = *(const float4*)&ea[(size_t)pcC*4];
    }
    {
      bf16x8 af0, af1;
      #pragma unroll
      for (int j = 0; j < 8; j++){
        float pre0 = bf2f((unsigned short)pA0[j]) + bf2f((unsigned short)qA0[j]) + b1r0[j]
                   + aA.x*wc0[j].x + aA.y*wc0[j].y + aA.z*wc0[j].z + aA.w*wc0[j].w;
        af0[j] = (short)f2bf(fmaxf(pre0, 0.f));
        float pre1 = bf2f((unsigned short)pA1[j]) + bf2f((unsigned short)qA1[j]) + b1r1[j]
                   + aA.x*wc1[j].x + aA.y*wc1[j].y + aA.z*wc1[j].z + aA.w*wc1[j].w;
        af1[j] = (short)f2bf(fmaxf(pre1, 0.f));
      }
      f32x4 acc = {0.f, 0.f, 0.f, 0.f};
      acc = __builtin_amdgcn_mfma_f32_16x16x32_bf16(af0, bfr0, acc, 0, 0, 0);
      acc = __builtin_amdgcn_mfma_f32_16x16x32_bf16(af1, bfr1, acc, 0, 0, 0);
      if (r < 3){
        #pragma unroll
        for (int j = 0; j < 4; j++){
          int erow = t*16 + g*4 + j;
          if (erow < E) out[(size_t)erow*3 + r] = acc[j] + bo;
        }
      }
    }
    if (t2 >= nt) break;
    t = t2; t2 = t3;
    aA = aB; pA0 = pB0; pA1 = pB1; qA0 = qB0; qA1 = qB1;
    sB = sC; dB = dC; aB = aC;
  }
}

extern "C" void kernel_launch(void* const* d_in, const int* in_sizes, int n_in,
                              void* d_out, int out_size, void* d_ws, size_t ws_size,
                              hipStream_t stream)
{
  const float* x   = (const float*)d_in[0];
  const int*   ei  = (const int*)d_in[1];
  const float* ea  = (const float*)d_in[2];
  const float* h   = (const float*)d_in[3];
  const float* W1l = (const float*)d_in[4];
  const float* b1l = (const float*)d_in[5];
  const float* W1r = (const float*)d_in[6];
  const float* W2l = (const float*)d_in[7];
  const float* b2l = (const float*)d_in[8];
  const float* W2r = (const float*)d_in[9];
  const float* Wih = (const float*)d_in[10];
  const float* Whh = (const float*)d_in[11];
  const float* bih = (const float*)d_in[12];
  const float* bhh = (const float*)d_in[13];
  const float* Wd1 = (const float*)d_in[14];
  const float* bd1 = (const float*)d_in[15];
  const float* Wd2 = (const float*)d_in[16];
  const float* bd2 = (const float*)d_in[17];
  const float* Wf1 = (const float*)d_in[18];
  const float* bf1 = (const float*)d_in[19];
  const float* Wf2 = (const float*)d_in[20];
  const float* bf2 = (const float*)d_in[21];

  int N = in_sizes[0] / IN_DIM;
  int E = in_sizes[1] / 2;
  int npp = (N + 7) / 8;  // nodes per XCD partition

  char* ws = (char*)d_ws;
  size_t off = 0;
  auto alloc = [&](size_t bytes) -> char* {
    char* p = ws + off;
    off = (off + bytes + 255) & ~(size_t)255;
    return p;
  };
  int* counts  = (int*)alloc((size_t)N*4);
  int* offsets = (int*)alloc((size_t)N*4);
  int* cursor  = (int*)alloc((size_t)N*4);
  int* bsum    = (int*)alloc(1024);
  int* csr     = (int*)alloc((size_t)E*4);
  // pool: aggx(6.4MB) | x1bf(12.8MB) | agg2bf(12.8MB); reused post-GRU:
  //   PQbf (12.8MB) over aggx+x1bf; D1 (6.4MB) over agg2bf
  float* aggx            = (float*)alloc((size_t)N*32*4);
  unsigned short* x1bf   = (unsigned short*)alloc((size_t)N*H*2);
  unsigned short* agg2bf = (unsigned short*)alloc((size_t)N*H*2);
  unsigned short* PQbf = (unsigned short*)aggx;
  float* D1            = (float*)agg2bf;
  unsigned short* x2bf   = (unsigned short*)alloc((size_t)N*H*2);
  unsigned short* hnewbf = (unsigned short*)alloc((size_t)N*H*2);
  unsigned short* W2l_bf = (unsigned short*)alloc(16384*2);
  unsigned short* W2r_bf = (unsigned short*)alloc(16384*2);
  unsigned short* Wih_bf = (unsigned short*)alloc(49152*2);
  unsigned short* Whh_bf = (unsigned short*)alloc(49152*2);
  unsigned short* V2_bf  = (unsigned short*)alloc(20480*2);

  float* disp  = (float*)d_out;
  float* force = disp + (size_t)N*3;
  float* hnew  = force + (size_t)E*3;

  hipMemsetAsync(counts, 0, (size_t)N*4, stream);
  int nb = (N + 255) / 256;
  k_count  <<<2048, 256, 0, stream>>>(ei + E, counts, E, npp);
  k_scanA  <<<nb, 256, 0, stream>>>(counts, offsets, bsum, N);
  k_scanB  <<<1, 256, 0, stream>>>(bsum, nb);
  k_scanC  <<<nb, 256, 0, stream>>>(offsets, cursor, bsum, N);
  k_scatter<<<2048, 256, 0, stream>>>(ei, cursor, csr, E, npp);

  k_wconv  <<<192, 256, 0, stream>>>(W2l, W2r, Wih, Whh, Wf1, Wd1,
                                     W2l_bf, W2r_bf, Wih_bf, Whh_bf, V2_bf);

  k_aggx   <<<4096, 256, 0, stream>>>(x, csr, offsets, counts, aggx, N);
  k_lin1   <<<2048, 256, 0, stream>>>(aggx, x, W1l, b1l, W1r, x1bf, N);
  k_agg2   <<<4096, 256, 0, stream>>>(x1bf, csr, offsets, counts, agg2bf, N);

  int nstrips = (N + 127) / 128;
  k_dual2  <<<nstrips, 512, 0, stream>>>(agg2bf, x1bf, W2l_bf, W2r_bf, b2l, x2bf, N);
  k_gru2   <<<nstrips, 512, 0, stream>>>(x2bf, h, Wih_bf, Whh_bf, bih, bhh, hnew, hnewbf, N);
  k_proj2  <<<nstrips, 512, 0, stream>>>(hnewbf, V2_bf, bd1, PQbf, D1, N);
  k_disp2  <<<1024, 256, 0, stream>>>(D1, Wd2, bd2, disp, N);
  k_force  <<<2048, 256, 0, stream>>>(ei, ea, PQbf, Wf1, bf1, Wf2, bf2, force, E);
}

// Round 9
// 300.301 us; speedup vs baseline: 4.0112x; 1.2114x over previous
//
#include <hip/hip_runtime.h>
#include <hip/hip_bf16.h>

#define H 128
#define IN_DIM 30
#define LDSP 136  // padded row stride (ushorts) for staged activations
#define LDSP1 72  // padded row stride for lin1 strips (K=64)

typedef __attribute__((ext_vector_type(8))) short bf16x8;
typedef __attribute__((ext_vector_type(8))) unsigned short u16x8;
typedef __attribute__((ext_vector_type(4))) float f32x4;

__device__ inline unsigned short f2bf(float f){
  unsigned int u = __builtin_bit_cast(unsigned int, f);
  unsigned int r = u + 0x7FFF + ((u >> 16) & 1);
  return (unsigned short)(r >> 16);
}
__device__ inline float bf2f(unsigned short b){
  unsigned int u = ((unsigned int)b) << 16;
  return __builtin_bit_cast(float, u);
}
__device__ inline bf16x8 ldfrag(const unsigned short* p){
  return *(const bf16x8*)p;
}

// ---------------- CSR build (XCD-partitioned: block b owns node range of partition b&7) ----------------
__global__ void k_count(const int* __restrict__ col, int* __restrict__ counts,
                        int E, int npp){
  int part = blockIdx.x & 7;
  int inst = blockIdx.x >> 3;
  int ninst = gridDim.x >> 3;
  int lo = part*npp, hi = lo + npp;
  for (int e = inst*blockDim.x + threadIdx.x; e < E; e += ninst*blockDim.x){
    int c = col[e];
    if (c >= lo && c < hi) atomicAdd(&counts[c], 1);
  }
}

__global__ void k_scanA(const int* __restrict__ counts, int* __restrict__ offsets,
                        int* __restrict__ bsum, int n){
  __shared__ int buf[256];
  int i = blockIdx.x*256 + threadIdx.x;
  int v = (i < n) ? counts[i] : 0;
  buf[threadIdx.x] = v; __syncthreads();
  for (int off = 1; off < 256; off <<= 1){
    int t = (threadIdx.x >= off) ? buf[threadIdx.x - off] : 0;
    __syncthreads();
    buf[threadIdx.x] += t;
    __syncthreads();
  }
  if (i < n) offsets[i] = buf[threadIdx.x] - v;
  if (threadIdx.x == 255) bsum[blockIdx.x] = buf[255];
}

__global__ void k_scanB(int* __restrict__ bsum, int nb){
  __shared__ int buf[256];
  int v = (threadIdx.x < nb) ? bsum[threadIdx.x] : 0;
  buf[threadIdx.x] = v; __syncthreads();
  for (int off = 1; off < 256; off <<= 1){
    int t = (threadIdx.x >= off) ? buf[threadIdx.x - off] : 0;
    __syncthreads();
    buf[threadIdx.x] += t;
    __syncthreads();
  }
  if (threadIdx.x < nb) bsum[threadIdx.x] = buf[threadIdx.x] - v;
}

__global__ void k_scanC(int* __restrict__ offsets, int* __restrict__ cursor,
                        const int* __restrict__ bsum, int n){
  int i = blockIdx.x*256 + threadIdx.x;
  if (i < n){ int o = offsets[i] + bsum[blockIdx.x]; offsets[i] = o; cursor[i] = o; }
}

__global__ void k_scatter(const int* __restrict__ ei, int* __restrict__ cursor,
                          int* __restrict__ csr, int E, int npp){
  int part = blockIdx.x & 7;
  int inst = blockIdx.x >> 3;
  int ninst = gridDim.x >> 3;
  int lo = part*npp, hi = lo + npp;
  for (int e = inst*blockDim.x + threadIdx.x; e < E; e += ninst*blockDim.x){
    int c = ei[E + e];
    if (c >= lo && c < hi){
      int p = atomicAdd(&cursor[c], 1);
      csr[p] = ei[e];
    }
  }
}

// ---------------- weight conversion to bf16 ----------------
// V2 layout [160][128]: rows 0..63 = Wf1 P-part, 64..127 = Wf1 Q-part, 128..159 = Wd1
// W1c layout [128][64]: cols 0..29 = W1l, 32..61 = W1r, rest 0
__global__ void k_wconv(const float* __restrict__ W2l, const float* __restrict__ W2r,
                        const float* __restrict__ Wih, const float* __restrict__ Whh,
                        const float* __restrict__ Wf1, const float* __restrict__ Wd1,
                        const float* __restrict__ W1l, const float* __restrict__ W1r,
                        unsigned short* __restrict__ W2l_bf, unsigned short* __restrict__ W2r_bf,
                        unsigned short* __restrict__ Wih_bf, unsigned short* __restrict__ Whh_bf,
                        unsigned short* __restrict__ V2_bf, unsigned short* __restrict__ W1c_bf){
  int stride = gridDim.x*blockDim.x;
  for (int i = blockIdx.x*blockDim.x + threadIdx.x; i < 49152; i += stride){
    if (i < 8192){
      int c = i >> 6, k = i & 63;
      float v = 0.f;
      if (k < IN_DIM)                      v = W1l[c*IN_DIM + k];
      else if (k >= 32 && k < 32 + IN_DIM) v = W1r[c*IN_DIM + (k - 32)];
      W1c_bf[i] = f2bf(v);
    }
    if (i < 16384){
      W2l_bf[i] = f2bf(W2l[i]);
      W2r_bf[i] = f2bf(W2r[i]);
    }
    if (i < 20480){
      int j = i >> 7, k = i & 127;
      float v;
      if (j < 64)        v = Wf1[j*260 + k];
      else if (j < 128)  v = Wf1[(j-64)*260 + 128 + k];
      else               v = Wd1[(j-128)*128 + k];
      V2_bf[i] = f2bf(v);
    }
    Wih_bf[i] = f2bf(Wih[i]);
    Whh_bf[i] = f2bf(Whh[i]);
  }
}

// ---------------- aggx: mean of x (30-dim) rows -> bf16 [N][32] ----------------
__global__ __launch_bounds__(256) void k_aggx(
    const float* __restrict__ x, const int* __restrict__ csr,
    const int* __restrict__ offsets, const int* __restrict__ counts,
    unsigned short* __restrict__ aggxbf, int N)
{
  int t = blockIdx.x*blockDim.x + threadIdx.x;
  int gw = t >> 6, lane = t & 63;
  int nw = (gridDim.x*blockDim.x) >> 6;
  int half = lane >> 5, c = lane & 31;
  bool act = (c < IN_DIM);
  for (int d = gw; d < N; d += nw){
    int base = offsets[d], cnt = counts[d];
    float s0 = 0.f, s1 = 0.f;
    int i = half;
    for (; i + 2 < cnt; i += 4){
      int sr0 = csr[base + i];
      int sr1 = csr[base + i + 2];
      if (act){
        s0 += x[(size_t)sr0*IN_DIM + c];
        s1 += x[(size_t)sr1*IN_DIM + c];
      }
    }
    for (; i < cnt; i += 2){
      int sr = csr[base + i];
      if (act) s0 += x[(size_t)sr*IN_DIM + c];
    }
    float s = s0 + s1;
    s += __shfl_xor(s, 32);
    if (lane < 32){
      float inv = 1.f / (float)(cnt > 0 ? cnt : 1);
      aggxbf[(size_t)d*32 + c] = act ? f2bf(s*inv) : (unsigned short)0;
    }
  }
}

// ---------------- lin1 via MFMA strips: x1 = relu([agg|x] @ W1c.T + b1l) ----------------
__global__ __launch_bounds__(512) void k_lin1m(
    const unsigned short* __restrict__ aggxbf, const float* __restrict__ x,
    const unsigned short* __restrict__ W1c_bf, const float* __restrict__ b1l,
    unsigned short* __restrict__ x1bf, int N)
{
  __shared__ unsigned short sA[128*LDSP1];
  int tid = threadIdx.x;
  int wid = tid >> 6, l = tid & 63, m16 = l & 15, g4 = l >> 4;
  int col = wid*16 + m16;
  bf16x8 w1[2];
  #pragma unroll
  for (int kb = 0; kb < 2; kb++)
    w1[kb] = ldfrag(W1c_bf + (size_t)col*64 + kb*32 + g4*8);
  float bc = b1l[col];
  int nstrips = (N + 127) >> 7;
  for (int s = blockIdx.x; s < nstrips; s += gridDim.x){
    int base = s << 7;
    __syncthreads();
    for (int i = tid; i < 2048; i += 512){
      int row = i >> 4, c4 = (i & 15) << 2;
      int gr = min(base + row, N-1);
      ushort4 v;
      if (c4 < 32){
        v = *(const ushort4*)&aggxbf[(size_t)gr*32 + c4];
      } else {
        int j = c4 - 32;
        const float* xr = x + (size_t)gr*IN_DIM + j;
        v.x = f2bf(xr[0]);
        v.y = f2bf(xr[1]);
        v.z = (j + 2 < IN_DIM) ? f2bf(xr[2]) : (unsigned short)0;
        v.w = (j + 3 < IN_DIM) ? f2bf(xr[3]) : (unsigned short)0;
      }
      *(ushort4*)&sA[row*LDSP1 + c4] = v;
    }
    __syncthreads();
    #pragma unroll 1
    for (int rt = 0; rt < 8; rt++){
      int rb = rt*16;
      f32x4 acc = {bc, bc, bc, bc};
      #pragma unroll
      for (int kb = 0; kb < 2; kb++){
        bf16x8 a = *(const bf16x8*)&sA[(rb + m16)*LDSP1 + kb*32 + g4*8];
        acc = __builtin_amdgcn_mfma_f32_16x16x32_bf16(a, w1[kb], acc, 0, 0, 0);
      }
      #pragma unroll
      for (int j = 0; j < 4; j++){
        int row = base + rb + g4*4 + j;
        if (row < N)
          x1bf[(size_t)row*H + col] = f2bf(fmaxf(acc[j], 0.f));
      }
    }
  }
}

// ---------------- agg2 ----------------
__global__ __launch_bounds__(256) void k_agg2(
    const unsigned short* __restrict__ x1bf, const int* __restrict__ csr,
    const int* __restrict__ offsets, const int* __restrict__ counts,
    unsigned short* __restrict__ agg2bf, int N)
{
  int t = blockIdx.x*blockDim.x + threadIdx.x;
  int gw = t >> 6, lane = t & 63;
  int nw = (gridDim.x*blockDim.x) >> 6;
  const unsigned int* x1u = (const unsigned int*)x1bf;
  unsigned int* agu = (unsigned int*)agg2bf;
  for (int d = gw; d < N; d += nw){
    int base = offsets[d], cnt = counts[d];
    float a0 = 0.f, a1 = 0.f;
    int i = 0;
    for (; i + 3 < cnt; i += 4){
      int s0 = csr[base + i],     s1 = csr[base + i + 1];
      int s2 = csr[base + i + 2], s3 = csr[base + i + 3];
      unsigned int v0 = x1u[(size_t)s0*64 + lane];
      unsigned int v1 = x1u[(size_t)s1*64 + lane];
      unsigned int v2 = x1u[(size_t)s2*64 + lane];
      unsigned int v3 = x1u[(size_t)s3*64 + lane];
      a0 += bf2f((unsigned short)(v0 & 0xffff)) + bf2f((unsigned short)(v1 & 0xffff))
          + bf2f((unsigned short)(v2 & 0xffff)) + bf2f((unsigned short)(v3 & 0xffff));
      a1 += bf2f((unsigned short)(v0 >> 16)) + bf2f((unsigned short)(v1 >> 16))
          + bf2f((unsigned short)(v2 >> 16)) + bf2f((unsigned short)(v3 >> 16));
    }
    for (; i < cnt; i++){
      unsigned int v = x1u[(size_t)csr[base + i]*64 + lane];
      a0 += bf2f((unsigned short)(v & 0xffff));
      a1 += bf2f((unsigned short)(v >> 16));
    }
    float inv = 1.f / (float)(cnt > 0 ? cnt : 1);
    unsigned int o = (unsigned int)f2bf(a0*inv) | ((unsigned int)f2bf(a1*inv) << 16);
    agu[(size_t)d*64 + lane] = o;
  }
}

// ============ strip GEMM kernels: 512 thr, 128-row strips, LDS-staged A ============

// ---------------- SAGE2: x2 = relu(agg2@W2l.T + b2l + x1@W2r.T) ----------------
__global__ __launch_bounds__(512) void k_dual2(
    const unsigned short* __restrict__ Abf, const unsigned short* __restrict__ Bbf,
    const unsigned short* __restrict__ Wa, const unsigned short* __restrict__ Wb,
    const float* __restrict__ bias, unsigned short* __restrict__ outbf, int N)
{
  __shared__ unsigned short sA[128*LDSP];
  __shared__ unsigned short sB[128*LDSP];
  int tid = threadIdx.x;
  int wid = tid >> 6, l = tid & 63, m16 = l & 15, g4 = l >> 4;
  int col = wid*16 + m16;
  bf16x8 wa[4], wb[4];
  #pragma unroll
  for (int kb = 0; kb < 4; kb++){
    wa[kb] = ldfrag(Wa + (size_t)col*H + kb*32 + g4*8);
    wb[kb] = ldfrag(Wb + (size_t)col*H + kb*32 + g4*8);
  }
  float bc = bias[col];
  int nstrips = (N + 127) >> 7;
  for (int s = blockIdx.x; s < nstrips; s += gridDim.x){
    int base = s << 7;
    __syncthreads();
    for (int c = tid; c < 4096; c += 512){
      int mat = c >> 11, cc = c & 2047;
      int row = cc >> 4, co = cc & 15;
      int gr = min(base + row, N-1);
      u16x8 v = *(const u16x8*)((mat ? Bbf : Abf) + (size_t)gr*H + co*8);
      *(u16x8*)&((mat ? sB : sA)[row*LDSP + co*8]) = v;
    }
    __syncthreads();
    #pragma unroll 1
    for (int rt = 0; rt < 8; rt++){
      int rb = rt*16;
      f32x4 acc = {bc, bc, bc, bc};
      #pragma unroll
      for (int kb = 0; kb < 4; kb++){
        bf16x8 a = *(const bf16x8*)&sA[(rb + m16)*LDSP + kb*32 + g4*8];
        acc = __builtin_amdgcn_mfma_f32_16x16x32_bf16(a, wa[kb], acc, 0, 0, 0);
        bf16x8 b = *(const bf16x8*)&sB[(rb + m16)*LDSP + kb*32 + g4*8];
        acc = __builtin_amdgcn_mfma_f32_16x16x32_bf16(b, wb[kb], acc, 0, 0, 0);
      }
      #pragma unroll
      for (int j = 0; j < 4; j++){
        int row = base + rb + g4*4 + j;
        if (row < N)
          outbf[(size_t)row*H + col] = f2bf(fmaxf(acc[j], 0.f));
      }
    }
  }
}

// ---------------- fused GRU (stages h f32 -> bf16 inline) ----------------
__global__ __launch_bounds__(512) void k_gru2(
    const unsigned short* __restrict__ x2bf, const float* __restrict__ h,
    const unsigned short* __restrict__ Wih_bf, const unsigned short* __restrict__ Whh_bf,
    const float* __restrict__ bih, const float* __restrict__ bhh,
    float* __restrict__ hnew, unsigned short* __restrict__ hnewbf, int N)
{
  __shared__ unsigned short sX[128*LDSP];
  __shared__ unsigned short sH[128*LDSP];
  int tid = threadIdx.x;
  int wid = tid >> 6, l = tid & 63, m16 = l & 15, g4 = l >> 4;
  int col = wid*16 + m16;
  bf16x8 wih[3][4], whh[3][4];
  #pragma unroll
  for (int g = 0; g < 3; g++){
    #pragma unroll
    for (int kb = 0; kb < 4; kb++){
      wih[g][kb] = ldfrag(Wih_bf + (size_t)(g*H + col)*H + kb*32 + g4*8);
      whh[g][kb] = ldfrag(Whh_bf + (size_t)(g*H + col)*H + kb*32 + g4*8);
    }
  }
  float bir = bih[col],       bhr = bhh[col];
  float biz = bih[H + col],   bhz = bhh[H + col];
  float bin = bih[2*H + col], bhn = bhh[2*H + col];
  int nstrips = (N + 127) >> 7;
  for (int s = blockIdx.x; s < nstrips; s += gridDim.x){
    int base = s << 7;
    __syncthreads();
    for (int c = tid; c < 4096; c += 512){
      int mat = c >> 11, cc = c & 2047;
      int row = cc >> 4, co = cc & 15;
      int gr = min(base + row, N-1);
      if (mat == 0){
        u16x8 v = *(const u16x8*)(x2bf + (size_t)gr*H + co*8);
        *(u16x8*)&sX[row*LDSP + co*8] = v;
      } else {
        float4 f0 = *(const float4*)(h + (size_t)gr*H + co*8);
        float4 f1 = *(const float4*)(h + (size_t)gr*H + co*8 + 4);
        u16x8 v;
        v[0] = f2bf(f0.x); v[1] = f2bf(f0.y); v[2] = f2bf(f0.z); v[3] = f2bf(f0.w);
        v[4] = f2bf(f1.x); v[5] = f2bf(f1.y); v[6] = f2bf(f1.z); v[7] = f2bf(f1.w);
        *(u16x8*)&sH[row*LDSP + co*8] = v;
      }
    }
    __syncthreads();
    #pragma unroll 1
    for (int rt = 0; rt < 8; rt++){
      int rb = rt*16;
      bf16x8 aX[4], aH[4];
      #pragma unroll
      for (int kb = 0; kb < 4; kb++){
        aX[kb] = *(const bf16x8*)&sX[(rb + m16)*LDSP + kb*32 + g4*8];
        aH[kb] = *(const bf16x8*)&sH[(rb + m16)*LDSP + kb*32 + g4*8];
      }
      f32x4 aRi = {bir,bir,bir,bir}, aRh = {bhr,bhr,bhr,bhr};
      f32x4 aZi = {biz,biz,biz,biz}, aZh = {bhz,bhz,bhz,bhz};
      f32x4 aNi = {bin,bin,bin,bin}, aNh = {bhn,bhn,bhn,bhn};
      #pragma unroll
      for (int kb = 0; kb < 4; kb++){
        aRi = __builtin_amdgcn_mfma_f32_16x16x32_bf16(aX[kb], wih[0][kb], aRi, 0,0,0);
        aRh = __builtin_amdgcn_mfma_f32_16x16x32_bf16(aH[kb], whh[0][kb], aRh, 0,0,0);
        aZi = __builtin_amdgcn_mfma_f32_16x16x32_bf16(aX[kb], wih[1][kb], aZi, 0,0,0);
        aZh = __builtin_amdgcn_mfma_f32_16x16x32_bf16(aH[kb], whh[1][kb], aZh, 0,0,0);
        aNi = __builtin_amdgcn_mfma_f32_16x16x32_bf16(aX[kb], wih[2][kb], aNi, 0,0,0);
        aNh = __builtin_amdgcn_mfma_f32_16x16x32_bf16(aH[kb], whh[2][kb], aNh, 0,0,0);
      }
      #pragma unroll
      for (int j = 0; j < 4; j++){
        int row = base + rb + g4*4 + j;
        if (row < N){
          float r = 1.f / (1.f + expf(-(aRi[j] + aRh[j])));
          float z = 1.f / (1.f + expf(-(aZi[j] + aZh[j])));
          float nn = tanhf(aNi[j] + r*aNh[j]);
          float hv = bf2f(sH[(rb + g4*4 + j)*LDSP + col]);
          float o = (1.f - z)*nn + z*hv;
          hnew[(size_t)row*H + col] = o;
          hnewbf[(size_t)row*H + col] = f2bf(o);
        }
      }
    }
  }
}

// ---------------- proj: PQ (bf16, cols 0..127) and D1 (relu f32, V2 rows 128..159) ----------------
__global__ __launch_bounds__(512) void k_proj2(
    const unsigned short* __restrict__ hnewbf, const unsigned short* __restrict__ V2_bf,
    const float* __restrict__ bd1,
    unsigned short* __restrict__ PQbf, float* __restrict__ D1, int N)
{
  __shared__ unsigned short sHn[128*LDSP];
  int tid = threadIdx.x;
  int wid = tid >> 6, l = tid & 63, m16 = l & 15, g4 = l >> 4;
  int col = wid*16 + m16;
  bf16x8 v1[4], v2[4];
  #pragma unroll
  for (int kb = 0; kb < 4; kb++)
    v1[kb] = ldfrag(V2_bf + (size_t)col*H + kb*32 + g4*8);
  int dc = wid*16 + m16;
  float bdv = 0.f;
  if (wid < 2){
    #pragma unroll
    for (int kb = 0; kb < 4; kb++)
      v2[kb] = ldfrag(V2_bf + (size_t)(128 + dc)*H + kb*32 + g4*8);
    bdv = bd1[dc];
  }
  int nstrips = (N + 127) >> 7;
  for (int s = blockIdx.x; s < nstrips; s += gridDim.x){
    int base = s << 7;
    __syncthreads();
    for (int c = tid; c < 2048; c += 512){
      int row = c >> 4, co = c & 15;
      int gr = min(base + row, N-1);
      u16x8 v = *(const u16x8*)(hnewbf + (size_t)gr*H + co*8);
      *(u16x8*)&(sHn[row*LDSP + co*8]) = v;
    }
    __syncthreads();
    #pragma unroll 1
    for (int rt = 0; rt < 8; rt++){
      int rb = rt*16;
      bf16x8 aH[4];
      #pragma unroll
      for (int kb = 0; kb < 4; kb++)
        aH[kb] = *(const bf16x8*)&sHn[(rb + m16)*LDSP + kb*32 + g4*8];
      f32x4 acc = {0.f, 0.f, 0.f, 0.f};
      #pragma unroll
      for (int kb = 0; kb < 4; kb++)
        acc = __builtin_amdgcn_mfma_f32_16x16x32_bf16(aH[kb], v1[kb], acc, 0, 0, 0);
      #pragma unroll
      for (int j = 0; j < 4; j++){
        int row = base + rb + g4*4 + j;
        if (row < N)
          PQbf[(size_t)row*H + col] = f2bf(acc[j]);
      }
      if (wid < 2){
        f32x4 acc2 = {0.f, 0.f, 0.f, 0.f};
        #pragma unroll
        for (int kb = 0; kb < 4; kb++)
          acc2 = __builtin_amdgcn_mfma_f32_16x16x32_bf16(aH[kb], v2[kb], acc2, 0, 0, 0);
        #pragma unroll
        for (int j = 0; j < 4; j++){
          int row = base + rb + g4*4 + j;
          if (row < N)
            D1[(size_t)row*32 + dc] = fmaxf(acc2[j] + bdv, 0.f);
        }
      }
    }
  }
}

// ---------------- disp from D1: 32-lane group per node ----------------
__global__ __launch_bounds__(256) void k_disp2(
    const float* __restrict__ D1, const float* __restrict__ Wd2,
    const float* __restrict__ bd2, float* __restrict__ disp, int N)
{
  int t = blockIdx.x*blockDim.x + threadIdx.x;
  int gh = t >> 5, sub = t & 31;
  int nh = (gridDim.x*blockDim.x) >> 5;
  float w0 = Wd2[sub], w1 = Wd2[32 + sub], w2 = Wd2[64 + sub];
  float bo = (sub < 3) ? bd2[sub] : 0.f;
  for (int d = gh; d < N; d += nh){
    float v = D1[(size_t)d*32 + sub];
    float v0 = v*w0, v1 = v*w1, v2 = v*w2;
    #pragma unroll
    for (int off = 1; off < 32; off <<= 1){
      v0 += __shfl_xor(v0, off, 32);
      v1 += __shfl_xor(v1, off, 32);
      v2 += __shfl_xor(v2, off, 32);
    }
    if (sub < 3) disp[(size_t)d*3 + sub] = (sub == 0 ? v0 : (sub == 1 ? v1 : v2)) + bo;
  }
}

// ---------------- force decoder: MFMA over 16-edge tiles, 3-stage pipelined gathers ----------------
__global__ __launch_bounds__(256) void k_force(
    const int* __restrict__ ei, const float* __restrict__ ea,
    const unsigned short* __restrict__ PQbf,
    const float* __restrict__ Wf1, const float* __restrict__ bf1,
    const float* __restrict__ Wf2, const float* __restrict__ bf2,
    float* __restrict__ out, int E)
{
  int l = threadIdx.x & 63;
  int r = l & 15, g = l >> 4;
  float4 wc0[8], wc1[8];
  float b1r0[8], b1r1[8];
  bf16x8 bfr0, bfr1;
  float bo = (r < 3) ? bf2[r] : 0.f;
  #pragma unroll
  for (int j = 0; j < 8; j++){
    int k0 = g*8 + j, k1 = 32 + g*8 + j;
    wc0[j] = *(const float4*)&Wf1[k0*260 + 256];
    wc1[j] = *(const float4*)&Wf1[k1*260 + 256];
    b1r0[j] = bf1[k0];
    b1r1[j] = bf1[k1];
    bfr0[j] = (r < 3) ? (short)f2bf(Wf2[r*64 + k0]) : (short)0;
    bfr1[j] = (r < 3) ? (short)f2bf(Wf2[r*64 + k1]) : (short)0;
  }
  int nt = (E + 15) >> 4;
  int stride = gridDim.x*4;
  int t = blockIdx.x*4 + (threadIdx.x >> 6);
  if (t >= nt) return;

  int pcA = min(t*16 + r, E-1);
  int sA = ei[pcA], dA = ei[E + pcA];
  float4 aA = *(const float4*)&ea[(size_t)pcA*4];
  u16x8 pA0 = *(const u16x8*)&PQbf[(size_t)sA*H + g*8];
  u16x8 pA1 = *(const u16x8*)&PQbf[(size_t)sA*H + 32 + g*8];
  u16x8 qA0 = *(const u16x8*)&PQbf[(size_t)dA*H + 64 + g*8];
  u16x8 qA1 = *(const u16x8*)&PQbf[(size_t)dA*H + 96 + g*8];
  int t2 = t + stride;
  int sB = 0, dB = 0; float4 aB = {0.f,0.f,0.f,0.f};
  if (t2 < nt){
    int pcB = min(t2*16 + r, E-1);
    sB = ei[pcB]; dB = ei[E + pcB];
    aB = *(const float4*)&ea[(size_t)pcB*4];
  }
  while (true){
    u16x8 pB0, pB1, qB0, qB1;
    if (t2 < nt){
      pB0 = *(const u16x8*)&PQbf[(size_t)sB*H + g*8];
      pB1 = *(const u16x8*)&PQbf[(size_t)sB*H + 32 + g*8];
      qB0 = *(const u16x8*)&PQbf[(size_t)dB*H + 64 + g*8];
      qB1 = *(const u16x8*)&PQbf[(size_t)dB*H + 96 + g*8];
    }
    int t3 = t2 + stride;
    int sC = 0, dC = 0; float4 aC = {0.f,0.f,0.f,0.f};
    if (t3 < nt){
      int pcC = min(t3*16 + r, E-1);
      sC = ei[pcC]; dC = ei[E + pcC];
      aC = *(const float4*)&ea[(size_t)pcC*4];
    }
    {
      bf16x8 af0, af1;
      #pragma unroll
      for (int j = 0; j < 8; j++){
        float pre0 = bf2f((unsigned short)pA0[j]) + bf2f((unsigned short)qA0[j]) + b1r0[j]
                   + aA.x*wc0[j].x + aA.y*wc0[j].y + aA.z*wc0[j].z + aA.w*wc0[j].w;
        af0[j] = (short)f2bf(fmaxf(pre0, 0.f));
        float pre1 = bf2f((unsigned short)pA1[j]) + bf2f((unsigned short)qA1[j]) + b1r1[j]
                   + aA.x*wc1[j].x + aA.y*wc1[j].y + aA.z*wc1[j].z + aA.w*wc1[j].w;
        af1[j] = (short)f2bf(fmaxf(pre1, 0.f));
      }
      f32x4 acc = {0.f, 0.f, 0.f, 0.f};
      acc = __builtin_amdgcn_mfma_f32_16x16x32_bf16(af0, bfr0, acc, 0, 0, 0);
      acc = __builtin_amdgcn_mfma_f32_16x16x32_bf16(af1, bfr1, acc, 0, 0, 0);
      if (r < 3){
        #pragma unroll
        for (int j = 0; j < 4; j++){
          int erow = t*16 + g*4 + j;
          if (erow < E) out[(size_t)erow*3 + r] = acc[j] + bo;
        }
      }
    }
    if (t2 >= nt) break;
    t = t2; t2 = t3;
    aA = aB; pA0 = pB0; pA1 = pB1; qA0 = qB0; qA1 = qB1;
    sB = sC; dB = dC; aB = aC;
  }
}

extern "C" void kernel_launch(void* const* d_in, const int* in_sizes, int n_in,
                              void* d_out, int out_size, void* d_ws, size_t ws_size,
                              hipStream_t stream)
{
  const float* x   = (const float*)d_in[0];
  const int*   ei  = (const int*)d_in[1];
  const float* ea  = (const float*)d_in[2];
  const float* h   = (const float*)d_in[3];
  const float* W1l = (const float*)d_in[4];
  const float* b1l = (const float*)d_in[5];
  const float* W1r = (const float*)d_in[6];
  const float* W2l = (const float*)d_in[7];
  const float* b2l = (const float*)d_in[8];
  const float* W2r = (const float*)d_in[9];
  const float* Wih = (const float*)d_in[10];
  const float* Whh = (const float*)d_in[11];
  const float* bih = (const float*)d_in[12];
  const float* bhh = (const float*)d_in[13];
  const float* Wd1 = (const float*)d_in[14];
  const float* bd1 = (const float*)d_in[15];
  const float* Wd2 = (const float*)d_in[16];
  const float* bd2 = (const float*)d_in[17];
  const float* Wf1 = (const float*)d_in[18];
  const float* bf1 = (const float*)d_in[19];
  const float* Wf2 = (const float*)d_in[20];
  const float* bf2 = (const float*)d_in[21];

  int N = in_sizes[0] / IN_DIM;
  int E = in_sizes[1] / 2;
  int npp = (N + 7) / 8;  // nodes per XCD partition

  char* ws = (char*)d_ws;
  size_t off = 0;
  auto alloc = [&](size_t bytes) -> char* {
    char* p = ws + off;
    off = (off + bytes + 255) & ~(size_t)255;
    return p;
  };
  int* counts  = (int*)alloc((size_t)N*4);
  int* offsets = (int*)alloc((size_t)N*4);
  int* cursor  = (int*)alloc((size_t)N*4);
  int* bsum    = (int*)alloc(1024);
  int* csr     = (int*)alloc((size_t)E*4);
  // pool: aggxbf(uses 3.2MB of 6.4MB slot) | x1bf(12.8MB) | agg2bf(12.8MB);
  // reused post-GRU: PQbf (12.8MB) over aggx+x1bf slots; D1 (6.4MB) over agg2bf
  unsigned short* aggxbf = (unsigned short*)alloc((size_t)N*32*4);
  unsigned short* x1bf   = (unsigned short*)alloc((size_t)N*H*2);
  unsigned short* agg2bf = (unsigned short*)alloc((size_t)N*H*2);
  unsigned short* PQbf = (unsigned short*)aggxbf;
  float* D1            = (float*)agg2bf;
  unsigned short* x2bf   = (unsigned short*)alloc((size_t)N*H*2);
  unsigned short* hnewbf = (unsigned short*)alloc((size_t)N*H*2);
  unsigned short* W2l_bf = (unsigned short*)alloc(16384*2);
  unsigned short* W2r_bf = (unsigned short*)alloc(16384*2);
  unsigned short* Wih_bf = (unsigned short*)alloc(49152*2);
  unsigned short* Whh_bf = (unsigned short*)alloc(49152*2);
  unsigned short* V2_bf  = (unsigned short*)alloc(20480*2);
  unsigned short* W1c_bf = (unsigned short*)alloc(8192*2);

  float* disp  = (float*)d_out;
  float* force = disp + (size_t)N*3;
  float* hnew  = force + (size_t)E*3;

  hipMemsetAsync(counts, 0, (size_t)N*4, stream);
  int nb = (N + 255) / 256;
  k_count  <<<2048, 256, 0, stream>>>(ei + E, counts, E, npp);
  k_scanA  <<<nb, 256, 0, stream>>>(counts, offsets, bsum, N);
  k_scanB  <<<1, 256, 0, stream>>>(bsum, nb);
  k_scanC  <<<nb, 256, 0, stream>>>(offsets, cursor, bsum, N);
  k_scatter<<<2048, 256, 0, stream>>>(ei, cursor, csr, E, npp);

  k_wconv  <<<192, 256, 0, stream>>>(W2l, W2r, Wih, Whh, Wf1, Wd1, W1l, W1r,
                                     W2l_bf, W2r_bf, Wih_bf, Whh_bf, V2_bf, W1c_bf);

  k_aggx   <<<4096, 256, 0, stream>>>(x, csr, offsets, counts, aggxbf, N);

  int nstrips = (N + 127) / 128;
  k_lin1m  <<<nstrips, 512, 0, stream>>>(aggxbf, x, W1c_bf, b1l, x1bf, N);
  k_agg2   <<<4096, 256, 0, stream>>>(x1bf, csr, offsets, counts, agg2bf, N);
  k_dual2  <<<nstrips, 512, 0, stream>>>(agg2bf, x1bf, W2l_bf, W2r_bf, b2l, x2bf, N);
  k_gru2   <<<nstrips, 512, 0, stream>>>(x2bf, h, Wih_bf, Whh_bf, bih, bhh, hnew, hnewbf, N);
  k_proj2  <<<nstrips, 512, 0, stream>>>(hnewbf, V2_bf, bd1, PQbf, D1, N);
  k_disp2  <<<1024, 256, 0, stream>>>(D1, Wd2, bd2, disp, N);
  k_force  <<<2048, 256, 0, stream>>>(ei, ea, PQbf, Wf1, bf1, Wf2, bf2, force, E);
}